// Round 1
// 1964.567 us; speedup vs baseline: 1.0345x; 1.0345x over previous
//
#include <hip/hip_runtime.h>
#include <math.h>

#define B_ 256
#define N_ 127
#define S_ 128
#define NDIM_ 3
#define D_ 256
#define H_ 8
#define DH_ 32
#define M_ 256
#define HID_ 256
#define L_ 4
#define LOG2E 1.44269504088896340736f

typedef __attribute__((ext_vector_type(8))) short short8;
typedef __attribute__((ext_vector_type(4))) float floatx4;

// ---------- bf16 split helpers ----------
__device__ __forceinline__ ushort bf16_rn(float x) {
    unsigned u = __float_as_uint(x);
    u = (u + 0x7fffu + ((u >> 16) & 1u)) >> 16;
    return (ushort)u;
}
__device__ __forceinline__ void split2(float x, unsigned& hh, unsigned& ll) {
    const ushort h = bf16_rn(x);
    const float r = x - __uint_as_float(((unsigned)h) << 16);
    const ushort l = bf16_rn(r);
    hh = (unsigned)h * 0x10001u;
    ll = (unsigned)l * 0x10001u;
}
__device__ __forceinline__ unsigned split_pack(float x) {
    const ushort h = bf16_rn(x);
    const float r = x - __uint_as_float(((unsigned)h) << 16);
    const ushort l = bf16_rn(r);
    return (unsigned)h | ((unsigned)l << 16);
}

// ---------- block reductions ----------
__device__ __forceinline__ float blk_sum(float v, float* sred) {
#pragma unroll
    for (int o = 32; o > 0; o >>= 1) v += __shfl_xor(v, o, 64);
    if ((threadIdx.x & 63) == 0) sred[threadIdx.x >> 6] = v;
    __syncthreads();
    v = sred[0] + sred[1] + sred[2] + sred[3];
    __syncthreads();
    return v;
}

// ---------- embedding ----------
__global__ void k_embed(const float* __restrict__ x, const float* __restrict__ ew,
                        const float* __restrict__ eb, float* __restrict__ h) {
    const int idx = blockIdx.x * 256 + threadIdx.x;
    const int d = idx & (D_ - 1);
    const int n = (idx >> 8) & (S_ - 1);
    const int b = idx >> 15;
    float val = 0.f;
    if (n > 0) {
        const float* xr = x + ((size_t)b * N_ + (n - 1)) * NDIM_;
        val = eb[d] + xr[0] * ew[d * 3 + 0] + xr[1] * ew[d * 3 + 1] + xr[2] * ew[d * 3 + 2];
    }
    h[idx] = val;
}

// ---------- weight pre-split (compact): fp32 -> uint [h|l<<16] ----------
__global__ void __launch_bounds__(256) k_wconv(const float* __restrict__ src, unsigned* __restrict__ dst) {
    const int idx = (blockIdx.x * 256 + threadIdx.x) * 4;
    const float4 w4 = *(const float4*)&src[idx];
    const float v[4] = {w4.x, w4.y, w4.z, w4.w};
    unsigned u[4];
#pragma unroll
    for (int i = 0; i < 4; i++) u[i] = split_pack(v[i]);
    *(uint4*)&dst[idx] = make_uint4(u[0], u[1], u[2], u[3]);
}

// ---------- MFMA bf16x2-split GEMM, software-pipelined ----------
// 512 threads (8 waves); wave w: row-group w>>2, col-group w&3; acc[2][4].
// Pipeline per s-step: issue global loads for s+1 (regs) -> MFMA from LDS[p]
// -> split+write s+1 to LDS[p^1] -> ONE barrier. vm-wait lands after MFMAs.
template<int EPI>
__global__ void __launch_bounds__(512, 4) k_gemm(
    const float* __restrict__ A, const unsigned* __restrict__ W2,
    const float* __restrict__ bias, const float* __restrict__ g1,
    const float* __restrict__ g2, const int* __restrict__ mask,
    float* __restrict__ out)
{
    __shared__ ushort A2s[2][4 * 64 * 8];     // [buf][c][row][8]
    __shared__ ushort W2s[2][4 * 256 * 8];    // [buf][c][col][8]
    __shared__ float sredA[64][4], sredB[64][4];
    const int t = threadIdx.x;
    const int w = t >> 6, lane = t & 63;
    const int quad = lane >> 4, l16 = lane & 15;
    const int rowbase = 32 * (w >> 2), colbase = 64 * (w & 3);
    const int colg = w & 3;
    const int row0 = blockIdx.x * 64;

    floatx4 acc[2][4];
#pragma unroll
    for (int rt = 0; rt < 2; rt++)
#pragma unroll
        for (int ct = 0; ct < 4; ct++) acc[rt][ct] = (floatx4){0.f, 0.f, 0.f, 0.f};

    const int srow = t >> 2, skq = t & 3;                  // A staging (t < 256)
    const float* Arow = A + (size_t)(row0 + srow) * D_ + skq * 2;
    const int wcol = t - 256;                              // W staging (t >= 256)
    const unsigned* Wrow = W2 + (size_t)wcol * 256;

    // prologue: stage s=0 into buf 0
    if (t < 256) {
        const float2 a2 = *(const float2*)(Arow);
        unsigned hh0, ll0, hh1, ll1;
        split2(a2.x, hh0, ll0); split2(a2.y, hh1, ll1);
        *(uint4*)&A2s[0][skq * 512 + srow * 8] = make_uint4(hh0, ll0, hh1, ll1);
    } else {
        const uint4* wp = (const uint4*)(Wrow);
        const uint4 w0 = wp[0], w1 = wp[1];
        *(uint4*)&W2s[0][0 * 2048 + wcol * 8] = make_uint4(w0.x, w0.x, w0.y, w0.y);
        *(uint4*)&W2s[0][1 * 2048 + wcol * 8] = make_uint4(w0.z, w0.z, w0.w, w0.w);
        *(uint4*)&W2s[0][2 * 2048 + wcol * 8] = make_uint4(w1.x, w1.x, w1.y, w1.y);
        *(uint4*)&W2s[0][3 * 2048 + wcol * 8] = make_uint4(w1.z, w1.z, w1.w, w1.w);
    }
    __syncthreads();

    for (int s = 0; s < 32; s++) {
        const int p = s & 1;
        // (1) issue global loads for s+1 into registers — no use until (3)
        float2 a_nxt;
        uint4 w0_nxt, w1_nxt;
        if (s + 1 < 32) {
            if (t < 256) a_nxt = *(const float2*)(Arow + (s + 1) * 8);
            else {
                const uint4* wp = (const uint4*)(Wrow + (s + 1) * 8);
                w0_nxt = wp[0]; w1_nxt = wp[1];
            }
        }
        // (2) MFMA on step s from LDS[p]
        short8 af[2], bf[4];
#pragma unroll
        for (int rt = 0; rt < 2; rt++)
            af[rt] = *(const short8*)&A2s[p][quad * 512 + (rowbase + 16 * rt + l16) * 8];
#pragma unroll
        for (int ct = 0; ct < 4; ct++)
            bf[ct] = *(const short8*)&W2s[p][quad * 2048 + (colbase + 16 * ct + l16) * 8];
#pragma unroll
        for (int rt = 0; rt < 2; rt++)
#pragma unroll
            for (int ct = 0; ct < 4; ct++)
                acc[rt][ct] = __builtin_amdgcn_mfma_f32_16x16x32_bf16(af[rt], bf[ct], acc[rt][ct], 0, 0, 0);
        // (3) split + write s+1 into LDS[p^1] (free since s-1's MFMAs done pre-barrier)
        if (s + 1 < 32) {
            if (t < 256) {
                unsigned hh0, ll0, hh1, ll1;
                split2(a_nxt.x, hh0, ll0); split2(a_nxt.y, hh1, ll1);
                *(uint4*)&A2s[p ^ 1][skq * 512 + srow * 8] = make_uint4(hh0, ll0, hh1, ll1);
            } else {
                *(uint4*)&W2s[p ^ 1][0 * 2048 + wcol * 8] = make_uint4(w0_nxt.x, w0_nxt.x, w0_nxt.y, w0_nxt.y);
                *(uint4*)&W2s[p ^ 1][1 * 2048 + wcol * 8] = make_uint4(w0_nxt.z, w0_nxt.z, w0_nxt.w, w0_nxt.w);
                *(uint4*)&W2s[p ^ 1][2 * 2048 + wcol * 8] = make_uint4(w1_nxt.x, w1_nxt.x, w1_nxt.y, w1_nxt.y);
                *(uint4*)&W2s[p ^ 1][3 * 2048 + wcol * 8] = make_uint4(w1_nxt.z, w1_nxt.z, w1_nxt.w, w1_nxt.w);
            }
        }
        // (4) single barrier
        __syncthreads();
    }

    int colv[4]; float bv[4];
#pragma unroll
    for (int ct = 0; ct < 4; ct++) { colv[ct] = colbase + 16 * ct + l16; bv[ct] = bias[colv[ct]]; }

    if (EPI <= 1) {
        const int b = row0 >> 7;
#pragma unroll
        for (int rt = 0; rt < 2; rt++)
#pragma unroll
        for (int i = 0; i < 4; i++) {
            const int rl = rowbase + 16 * rt + quad * 4 + i;
            const int n = (row0 + rl) & (S_ - 1);
            float keep = 1.f;
            if (EPI == 1) keep = (n == 0) ? 1.f : (mask[b * N_ + n - 1] ? 0.f : 1.f);
#pragma unroll
            for (int ct = 0; ct < 4; ct++) {
                float c = acc[rt][ct][i] + bv[ct];
                if (EPI == 1) c *= keep;
                const int col = colv[ct];
                out[(((size_t)b * H_ + (col >> 5)) * S_ + n) * DH_ + (col & 31)] = c;
            }
        }
    } else if (EPI == 2) {
        float gv[4], bbv[4];
#pragma unroll
        for (int ct = 0; ct < 4; ct++) { gv[ct] = g1[colv[ct]]; bbv[ct] = g2[colv[ct]]; }
#pragma unroll
        for (int rt = 0; rt < 2; rt++)
#pragma unroll
        for (int i = 0; i < 4; i++) {
            const int rl = rowbase + 16 * rt + quad * 4 + i;
            float s = 0.f, s2 = 0.f;
#pragma unroll
            for (int ct = 0; ct < 4; ct++) {
                const float c = acc[rt][ct][i] + bv[ct];
                s += c; s2 += c * c;
            }
#pragma unroll
            for (int o = 8; o > 0; o >>= 1) { s += __shfl_xor(s, o, 64); s2 += __shfl_xor(s2, o, 64); }
            if (l16 == 0) { sredA[rl][colg] = s; sredB[rl][colg] = s2; }
        }
        __syncthreads();
#pragma unroll
        for (int rt = 0; rt < 2; rt++)
#pragma unroll
        for (int i = 0; i < 4; i++) {
            const int rl = rowbase + 16 * rt + quad * 4 + i;
            const float s = sredA[rl][0] + sredA[rl][1] + sredA[rl][2] + sredA[rl][3];
            const float s2 = sredB[rl][0] + sredB[rl][1] + sredB[rl][2] + sredB[rl][3];
            const float mu = s * (1.f / D_);
            const float rs = rsqrtf(s2 * (1.f / D_) - mu * mu + 1e-5f);
#pragma unroll
            for (int ct = 0; ct < 4; ct++) {
                const float c = acc[rt][ct][i] + bv[ct];
                out[(size_t)(row0 + rl) * D_ + colv[ct]] = (c - mu) * rs * gv[ct] + bbv[ct];
            }
        }
    } else {
#pragma unroll
        for (int rt = 0; rt < 2; rt++)
#pragma unroll
        for (int i = 0; i < 4; i++) {
            const int rl = rowbase + 16 * rt + quad * 4 + i;
#pragma unroll
            for (int ct = 0; ct < 4; ct++) {
                const float c = acc[rt][ct][i] + bv[ct];
                out[(size_t)(row0 + rl) * D_ + colv[ct]] = (c >= 0.f) ? c : 0.2f * c;
            }
        }
    }
}

// ---------- reset kmax slots ----------
__global__ void k_reset(int* slots) {
    if (threadIdx.x < 4) {
        const int i = __float_as_int(-INFINITY);
        slots[threadIdx.x] = (i >= 0) ? i : (i ^ 0x7fffffff);
    }
}

// ---------- MFMA global k-max (proven) ----------
__global__ void __launch_bounds__(256) k_dmax(
    const float* __restrict__ kg, const unsigned* __restrict__ P2, int* __restrict__ slot)
{
    __shared__ __align__(16) ushort A2s[64 * 136];
    __shared__ __align__(16) ushort Ps[128 * 136];
    __shared__ float sred[4];
    const int t = threadIdx.x;
    const size_t row0 = (size_t)(blockIdx.x >> 1) * 64;
    const int m0 = (blockIdx.x & 1) * 128;
    {
        const int row = t >> 2, kq = (t & 3) * 8;
        const float* src = kg + (row0 + row) * DH_ + kq;
        const float4 f0 = *(const float4*)src;
        const float4 f1 = *(const float4*)(src + 4);
        const float vv[8] = {f0.x, f0.y, f0.z, f0.w, f1.x, f1.y, f1.z, f1.w};
#pragma unroll
        for (int i = 0; i < 4; i++) {
            unsigned hh0, ll0, hh1, ll1;
            split2(vv[2 * i], hh0, ll0); split2(vv[2 * i + 1], hh1, ll1);
            *(uint4*)&A2s[row * 136 + ((t & 3) * 4 + i) * 8] = make_uint4(hh0, ll0, hh1, ll1);
        }
    }
    {
        const int col = t >> 1;
        const unsigned* src = P2 + (m0 + col) * DH_ + (t & 1) * 16;
#pragma unroll
        for (int i = 0; i < 8; i++) {
            const unsigned u0 = src[2 * i], u1 = src[2 * i + 1];
            *(uint4*)&Ps[col * 136 + ((t & 1) * 8 + i) * 8] = make_uint4(u0, u0, u1, u1);
        }
    }
    __syncthreads();
    const int w = t >> 6, lane = t & 63, quad = lane >> 4, l16 = lane & 15;
    floatx4 acc[4][2];
#pragma unroll
    for (int rt = 0; rt < 4; rt++)
#pragma unroll
        for (int ct = 0; ct < 2; ct++) acc[rt][ct] = (floatx4){0.f, 0.f, 0.f, 0.f};
#pragma unroll
    for (int kk = 0; kk < 4; kk++) {
        short8 af[4], bf[2];
#pragma unroll
        for (int rt = 0; rt < 4; rt++)
            af[rt] = *(const short8*)&A2s[(rt * 16 + l16) * 136 + (kk * 4 + quad) * 8];
#pragma unroll
        for (int ct = 0; ct < 2; ct++)
            bf[ct] = *(const short8*)&Ps[((w * 2 + ct) * 16 + l16) * 136 + (kk * 4 + quad) * 8];
#pragma unroll
        for (int rt = 0; rt < 4; rt++)
#pragma unroll
            for (int ct = 0; ct < 2; ct++)
                acc[rt][ct] = __builtin_amdgcn_mfma_f32_16x16x32_bf16(af[rt], bf[ct], acc[rt][ct], 0, 0, 0);
    }
    float mx = -INFINITY;
#pragma unroll
    for (int rt = 0; rt < 4; rt++)
#pragma unroll
        for (int ct = 0; ct < 2; ct++)
#pragma unroll
            for (int i = 0; i < 4; i++) mx = fmaxf(mx, acc[rt][ct][i]);
#pragma unroll
    for (int o = 32; o > 0; o >>= 1) mx = fmaxf(mx, __shfl_xor(mx, o, 64));
    if (lane == 0) sred[w] = mx;
    __syncthreads();
    if (t == 0) {
        const float m4 = fmaxf(fmaxf(sred[0], sred[1]), fmaxf(sred[2], sred[3]))
                       * 0.42044820762685725f;
        const int i = __float_as_int(m4);
        atomicMax(slot, (i >= 0) ? i : (i ^ 0x7fffffff));
    }
}

// ---------- full-MFMA performer attention v2, 1024 threads (16 waves) ----------
// Restructure vs v1:
//  * Q never staged in LDS: each wave holds its Q B-fragments in 16 VGPRs (qf[4]).
//  * P quarters staged ONCE per qd; qp MFMAs run concurrently with ctx MFMAs
//    (8 waves each, alternating halves per qd) — no idle half during ctx.
//  * adq reassigned to [2 qd][4 m-tiles] per wave so the o-MFMA B-operand comes
//    straight from registers (exp+split of own acc == B-fragment); the entire
//    qpA LDS round-trip (128 writes + 256 reads + 8 barriers) is deleted.
//  * o computed transposed (o^T[d][n] = ctx^T * qp^T); cross-half 16 KB f32
//    reduction aliased over dead kpT buffer; final store is a coalesced float4.
// Barriers per block: ~30 -> ~15. Arithmetic identical to v1.
__global__ void __launch_bounds__(1024) k_attn2(
    const float* __restrict__ qg, const float* __restrict__ kg, const float* __restrict__ vg,
    const unsigned* __restrict__ P2, const int* __restrict__ slot,
    float* __restrict__ outp)
{
    extern __shared__ char smem[];
    ushort* sA    = (ushort*)(smem);            // [128][136]: K-split
    ushort* sB    = (ushort*)(smem + 34816);    // [64][136]: P-quarter {h,l,h,l}
    ushort* sBig  = (ushort*)(smem + 52224);    // kpT [64][264]; later oRed f32[4096]
    ushort* sV    = (ushort*)(smem + 86016);    // [32][264]: v dup
    ushort* sCtx  = (ushort*)(smem + 102912);   // [32][520]: ctx dup
    float* sdk    = (float*)(smem + 136192);    // [128]
    float* sdq    = (float*)(smem + 136704);    // [128]
    float* smaxP  = (float*)(smem + 137216);    // [2][128]
    float* sdenP  = (float*)(smem + 138240);    // [2][128]
    float* sksum  = (float*)(smem + 139264);    // [256]
    float* sksP   = (float*)(smem + 140288);    // [16][32]

    const int bh = blockIdx.x;
    const int b = bh >> 3, hh = bh & 7;
    const int t = threadIdx.x;
    const int w = t >> 6, lane = t & 63, quad = lane >> 4, l16 = lane & 15;
    const int wg = w & 7, wh = w >> 3;
    const int nq = wg * 16 + l16;
    const float* kb = kg + (size_t)bh * S_ * DH_;
    const float* qb = qg + (size_t)bh * S_ * DH_;
    const float* vb = vg + (size_t)bh * S_ * DH_;
    const float nrm = 0.42044820762685725f;
    const float diagc = 0.5f * nrm * nrm;
    const float ratio = 0.0625f;

    union U8 { uint4 u; short8 s; };

    // Q B-fragments into regs: per ks, slots = {qh,qh,ql,ql}x2 for d0=ks*8+quad*2, d0+1
    short8 qf[4];
    {
        const float* qrow = qb + (size_t)nq * DH_ + quad * 2;
#pragma unroll
        for (int ks = 0; ks < 4; ks++) {
            const float2 qv = *(const float2*)(qrow + ks * 8);
            unsigned hh0, ll0, hh1, ll1;
            split2(qv.x, hh0, ll0); split2(qv.y, hh1, ll1);
            U8 tmp; tmp.u = make_uint4(hh0, ll0, hh1, ll1);
            qf[ks] = tmp.s;
        }
    }

    if (t < 512) {
        const int row = t >> 2, seg = t & 3;
        const float* src = kb + row * DH_ + seg * 8;
        float vv[8];
        *(float4*)&vv[0] = *(const float4*)&src[0];
        *(float4*)&vv[4] = *(const float4*)&src[4];
#pragma unroll
        for (int p = 0; p < 4; p++) {
            unsigned hh0, ll0, hh1, ll1;
            split2(vv[2 * p], hh0, ll0); split2(vv[2 * p + 1], hh1, ll1);
            *(uint4*)&sA[row * 136 + seg * 32 + p * 8] = make_uint4(hh0, ll0, hh1, ll1);
        }
    } else {
        const int tt2 = t - 512;
        const int n = tt2 & 127, d0 = (tt2 >> 7) * 8;
        const float* src = vb + n * DH_ + d0;
        float vv[8];
        *(float4*)&vv[0] = *(const float4*)&src[0];
        *(float4*)&vv[4] = *(const float4*)&src[4];
        unsigned* dst = (unsigned*)sV;
#pragma unroll
        for (int j = 0; j < 8; j++)
            dst[(d0 + j) * 132 + n] = (unsigned)bf16_rn(vv[j]) * 0x10001u;
    }
    if (t < 128) {
        float s = 0.f, s2 = 0.f;
#pragma unroll
        for (int d4 = 0; d4 < DH_ / 4; d4++) {
            const float4 kk = *(const float4*)&kb[t * DH_ + d4 * 4];
            s += kk.x * kk.x + kk.y * kk.y + kk.z * kk.z + kk.w * kk.w;
            const float4 qq = *(const float4*)&qb[t * DH_ + d4 * 4];
            s2 += qq.x * qq.x + qq.y * qq.y + qq.z * qq.z + qq.w * qq.w;
        }
        sdk[t] = s * diagc;
        sdq[t] = s2 * diagc;
    }
    float kmaxv;
    { const int iv = *slot; kmaxv = __int_as_float((iv >= 0) ? iv : (iv ^ 0x7fffffff)); }
    __syncthreads();

    // adq[j][mtl]: qp dd for this wave's qds (wh=1 -> qd {0,2}; wh=0 -> qd {1,3}),
    // all 4 m-tiles of the quarter. Layout: row m = mtl*16+quad*4+i, col n = nq.
    floatx4 adq[2][4];
#pragma unroll
    for (int j = 0; j < 2; j++)
#pragma unroll
        for (int mtl = 0; mtl < 4; mtl++) adq[j][mtl] = (floatx4){0.f, 0.f, 0.f, 0.f};

#pragma unroll
    for (int qd = 0; qd < 4; qd++) {
        // stage P quarter (safe: previous phase-C readers finished before last barrier)
        {
            const int col = t >> 4, ch2 = t & 15;
            const unsigned* src = P2 + (size_t)(qd * 64 + col) * DH_ + ch2 * 2;
            const unsigned u0 = src[0], u1 = src[1];
            *(uint4*)&sB[col * 136 + ch2 * 8] = make_uint4(u0, u0, u1, u1);
        }
        __syncthreads();
        // phase B: kp MFMAs (all 16 waves) + exp/split/pack + ksum partials
        floatx4 acc[2];
        acc[0] = (floatx4){0.f, 0.f, 0.f, 0.f};
        acc[1] = (floatx4){0.f, 0.f, 0.f, 0.f};
#pragma unroll
        for (int ks = 0; ks < 4; ks++) {
            const short8 af = *(const short8*)&sA[nq * 136 + ks * 32 + quad * 8];
            short8 bf[2];
#pragma unroll
            for (int ctl = 0; ctl < 2; ctl++)
                bf[ctl] = *(const short8*)&sB[((2 * wh + ctl) * 16 + l16) * 136 + ks * 32 + quad * 8];
#pragma unroll
            for (int ctl = 0; ctl < 2; ctl++)
                acc[ctl] = __builtin_amdgcn_mfma_f32_16x16x32_bf16(af, bf[ctl], acc[ctl], 0, 0, 0);
        }
        unsigned* kpT = (unsigned*)sBig;
        float kc[2];
#pragma unroll
        for (int ctl = 0; ctl < 2; ctl++) {
            float kcl = 0.f;
            unsigned pk[4];
#pragma unroll
            for (int i = 0; i < 4; i++) {
                const int n = wg * 16 + quad * 4 + i;
                const float kp = ratio * (exp2f((acc[ctl][i] * nrm - sdk[n] - kmaxv) * LOG2E) + 1e-4f);
                kcl += kp;
                pk[i] = split_pack(kp);
            }
            *(uint4*)&kpT[((2 * wh + ctl) * 16 + l16) * 132 + wg * 16 + quad * 4] =
                make_uint4(pk[0], pk[1], pk[2], pk[3]);
            kc[ctl] = kcl;
        }
#pragma unroll
        for (int ctl = 0; ctl < 2; ctl++) {
            kc[ctl] += __shfl_xor(kc[ctl], 16, 64);
            kc[ctl] += __shfl_xor(kc[ctl], 32, 64);
        }
        if (quad == 0) {
            sksP[w * 32 + l16] = kc[0];
            sksP[w * 32 + 16 + l16] = kc[1];
        }
        __syncthreads();
        // phase C: one half does qp MFMAs (B from regs), other half does ctx MFMAs
        const int qown = (qd & 1) ^ 1;   // which wh computes qp this qd
        if (wh == qown) {
            const int aidx = qd >> 1;
#pragma unroll
            for (int mtl = 0; mtl < 4; mtl++)
#pragma unroll
                for (int ks = 0; ks < 4; ks++) {
                    const short8 af2 = *(const short8*)&sB[(mtl * 16 + l16) * 136 + ks * 32 + quad * 8];
                    adq[aidx][mtl] = __builtin_amdgcn_mfma_f32_16x16x32_bf16(af2, qf[ks], adq[aidx][mtl], 0, 0, 0);
                }
        } else {
            const int mt = wg & 3, dt = wg >> 2;
            floatx4 cacc = (floatx4){0.f, 0.f, 0.f, 0.f};
#pragma unroll
            for (int ks = 0; ks < 8; ks++) {
                const short8 a = *(const short8*)&sBig[(mt * 16 + l16) * 264 + ks * 32 + quad * 8];
                const short8 bvv = *(const short8*)&sV[(dt * 16 + l16) * 264 + ks * 32 + quad * 8];
                cacc = __builtin_amdgcn_mfma_f32_16x16x32_bf16(a, bvv, cacc, 0, 0, 0);
            }
            unsigned* ctxB = (unsigned*)sCtx;
            unsigned pk2[4];
#pragma unroll
            for (int i = 0; i < 4; i++) pk2[i] = (unsigned)bf16_rn(cacc[i]) * 0x10001u;
            *(uint4*)&ctxB[(dt * 16 + l16) * 260 + qd * 64 + mt * 16 + quad * 4] =
                make_uint4(pk2[0], pk2[1], pk2[2], pk2[3]);
        }
        if (t < 64) {
            float s = 0.f;
#pragma unroll
            for (int wg2 = 0; wg2 < 8; wg2++)
                s += sksP[((t >> 5) * 8 + wg2) * 32 + (t & 31)];
            sksum[qd * 64 + t] = s;
        }
        __syncthreads();
    }

    // row max over this wave's half of (qd,m); union across wh = full m range
    {
        float mxn = -INFINITY;
#pragma unroll
        for (int j = 0; j < 2; j++)
#pragma unroll
            for (int mtl = 0; mtl < 4; mtl++)
#pragma unroll
                for (int i = 0; i < 4; i++) mxn = fmaxf(mxn, adq[j][mtl][i]);
        mxn = fmaxf(mxn, __shfl_xor(mxn, 16, 64));
        mxn = fmaxf(mxn, __shfl_xor(mxn, 32, 64));
        if (quad == 0) smaxP[wh * 128 + nq] = mxn;
    }
    __syncthreads();
    const float dmq = sdq[nq] + fmaxf(smaxP[nq], smaxP[128 + nq]) * nrm;

    // o^T[d][n]: A = ctx^T from sCtx (dup), B = exp+split of adq straight from regs.
    // No barriers in this loop — sCtx/sksum are stable.
    floatx4 oT[2];
    oT[0] = (floatx4){0.f, 0.f, 0.f, 0.f};
    oT[1] = (floatx4){0.f, 0.f, 0.f, 0.f};
    float dp = 0.f;
#pragma unroll
    for (int j = 0; j < 2; j++) {
        const int qdo = 2 * j + (wh ^ 1);
#pragma unroll
        for (int mtl = 0; mtl < 4; mtl++) {
            unsigned pk[4];
#pragma unroll
            for (int i = 0; i < 4; i++) {
                const float qp = ratio * (exp2f((adq[j][mtl][i] * nrm - dmq) * LOG2E) + 1e-4f);
                dp += qp * sksum[qdo * 64 + mtl * 16 + quad * 4 + i];
                pk[i] = split_pack(qp);
            }
            U8 tb; tb.u = make_uint4(pk[0], pk[1], pk[2], pk[3]);
#pragma unroll
            for (int dt = 0; dt < 2; dt++) {
                const short8 actx = *(const short8*)&sCtx[(dt * 16 + l16) * 520 + qdo * 128 + mtl * 32 + quad * 8];
                oT[dt] = __builtin_amdgcn_mfma_f32_16x16x32_bf16(actx, tb.s, oT[dt], 0, 0, 0);
            }
        }
    }
    dp += __shfl_xor(dp, 16, 64);
    dp += __shfl_xor(dp, 32, 64);
    if (quad == 0) sdenP[wh * 128 + nq] = dp;

    // cross-half o reduction through dead kpT space, then coalesced float4 store
    float* oRed = (float*)sBig;
    if (wh == 1) {
#pragma unroll
        for (int dt = 0; dt < 2; dt++)
            *(floatx4*)&oRed[((wg * 2 + dt) * 64 + lane) * 4] = oT[dt];
    }
    __syncthreads();
    if (wh == 0) {
        const float inv = 1.0f / (sdenP[nq] + sdenP[128 + nq]);
#pragma unroll
        for (int dt = 0; dt < 2; dt++) {
            const floatx4 o2 = *(const floatx4*)&oRed[((wg * 2 + dt) * 64 + lane) * 4];
            float4 r;
            r.x = (oT[dt][0] + o2[0]) * inv;
            r.y = (oT[dt][1] + o2[1]) * inv;
            r.z = (oT[dt][2] + o2[2]) * inv;
            r.w = (oT[dt][3] + o2[3]) * inv;
            *(float4*)&outp[((size_t)b * S_ + nq) * D_ + hh * DH_ + dt * 16 + quad * 4] = r;
        }
    }
}

// ---------- classification head ----------
__global__ void __launch_bounds__(256) k_head(
    const float* __restrict__ hfin, const float* __restrict__ h1w, const float* __restrict__ h1b,
    const float* __restrict__ h2w, const float* __restrict__ h2b,
    const float* __restrict__ ow, const float* __restrict__ ob, float* __restrict__ outp)
{
    __shared__ float c0[D_];
    __shared__ float c1[2 * HID_];
    __shared__ float sred[4];
    const int t = threadIdx.x;
    const int b = blockIdx.x;
    c0[t] = hfin[(size_t)b * S_ * D_ + t];
    __syncthreads();
#pragma unroll
    for (int half = 0; half < 2; half++) {
        const int j = half * 256 + t;
        float a = h1b[j];
        const float* w = h1w + (size_t)j * D_;
        for (int d = 0; d < D_; d += 4) {
            const float4 w4 = *(const float4*)&w[d];
            const float4 x4 = *(const float4*)&c0[d];
            a += x4.x * w4.x + x4.y * w4.y + x4.z * w4.z + x4.w * w4.w;
        }
        c1[j] = (a >= 0.f) ? a : 0.2f * a;
    }
    __syncthreads();
    float a2 = h2b[t];
    const float* w2 = h2w + (size_t)t * (2 * HID_);
    for (int j = 0; j < 2 * HID_; j += 4) {
        const float4 w4 = *(const float4*)&w2[j];
        const float4 x4 = *(const float4*)&c1[j];
        a2 += x4.x * w4.x + x4.y * w4.y + x4.z * w4.z + x4.w * w4.w;
    }
    const float c2 = (a2 >= 0.f) ? a2 : 0.2f * a2;
    const float s = blk_sum(c2 * ow[t], sred);
    if (t == 0) outp[b] = s + ob[0];
}

extern "C" void kernel_launch(void* const* d_in, const int* in_sizes, int n_in,
                              void* d_out, int out_size, void* d_ws, size_t ws_size,
                              hipStream_t stream)
{
    const float* x     = (const float*)d_in[0];
    const int*   mask  = (const int*)d_in[1];
    const float* emb_w = (const float*)d_in[2];
    const float* emb_b = (const float*)d_in[3];
    const float* Wq    = (const float*)d_in[4];
    const float* bq    = (const float*)d_in[5];
    const float* Wk    = (const float*)d_in[6];
    const float* bk    = (const float*)d_in[7];
    const float* Wv    = (const float*)d_in[8];
    const float* bv    = (const float*)d_in[9];
    const float* Wo    = (const float*)d_in[10];
    const float* bo    = (const float*)d_in[11];
    const float* proj  = (const float*)d_in[12];
    const float* n1w   = (const float*)d_in[13];
    const float* n1b   = (const float*)d_in[14];
    const float* n2w   = (const float*)d_in[15];
    const float* n2b   = (const float*)d_in[16];
    const float* f1w   = (const float*)d_in[17];
    const float* f1b   = (const float*)d_in[18];
    const float* f2w   = (const float*)d_in[19];
    const float* f2b   = (const float*)d_in[20];
    const float* h1w   = (const float*)d_in[21];
    const float* h1b   = (const float*)d_in[22];
    const float* h2w   = (const float*)d_in[23];
    const float* h2b   = (const float*)d_in[24];
    const float* ow    = (const float*)d_in[25];
    const float* ob    = (const float*)d_in[26];

    const size_t BSD = (size_t)B_ * S_ * D_;
    float* A = (float*)d_ws;
    float* Q = A + BSD;
    float* K = Q + BSD;
    float* V = K + BSD;
    float* T = K;                              // post-LN1 alias (K dead after attn)
    unsigned* W2 = (unsigned*)(V + BSD);       // compact split weights: 6 x L x 65536 uints
    const size_t WT = (size_t)L_ * 256 * 256;
    const size_t WM = (size_t)256 * 256;
    unsigned* P2 = W2 + 6 * WT;                // compact split proj: L x 256 x 32 uints
    int* slots = (int*)(P2 + (size_t)L_ * M_ * DH_);

    k_wconv<<<256, 256, 0, stream>>>(Wq,  W2 + 0 * WT);
    k_wconv<<<256, 256, 0, stream>>>(Wk,  W2 + 1 * WT);
    k_wconv<<<256, 256, 0, stream>>>(Wv,  W2 + 2 * WT);
    k_wconv<<<256, 256, 0, stream>>>(Wo,  W2 + 3 * WT);
    k_wconv<<<256, 256, 0, stream>>>(f1w, W2 + 4 * WT);
    k_wconv<<<256, 256, 0, stream>>>(f2w, W2 + 5 * WT);
    k_wconv<<<32, 256, 0, stream>>>(proj, P2);
    k_reset<<<1, 64, 0, stream>>>(slots);

    const int GB = B_ * S_ / 64;               // 512 blocks per GEMM
    const int DB = B_ * H_ * S_ / 64 * 2;      // 8192 blocks for k_dmax
    const size_t ATTN_LDS = 142336;            // 139 KB dynamic LDS

    k_embed<<<B_ * S_ * D_ / 256, 256, 0, stream>>>(x, emb_w, emb_b, A);
    for (int l = 0; l < L_; l++) {
        const unsigned* P2l = P2 + (size_t)l * M_ * DH_;
        k_gemm<0><<<GB, 512, 0, stream>>>(A, W2 + 0 * WT + l * WM, bq + l * D_, nullptr, nullptr, nullptr, Q);
        k_gemm<0><<<GB, 512, 0, stream>>>(A, W2 + 1 * WT + l * WM, bk + l * D_, nullptr, nullptr, nullptr, K);
        k_gemm<1><<<GB, 512, 0, stream>>>(A, W2 + 2 * WT + l * WM, bv + l * D_, nullptr, nullptr, mask, V);
        k_dmax<<<DB, 256, 0, stream>>>(K, P2l, slots + l);
        k_attn2<<<B_ * H_, 1024, ATTN_LDS, stream>>>(Q, K, V, P2l, slots + l, A);
        k_gemm<2><<<GB, 512, 0, stream>>>(A, W2 + 3 * WT + l * WM, bo + l * D_, n1w + l * D_, n1b + l * D_, nullptr, T);
        k_gemm<3><<<GB, 512, 0, stream>>>(T, W2 + 4 * WT + l * WM, f1b + l * HID_, nullptr, nullptr, nullptr, Q);
        k_gemm<2><<<GB, 512, 0, stream>>>(Q, W2 + 5 * WT + l * WM, f2b + l * D_, n2w + l * D_, n2b + l * D_, nullptr, A);
    }
    k_head<<<B_, 256, 0, stream>>>(A, h1w, h1b, h2w, h2b, ow, ob, (float*)d_out);
}

// Round 2
// 1937.741 us; speedup vs baseline: 1.0488x; 1.0138x over previous
//
#include <hip/hip_runtime.h>
#include <math.h>

#define B_ 256
#define N_ 127
#define S_ 128
#define NDIM_ 3
#define D_ 256
#define H_ 8
#define DH_ 32
#define M_ 256
#define HID_ 256
#define L_ 4
#define LOG2E 1.44269504088896340736f

typedef __attribute__((ext_vector_type(8))) short short8;
typedef __attribute__((ext_vector_type(4))) float floatx4;

// ---------- bf16 split helpers ----------
// Canonical activation format: packed uint  u = h | (l<<16)  where
// h = bf16_rn(x), l = bf16_rn(x - h). Same 4 B as fp32; producers pack once,
// consumers unpack with cheap byte-dup ops instead of a 12-op split2.
__device__ __forceinline__ ushort bf16_rn(float x) {
    unsigned u = __float_as_uint(x);
    u = (u + 0x7fffu + ((u >> 16) & 1u)) >> 16;
    return (ushort)u;
}
__device__ __forceinline__ unsigned split_pack(float x) {
    const ushort h = bf16_rn(x);
    const float r = x - __uint_as_float(((unsigned)h) << 16);
    const ushort l = bf16_rn(r);
    return (unsigned)h | ((unsigned)l << 16);
}
// {h,h} as two bf16 lanes
__device__ __forceinline__ unsigned dup_lo(unsigned u) {
    const unsigned h = u & 0xffffu;
    return h | (h << 16);
}
// {l,l} as two bf16 lanes
__device__ __forceinline__ unsigned dup_hi(unsigned u) {
    const unsigned l = u >> 16;
    return l | (l << 16);
}
// reconstruct fp32 ~= h + l (error ~2^-17 relative)
__device__ __forceinline__ float rec(unsigned u) {
    return __uint_as_float(u << 16) + __uint_as_float(u & 0xffff0000u);
}

// ---------- block reductions ----------
__device__ __forceinline__ float blk_sum(float v, float* sred) {
#pragma unroll
    for (int o = 32; o > 0; o >>= 1) v += __shfl_xor(v, o, 64);
    if ((threadIdx.x & 63) == 0) sred[threadIdx.x >> 6] = v;
    __syncthreads();
    v = sred[0] + sred[1] + sred[2] + sred[3];
    __syncthreads();
    return v;
}

// ---------- embedding (emits packed) ----------
__global__ void k_embed(const float* __restrict__ x, const float* __restrict__ ew,
                        const float* __restrict__ eb, unsigned* __restrict__ h) {
    const int idx = blockIdx.x * 256 + threadIdx.x;
    const int d = idx & (D_ - 1);
    const int n = (idx >> 8) & (S_ - 1);
    const int b = idx >> 15;
    float val = 0.f;
    if (n > 0) {
        const float* xr = x + ((size_t)b * N_ + (n - 1)) * NDIM_;
        val = eb[d] + xr[0] * ew[d * 3 + 0] + xr[1] * ew[d * 3 + 1] + xr[2] * ew[d * 3 + 2];
    }
    h[idx] = split_pack(val);
}

// ---------- weight pre-split (compact): fp32 -> uint [h|l<<16] ----------
__global__ void __launch_bounds__(256) k_wconv(const float* __restrict__ src, unsigned* __restrict__ dst) {
    const int idx = (blockIdx.x * 256 + threadIdx.x) * 4;
    const float4 w4 = *(const float4*)&src[idx];
    const float v[4] = {w4.x, w4.y, w4.z, w4.w};
    unsigned u[4];
#pragma unroll
    for (int i = 0; i < 4; i++) u[i] = split_pack(v[i]);
    *(uint4*)&dst[idx] = make_uint4(u[0], u[1], u[2], u[3]);
}

// ---------- MFMA bf16x2-split GEMM, software-pipelined ----------
// 512 threads (8 waves); wave w: row-group w>>2, col-group w&3; acc[2][4].
// A input is PACKED (h|l); staging is now dup_lo/dup_hi (3 ops) not split2 (12).
// All epilogues emit packed outputs.
template<int EPI>
__global__ void __launch_bounds__(512, 4) k_gemm(
    const unsigned* __restrict__ Ap, const unsigned* __restrict__ W2,
    const float* __restrict__ bias, const float* __restrict__ g1,
    const float* __restrict__ g2, const int* __restrict__ mask,
    unsigned* __restrict__ out)
{
    __shared__ ushort A2s[2][4 * 64 * 8];     // [buf][c][row][8]
    __shared__ ushort W2s[2][4 * 256 * 8];    // [buf][c][col][8]
    __shared__ float sredA[64][4], sredB[64][4];
    const int t = threadIdx.x;
    const int w = t >> 6, lane = t & 63;
    const int quad = lane >> 4, l16 = lane & 15;
    const int rowbase = 32 * (w >> 2), colbase = 64 * (w & 3);
    const int colg = w & 3;
    const int row0 = blockIdx.x * 64;

    floatx4 acc[2][4];
#pragma unroll
    for (int rt = 0; rt < 2; rt++)
#pragma unroll
        for (int ct = 0; ct < 4; ct++) acc[rt][ct] = (floatx4){0.f, 0.f, 0.f, 0.f};

    const int srow = t >> 2, skq = t & 3;                  // A staging (t < 256)
    const unsigned* Arow = Ap + (size_t)(row0 + srow) * D_ + skq * 2;
    const int wcol = t - 256;                              // W staging (t >= 256)
    const unsigned* Wrow = W2 + (size_t)wcol * 256;

    // prologue: stage s=0 into buf 0
    if (t < 256) {
        const uint2 a2 = *(const uint2*)(Arow);
        *(uint4*)&A2s[0][skq * 512 + srow * 8] =
            make_uint4(dup_lo(a2.x), dup_hi(a2.x), dup_lo(a2.y), dup_hi(a2.y));
    } else {
        const uint4* wp = (const uint4*)(Wrow);
        const uint4 w0 = wp[0], w1 = wp[1];
        *(uint4*)&W2s[0][0 * 2048 + wcol * 8] = make_uint4(w0.x, w0.x, w0.y, w0.y);
        *(uint4*)&W2s[0][1 * 2048 + wcol * 8] = make_uint4(w0.z, w0.z, w0.w, w0.w);
        *(uint4*)&W2s[0][2 * 2048 + wcol * 8] = make_uint4(w1.x, w1.x, w1.y, w1.y);
        *(uint4*)&W2s[0][3 * 2048 + wcol * 8] = make_uint4(w1.z, w1.z, w1.w, w1.w);
    }
    __syncthreads();

    for (int s = 0; s < 32; s++) {
        const int p = s & 1;
        // (1) issue global loads for s+1 into registers — no use until (3)
        uint2 a_nxt;
        uint4 w0_nxt, w1_nxt;
        if (s + 1 < 32) {
            if (t < 256) a_nxt = *(const uint2*)(Arow + (s + 1) * 8);
            else {
                const uint4* wp = (const uint4*)(Wrow + (s + 1) * 8);
                w0_nxt = wp[0]; w1_nxt = wp[1];
            }
        }
        // (2) MFMA on step s from LDS[p]
        short8 af[2], bf[4];
#pragma unroll
        for (int rt = 0; rt < 2; rt++)
            af[rt] = *(const short8*)&A2s[p][quad * 512 + (rowbase + 16 * rt + l16) * 8];
#pragma unroll
        for (int ct = 0; ct < 4; ct++)
            bf[ct] = *(const short8*)&W2s[p][quad * 2048 + (colbase + 16 * ct + l16) * 8];
#pragma unroll
        for (int rt = 0; rt < 2; rt++)
#pragma unroll
            for (int ct = 0; ct < 4; ct++)
                acc[rt][ct] = __builtin_amdgcn_mfma_f32_16x16x32_bf16(af[rt], bf[ct], acc[rt][ct], 0, 0, 0);
        // (3) unpack + write s+1 into LDS[p^1]
        if (s + 1 < 32) {
            if (t < 256) {
                *(uint4*)&A2s[p ^ 1][skq * 512 + srow * 8] =
                    make_uint4(dup_lo(a_nxt.x), dup_hi(a_nxt.x), dup_lo(a_nxt.y), dup_hi(a_nxt.y));
            } else {
                *(uint4*)&W2s[p ^ 1][0 * 2048 + wcol * 8] = make_uint4(w0_nxt.x, w0_nxt.x, w0_nxt.y, w0_nxt.y);
                *(uint4*)&W2s[p ^ 1][1 * 2048 + wcol * 8] = make_uint4(w0_nxt.z, w0_nxt.z, w0_nxt.w, w0_nxt.w);
                *(uint4*)&W2s[p ^ 1][2 * 2048 + wcol * 8] = make_uint4(w1_nxt.x, w1_nxt.x, w1_nxt.y, w1_nxt.y);
                *(uint4*)&W2s[p ^ 1][3 * 2048 + wcol * 8] = make_uint4(w1_nxt.z, w1_nxt.z, w1_nxt.w, w1_nxt.w);
            }
        }
        // (4) single barrier
        __syncthreads();
    }

    int colv[4]; float bv[4];
#pragma unroll
    for (int ct = 0; ct < 4; ct++) { colv[ct] = colbase + 16 * ct + l16; bv[ct] = bias[colv[ct]]; }

    if (EPI <= 1) {
        const int b = row0 >> 7;
#pragma unroll
        for (int rt = 0; rt < 2; rt++)
#pragma unroll
        for (int i = 0; i < 4; i++) {
            const int rl = rowbase + 16 * rt + quad * 4 + i;
            const int n = (row0 + rl) & (S_ - 1);
            float keep = 1.f;
            if (EPI == 1) keep = (n == 0) ? 1.f : (mask[b * N_ + n - 1] ? 0.f : 1.f);
#pragma unroll
            for (int ct = 0; ct < 4; ct++) {
                float c = acc[rt][ct][i] + bv[ct];
                if (EPI == 1) c *= keep;
                const int col = colv[ct];
                out[(((size_t)b * H_ + (col >> 5)) * S_ + n) * DH_ + (col & 31)] = split_pack(c);
            }
        }
    } else if (EPI == 2) {
        float gv[4], bbv[4];
#pragma unroll
        for (int ct = 0; ct < 4; ct++) { gv[ct] = g1[colv[ct]]; bbv[ct] = g2[colv[ct]]; }
#pragma unroll
        for (int rt = 0; rt < 2; rt++)
#pragma unroll
        for (int i = 0; i < 4; i++) {
            const int rl = rowbase + 16 * rt + quad * 4 + i;
            float s = 0.f, s2 = 0.f;
#pragma unroll
            for (int ct = 0; ct < 4; ct++) {
                const float c = acc[rt][ct][i] + bv[ct];
                s += c; s2 += c * c;
            }
#pragma unroll
            for (int o = 8; o > 0; o >>= 1) { s += __shfl_xor(s, o, 64); s2 += __shfl_xor(s2, o, 64); }
            if (l16 == 0) { sredA[rl][colg] = s; sredB[rl][colg] = s2; }
        }
        __syncthreads();
#pragma unroll
        for (int rt = 0; rt < 2; rt++)
#pragma unroll
        for (int i = 0; i < 4; i++) {
            const int rl = rowbase + 16 * rt + quad * 4 + i;
            const float s = sredA[rl][0] + sredA[rl][1] + sredA[rl][2] + sredA[rl][3];
            const float s2 = sredB[rl][0] + sredB[rl][1] + sredB[rl][2] + sredB[rl][3];
            const float mu = s * (1.f / D_);
            const float rs = rsqrtf(s2 * (1.f / D_) - mu * mu + 1e-5f);
#pragma unroll
            for (int ct = 0; ct < 4; ct++) {
                const float c = acc[rt][ct][i] + bv[ct];
                out[(size_t)(row0 + rl) * D_ + colv[ct]] = split_pack((c - mu) * rs * gv[ct] + bbv[ct]);
            }
        }
    } else {
#pragma unroll
        for (int rt = 0; rt < 2; rt++)
#pragma unroll
        for (int i = 0; i < 4; i++) {
            const int rl = rowbase + 16 * rt + quad * 4 + i;
#pragma unroll
            for (int ct = 0; ct < 4; ct++) {
                const float c = acc[rt][ct][i] + bv[ct];
                out[(size_t)(row0 + rl) * D_ + colv[ct]] = split_pack((c >= 0.f) ? c : 0.2f * c);
            }
        }
    }
}

// ---------- reset kmax slots ----------
__global__ void k_reset(int* slots) {
    if (threadIdx.x < 4) {
        const int i = __float_as_int(-INFINITY);
        slots[threadIdx.x] = (i >= 0) ? i : (i ^ 0x7fffffff);
    }
}

// ---------- MFMA global k-max (packed K input) ----------
__global__ void __launch_bounds__(256) k_dmax(
    const unsigned* __restrict__ kg, const unsigned* __restrict__ P2, int* __restrict__ slot)
{
    __shared__ __align__(16) ushort A2s[64 * 136];
    __shared__ __align__(16) ushort Ps[128 * 136];
    __shared__ float sred[4];
    const int t = threadIdx.x;
    const size_t row0 = (size_t)(blockIdx.x >> 1) * 64;
    const int m0 = (blockIdx.x & 1) * 128;
    {
        const int row = t >> 2, kq = (t & 3) * 8;
        const unsigned* src = kg + (row0 + row) * DH_ + kq;
        const uint4 f0 = *(const uint4*)src;
        const uint4 f1 = *(const uint4*)(src + 4);
        const unsigned uu[8] = {f0.x, f0.y, f0.z, f0.w, f1.x, f1.y, f1.z, f1.w};
#pragma unroll
        for (int i = 0; i < 4; i++) {
            *(uint4*)&A2s[row * 136 + ((t & 3) * 4 + i) * 8] =
                make_uint4(dup_lo(uu[2 * i]), dup_hi(uu[2 * i]), dup_lo(uu[2 * i + 1]), dup_hi(uu[2 * i + 1]));
        }
    }
    {
        const int col = t >> 1;
        const unsigned* src = P2 + (m0 + col) * DH_ + (t & 1) * 16;
#pragma unroll
        for (int i = 0; i < 8; i++) {
            const unsigned u0 = src[2 * i], u1 = src[2 * i + 1];
            *(uint4*)&Ps[col * 136 + ((t & 1) * 8 + i) * 8] = make_uint4(u0, u0, u1, u1);
        }
    }
    __syncthreads();
    const int w = t >> 6, lane = t & 63, quad = lane >> 4, l16 = lane & 15;
    floatx4 acc[4][2];
#pragma unroll
    for (int rt = 0; rt < 4; rt++)
#pragma unroll
        for (int ct = 0; ct < 2; ct++) acc[rt][ct] = (floatx4){0.f, 0.f, 0.f, 0.f};
#pragma unroll
    for (int kk = 0; kk < 4; kk++) {
        short8 af[4], bf[2];
#pragma unroll
        for (int rt = 0; rt < 4; rt++)
            af[rt] = *(const short8*)&A2s[(rt * 16 + l16) * 136 + (kk * 4 + quad) * 8];
#pragma unroll
        for (int ct = 0; ct < 2; ct++)
            bf[ct] = *(const short8*)&Ps[((w * 2 + ct) * 16 + l16) * 136 + (kk * 4 + quad) * 8];
#pragma unroll
        for (int rt = 0; rt < 4; rt++)
#pragma unroll
            for (int ct = 0; ct < 2; ct++)
                acc[rt][ct] = __builtin_amdgcn_mfma_f32_16x16x32_bf16(af[rt], bf[ct], acc[rt][ct], 0, 0, 0);
    }
    float mx = -INFINITY;
#pragma unroll
    for (int rt = 0; rt < 4; rt++)
#pragma unroll
        for (int ct = 0; ct < 2; ct++)
#pragma unroll
            for (int i = 0; i < 4; i++) mx = fmaxf(mx, acc[rt][ct][i]);
#pragma unroll
    for (int o = 32; o > 0; o >>= 1) mx = fmaxf(mx, __shfl_xor(mx, o, 64));
    if (lane == 0) sred[w] = mx;
    __syncthreads();
    if (t == 0) {
        const float m4 = fmaxf(fmaxf(sred[0], sred[1]), fmaxf(sred[2], sred[3]))
                       * 0.42044820762685725f;
        const int i = __float_as_int(m4);
        atomicMax(slot, (i >= 0) ? i : (i ^ 0x7fffffff));
    }
}

// ---------- full-MFMA performer attention v2 (packed I/O), 1024 threads ----------
__global__ void __launch_bounds__(1024) k_attn2(
    const unsigned* __restrict__ qg, const unsigned* __restrict__ kg, const unsigned* __restrict__ vg,
    const unsigned* __restrict__ P2, const int* __restrict__ slot,
    unsigned* __restrict__ outp)
{
    extern __shared__ char smem[];
    ushort* sA    = (ushort*)(smem);            // [128][136]: K-split
    ushort* sB    = (ushort*)(smem + 34816);    // [64][136]: P-quarter {h,l,h,l}
    ushort* sBig  = (ushort*)(smem + 52224);    // kpT [64][264]; later oRed f32[4096]
    ushort* sV    = (ushort*)(smem + 86016);    // [32][264]: v dup
    ushort* sCtx  = (ushort*)(smem + 102912);   // [32][520]: ctx dup
    float* sdk    = (float*)(smem + 136192);    // [128]
    float* sdq    = (float*)(smem + 136704);    // [128]
    float* smaxP  = (float*)(smem + 137216);    // [2][128]
    float* sdenP  = (float*)(smem + 138240);    // [2][128]
    float* sksum  = (float*)(smem + 139264);    // [256]
    float* sksP   = (float*)(smem + 140288);    // [16][32]

    const int bh = blockIdx.x;
    const int b = bh >> 3, hh = bh & 7;
    const int t = threadIdx.x;
    const int w = t >> 6, lane = t & 63, quad = lane >> 4, l16 = lane & 15;
    const int wg = w & 7, wh = w >> 3;
    const int nq = wg * 16 + l16;
    const unsigned* kb = kg + (size_t)bh * S_ * DH_;
    const unsigned* qb = qg + (size_t)bh * S_ * DH_;
    const unsigned* vb = vg + (size_t)bh * S_ * DH_;
    const float nrm = 0.42044820762685725f;
    const float diagc = 0.5f * nrm * nrm;
    const float ratio = 0.0625f;

    union U8 { uint4 u; short8 s; };

    // Q B-fragments into regs from packed
    short8 qf[4];
    {
        const unsigned* qrow = qb + (size_t)nq * DH_ + quad * 2;
#pragma unroll
        for (int ks = 0; ks < 4; ks++) {
            const uint2 qv = *(const uint2*)(qrow + ks * 8);
            U8 tmp; tmp.u = make_uint4(dup_lo(qv.x), dup_hi(qv.x), dup_lo(qv.y), dup_hi(qv.y));
            qf[ks] = tmp.s;
        }
    }

    if (t < 512) {
        const int row = t >> 2, seg = t & 3;
        const unsigned* src = kb + row * DH_ + seg * 8;
        const uint4 f0 = *(const uint4*)&src[0];
        const uint4 f1 = *(const uint4*)&src[4];
        const unsigned uu[8] = {f0.x, f0.y, f0.z, f0.w, f1.x, f1.y, f1.z, f1.w};
#pragma unroll
        for (int p = 0; p < 4; p++) {
            *(uint4*)&sA[row * 136 + seg * 32 + p * 8] =
                make_uint4(dup_lo(uu[2 * p]), dup_hi(uu[2 * p]), dup_lo(uu[2 * p + 1]), dup_hi(uu[2 * p + 1]));
        }
    } else {
        const int tt2 = t - 512;
        const int n = tt2 & 127, d0 = (tt2 >> 7) * 8;
        const unsigned* src = vb + n * DH_ + d0;
        const uint4 f0 = *(const uint4*)&src[0];
        const uint4 f1 = *(const uint4*)&src[4];
        const unsigned uu[8] = {f0.x, f0.y, f0.z, f0.w, f1.x, f1.y, f1.z, f1.w};
        unsigned* dst = (unsigned*)sV;
#pragma unroll
        for (int j = 0; j < 8; j++)
            dst[(d0 + j) * 132 + n] = dup_lo(uu[j]);
    }
    if (t < 128) {
        float s = 0.f, s2 = 0.f;
#pragma unroll
        for (int d4 = 0; d4 < DH_ / 4; d4++) {
            const uint4 kk = *(const uint4*)&kb[t * DH_ + d4 * 4];
            const float k0 = rec(kk.x), k1 = rec(kk.y), k2 = rec(kk.z), k3 = rec(kk.w);
            s += k0 * k0 + k1 * k1 + k2 * k2 + k3 * k3;
            const uint4 qq = *(const uint4*)&qb[t * DH_ + d4 * 4];
            const float q0 = rec(qq.x), q1 = rec(qq.y), q2 = rec(qq.z), q3 = rec(qq.w);
            s2 += q0 * q0 + q1 * q1 + q2 * q2 + q3 * q3;
        }
        sdk[t] = s * diagc;
        sdq[t] = s2 * diagc;
    }
    float kmaxv;
    { const int iv = *slot; kmaxv = __int_as_float((iv >= 0) ? iv : (iv ^ 0x7fffffff)); }
    __syncthreads();

    // adq[j][mtl]: qp dd for this wave's qds (wh=1 -> qd {0,2}; wh=0 -> qd {1,3})
    floatx4 adq[2][4];
#pragma unroll
    for (int j = 0; j < 2; j++)
#pragma unroll
        for (int mtl = 0; mtl < 4; mtl++) adq[j][mtl] = (floatx4){0.f, 0.f, 0.f, 0.f};

#pragma unroll
    for (int qd = 0; qd < 4; qd++) {
        // stage P quarter
        {
            const int col = t >> 4, ch2 = t & 15;
            const unsigned* src = P2 + (size_t)(qd * 64 + col) * DH_ + ch2 * 2;
            const unsigned u0 = src[0], u1 = src[1];
            *(uint4*)&sB[col * 136 + ch2 * 8] = make_uint4(u0, u0, u1, u1);
        }
        __syncthreads();
        // phase B: kp MFMAs (all 16 waves) + exp/split/pack + ksum partials
        floatx4 acc[2];
        acc[0] = (floatx4){0.f, 0.f, 0.f, 0.f};
        acc[1] = (floatx4){0.f, 0.f, 0.f, 0.f};
#pragma unroll
        for (int ks = 0; ks < 4; ks++) {
            const short8 af = *(const short8*)&sA[nq * 136 + ks * 32 + quad * 8];
            short8 bf[2];
#pragma unroll
            for (int ctl = 0; ctl < 2; ctl++)
                bf[ctl] = *(const short8*)&sB[((2 * wh + ctl) * 16 + l16) * 136 + ks * 32 + quad * 8];
#pragma unroll
            for (int ctl = 0; ctl < 2; ctl++)
                acc[ctl] = __builtin_amdgcn_mfma_f32_16x16x32_bf16(af, bf[ctl], acc[ctl], 0, 0, 0);
        }
        unsigned* kpT = (unsigned*)sBig;
        float kc[2];
#pragma unroll
        for (int ctl = 0; ctl < 2; ctl++) {
            float kcl = 0.f;
            unsigned pk[4];
#pragma unroll
            for (int i = 0; i < 4; i++) {
                const int n = wg * 16 + quad * 4 + i;
                const float kp = ratio * (exp2f((acc[ctl][i] * nrm - sdk[n] - kmaxv) * LOG2E) + 1e-4f);
                kcl += kp;
                pk[i] = split_pack(kp);
            }
            *(uint4*)&kpT[((2 * wh + ctl) * 16 + l16) * 132 + wg * 16 + quad * 4] =
                make_uint4(pk[0], pk[1], pk[2], pk[3]);
            kc[ctl] = kcl;
        }
#pragma unroll
        for (int ctl = 0; ctl < 2; ctl++) {
            kc[ctl] += __shfl_xor(kc[ctl], 16, 64);
            kc[ctl] += __shfl_xor(kc[ctl], 32, 64);
        }
        if (quad == 0) {
            sksP[w * 32 + l16] = kc[0];
            sksP[w * 32 + 16 + l16] = kc[1];
        }
        __syncthreads();
        // phase C: one half does qp MFMAs (B from regs), other half does ctx MFMAs
        const int qown = (qd & 1) ^ 1;
        if (wh == qown) {
            const int aidx = qd >> 1;
#pragma unroll
            for (int mtl = 0; mtl < 4; mtl++)
#pragma unroll
                for (int ks = 0; ks < 4; ks++) {
                    const short8 af2 = *(const short8*)&sB[(mtl * 16 + l16) * 136 + ks * 32 + quad * 8];
                    adq[aidx][mtl] = __builtin_amdgcn_mfma_f32_16x16x32_bf16(af2, qf[ks], adq[aidx][mtl], 0, 0, 0);
                }
        } else {
            const int mt = wg & 3, dt = wg >> 2;
            floatx4 cacc = (floatx4){0.f, 0.f, 0.f, 0.f};
#pragma unroll
            for (int ks = 0; ks < 8; ks++) {
                const short8 a = *(const short8*)&sBig[(mt * 16 + l16) * 264 + ks * 32 + quad * 8];
                const short8 bvv = *(const short8*)&sV[(dt * 16 + l16) * 264 + ks * 32 + quad * 8];
                cacc = __builtin_amdgcn_mfma_f32_16x16x32_bf16(a, bvv, cacc, 0, 0, 0);
            }
            unsigned* ctxB = (unsigned*)sCtx;
            unsigned pk2[4];
#pragma unroll
            for (int i = 0; i < 4; i++) pk2[i] = (unsigned)bf16_rn(cacc[i]) * 0x10001u;
            *(uint4*)&ctxB[(dt * 16 + l16) * 260 + qd * 64 + mt * 16 + quad * 4] =
                make_uint4(pk2[0], pk2[1], pk2[2], pk2[3]);
        }
        if (t < 64) {
            float s = 0.f;
#pragma unroll
            for (int wg2 = 0; wg2 < 8; wg2++)
                s += sksP[((t >> 5) * 8 + wg2) * 32 + (t & 31)];
            sksum[qd * 64 + t] = s;
        }
        __syncthreads();
    }

    // row max over this wave's half of (qd,m); union across wh = full m range
    {
        float mxn = -INFINITY;
#pragma unroll
        for (int j = 0; j < 2; j++)
#pragma unroll
            for (int mtl = 0; mtl < 4; mtl++)
#pragma unroll
                for (int i = 0; i < 4; i++) mxn = fmaxf(mxn, adq[j][mtl][i]);
        mxn = fmaxf(mxn, __shfl_xor(mxn, 16, 64));
        mxn = fmaxf(mxn, __shfl_xor(mxn, 32, 64));
        if (quad == 0) smaxP[wh * 128 + nq] = mxn;
    }
    __syncthreads();
    const float dmq = sdq[nq] + fmaxf(smaxP[nq], smaxP[128 + nq]) * nrm;

    // o^T[d][n]: A = ctx^T from sCtx (dup), B = exp+split of adq straight from regs.
    floatx4 oT[2];
    oT[0] = (floatx4){0.f, 0.f, 0.f, 0.f};
    oT[1] = (floatx4){0.f, 0.f, 0.f, 0.f};
    float dp = 0.f;
#pragma unroll
    for (int j = 0; j < 2; j++) {
        const int qdo = 2 * j + (wh ^ 1);
#pragma unroll
        for (int mtl = 0; mtl < 4; mtl++) {
            unsigned pk[4];
#pragma unroll
            for (int i = 0; i < 4; i++) {
                const float qp = ratio * (exp2f((adq[j][mtl][i] * nrm - dmq) * LOG2E) + 1e-4f);
                dp += qp * sksum[qdo * 64 + mtl * 16 + quad * 4 + i];
                pk[i] = split_pack(qp);
            }
            U8 tb; tb.u = make_uint4(pk[0], pk[1], pk[2], pk[3]);
#pragma unroll
            for (int dt = 0; dt < 2; dt++) {
                const short8 actx = *(const short8*)&sCtx[(dt * 16 + l16) * 520 + qdo * 128 + mtl * 32 + quad * 8];
                oT[dt] = __builtin_amdgcn_mfma_f32_16x16x32_bf16(actx, tb.s, oT[dt], 0, 0, 0);
            }
        }
    }
    dp += __shfl_xor(dp, 16, 64);
    dp += __shfl_xor(dp, 32, 64);
    if (quad == 0) sdenP[wh * 128 + nq] = dp;

    // cross-half o reduction through dead kpT space, then coalesced packed store
    float* oRed = (float*)sBig;
    if (wh == 1) {
#pragma unroll
        for (int dt = 0; dt < 2; dt++)
            *(floatx4*)&oRed[((wg * 2 + dt) * 64 + lane) * 4] = oT[dt];
    }
    __syncthreads();
    if (wh == 0) {
        const float inv = 1.0f / (sdenP[nq] + sdenP[128 + nq]);
#pragma unroll
        for (int dt = 0; dt < 2; dt++) {
            const floatx4 o2 = *(const floatx4*)&oRed[((wg * 2 + dt) * 64 + lane) * 4];
            const unsigned r0 = split_pack((oT[dt][0] + o2[0]) * inv);
            const unsigned r1 = split_pack((oT[dt][1] + o2[1]) * inv);
            const unsigned r2 = split_pack((oT[dt][2] + o2[2]) * inv);
            const unsigned r3 = split_pack((oT[dt][3] + o2[3]) * inv);
            *(uint4*)&outp[((size_t)b * S_ + nq) * D_ + hh * DH_ + dt * 16 + quad * 4] =
                make_uint4(r0, r1, r2, r3);
        }
    }
}

// ---------- classification head (packed input) ----------
__global__ void __launch_bounds__(256) k_head(
    const unsigned* __restrict__ hfin, const float* __restrict__ h1w, const float* __restrict__ h1b,
    const float* __restrict__ h2w, const float* __restrict__ h2b,
    const float* __restrict__ ow, const float* __restrict__ ob, float* __restrict__ outp)
{
    __shared__ float c0[D_];
    __shared__ float c1[2 * HID_];
    __shared__ float sred[4];
    const int t = threadIdx.x;
    const int b = blockIdx.x;
    c0[t] = rec(hfin[(size_t)b * S_ * D_ + t]);
    __syncthreads();
#pragma unroll
    for (int half = 0; half < 2; half++) {
        const int j = half * 256 + t;
        float a = h1b[j];
        const float* w = h1w + (size_t)j * D_;
        for (int d = 0; d < D_; d += 4) {
            const float4 w4 = *(const float4*)&w[d];
            const float4 x4 = *(const float4*)&c0[d];
            a += x4.x * w4.x + x4.y * w4.y + x4.z * w4.z + x4.w * w4.w;
        }
        c1[j] = (a >= 0.f) ? a : 0.2f * a;
    }
    __syncthreads();
    float a2 = h2b[t];
    const float* w2 = h2w + (size_t)t * (2 * HID_);
    for (int j = 0; j < 2 * HID_; j += 4) {
        const float4 w4 = *(const float4*)&w2[j];
        const float4 x4 = *(const float4*)&c1[j];
        a2 += x4.x * w4.x + x4.y * w4.y + x4.z * w4.z + x4.w * w4.w;
    }
    const float c2 = (a2 >= 0.f) ? a2 : 0.2f * a2;
    const float s = blk_sum(c2 * ow[t], sred);
    if (t == 0) outp[b] = s + ob[0];
}

extern "C" void kernel_launch(void* const* d_in, const int* in_sizes, int n_in,
                              void* d_out, int out_size, void* d_ws, size_t ws_size,
                              hipStream_t stream)
{
    const float* x     = (const float*)d_in[0];
    const int*   mask  = (const int*)d_in[1];
    const float* emb_w = (const float*)d_in[2];
    const float* emb_b = (const float*)d_in[3];
    const float* Wq    = (const float*)d_in[4];
    const float* bq    = (const float*)d_in[5];
    const float* Wk    = (const float*)d_in[6];
    const float* bk    = (const float*)d_in[7];
    const float* Wv    = (const float*)d_in[8];
    const float* bv    = (const float*)d_in[9];
    const float* Wo    = (const float*)d_in[10];
    const float* bo    = (const float*)d_in[11];
    const float* proj  = (const float*)d_in[12];
    const float* n1w   = (const float*)d_in[13];
    const float* n1b   = (const float*)d_in[14];
    const float* n2w   = (const float*)d_in[15];
    const float* n2b   = (const float*)d_in[16];
    const float* f1w   = (const float*)d_in[17];
    const float* f1b   = (const float*)d_in[18];
    const float* f2w   = (const float*)d_in[19];
    const float* f2b   = (const float*)d_in[20];
    const float* h1w   = (const float*)d_in[21];
    const float* h1b   = (const float*)d_in[22];
    const float* h2w   = (const float*)d_in[23];
    const float* h2b   = (const float*)d_in[24];
    const float* ow    = (const float*)d_in[25];
    const float* ob    = (const float*)d_in[26];

    const size_t BSD = (size_t)B_ * S_ * D_;
    unsigned* A = (unsigned*)d_ws;                 // packed activations
    unsigned* Q = A + BSD;
    unsigned* K = Q + BSD;
    unsigned* V = K + BSD;
    unsigned* T = K;                               // post-LN1 alias (K dead after attn)
    unsigned* W2 = V + BSD;                        // compact split weights: 6 x L x 65536 uints
    const size_t WT = (size_t)L_ * 256 * 256;
    const size_t WM = (size_t)256 * 256;
    unsigned* P2 = W2 + 6 * WT;                    // compact split proj: L x 256 x 32 uints
    int* slots = (int*)(P2 + (size_t)L_ * M_ * DH_);

    k_wconv<<<256, 256, 0, stream>>>(Wq,  W2 + 0 * WT);
    k_wconv<<<256, 256, 0, stream>>>(Wk,  W2 + 1 * WT);
    k_wconv<<<256, 256, 0, stream>>>(Wv,  W2 + 2 * WT);
    k_wconv<<<256, 256, 0, stream>>>(Wo,  W2 + 3 * WT);
    k_wconv<<<256, 256, 0, stream>>>(f1w, W2 + 4 * WT);
    k_wconv<<<256, 256, 0, stream>>>(f2w, W2 + 5 * WT);
    k_wconv<<<32, 256, 0, stream>>>(proj, P2);
    k_reset<<<1, 64, 0, stream>>>(slots);

    const int GB = B_ * S_ / 64;               // 512 blocks per GEMM
    const int DB = B_ * H_ * S_ / 64 * 2;      // 8192 blocks for k_dmax
    const size_t ATTN_LDS = 142336;            // 139 KB dynamic LDS

    k_embed<<<B_ * S_ * D_ / 256, 256, 0, stream>>>(x, emb_w, emb_b, A);
    for (int l = 0; l < L_; l++) {
        const unsigned* P2l = P2 + (size_t)l * M_ * DH_;
        k_gemm<0><<<GB, 512, 0, stream>>>(A, W2 + 0 * WT + l * WM, bq + l * D_, nullptr, nullptr, nullptr, Q);
        k_gemm<0><<<GB, 512, 0, stream>>>(A, W2 + 1 * WT + l * WM, bk + l * D_, nullptr, nullptr, nullptr, K);
        k_gemm<1><<<GB, 512, 0, stream>>>(A, W2 + 2 * WT + l * WM, bv + l * D_, nullptr, nullptr, mask, V);
        k_dmax<<<DB, 256, 0, stream>>>(K, P2l, slots + l);
        k_attn2<<<B_ * H_, 1024, ATTN_LDS, stream>>>(Q, K, V, P2l, slots + l, A);
        k_gemm<2><<<GB, 512, 0, stream>>>(A, W2 + 3 * WT + l * WM, bo + l * D_, n1w + l * D_, n1b + l * D_, nullptr, T);
        k_gemm<3><<<GB, 512, 0, stream>>>(T, W2 + 4 * WT + l * WM, f1b + l * HID_, nullptr, nullptr, nullptr, Q);
        k_gemm<2><<<GB, 512, 0, stream>>>(Q, W2 + 5 * WT + l * WM, f2b + l * D_, n2w + l * D_, n2b + l * D_, nullptr, A);
    }
    k_head<<<B_, 256, 0, stream>>>(A, h1w, h1b, h2w, h2b, ow, ob, (float*)d_out);
}

// Round 3
// 1768.480 us; speedup vs baseline: 1.1492x; 1.0957x over previous
//
#include <hip/hip_runtime.h>
#include <math.h>

#define B_ 256
#define N_ 127
#define S_ 128
#define NDIM_ 3
#define D_ 256
#define H_ 8
#define DH_ 32
#define M_ 256
#define HID_ 256
#define L_ 4
#define LOG2E 1.44269504088896340736f

typedef __attribute__((ext_vector_type(8))) short short8;
typedef __attribute__((ext_vector_type(4))) float floatx4;

// ---------- bf16 split helpers ----------
// Canonical activation format: packed uint  u = h | (l<<16)  where
// h = bf16_rn(x), l = bf16_rn(x - h). Same 4 B as fp32.
__device__ __forceinline__ ushort bf16_rn(float x) {
    unsigned u = __float_as_uint(x);
    u = (u + 0x7fffu + ((u >> 16) & 1u)) >> 16;
    return (ushort)u;
}
__device__ __forceinline__ unsigned split_pack(float x) {
    const ushort h = bf16_rn(x);
    const float r = x - __uint_as_float(((unsigned)h) << 16);
    const ushort l = bf16_rn(r);
    return (unsigned)h | ((unsigned)l << 16);
}
// {h,h} as two bf16 lanes
__device__ __forceinline__ unsigned dup_lo(unsigned u) {
    const unsigned h = u & 0xffffu;
    return h | (h << 16);
}
// {l,l} as two bf16 lanes
__device__ __forceinline__ unsigned dup_hi(unsigned u) {
    const unsigned l = u >> 16;
    return l | (l << 16);
}
// reconstruct fp32 ~= h + l (error ~2^-17 relative)
__device__ __forceinline__ float rec(unsigned u) {
    return __uint_as_float(u << 16) + __uint_as_float(u & 0xffff0000u);
}
// pack low halves of two packed uints: {h0, h1} as bf16x2
__device__ __forceinline__ unsigned hpair(unsigned u0, unsigned u1) {
    return (u0 & 0xffffu) | (u1 << 16);
}
// pack high halves: {l0, l1} as bf16x2
__device__ __forceinline__ unsigned lpair(unsigned u0, unsigned u1) {
    return (u0 >> 16) | (u1 & 0xffff0000u);
}

// ---------- block reductions ----------
__device__ __forceinline__ float blk_sum(float v, float* sred) {
#pragma unroll
    for (int o = 32; o > 0; o >>= 1) v += __shfl_xor(v, o, 64);
    if ((threadIdx.x & 63) == 0) sred[threadIdx.x >> 6] = v;
    __syncthreads();
    v = sred[0] + sred[1] + sred[2] + sred[3];
    __syncthreads();
    return v;
}

// ---------- embedding (emits packed) ----------
__global__ void k_embed(const float* __restrict__ x, const float* __restrict__ ew,
                        const float* __restrict__ eb, unsigned* __restrict__ h) {
    const int idx = blockIdx.x * 256 + threadIdx.x;
    const int d = idx & (D_ - 1);
    const int n = (idx >> 8) & (S_ - 1);
    const int b = idx >> 15;
    float val = 0.f;
    if (n > 0) {
        const float* xr = x + ((size_t)b * N_ + (n - 1)) * NDIM_;
        val = eb[d] + xr[0] * ew[d * 3 + 0] + xr[1] * ew[d * 3 + 1] + xr[2] * ew[d * 3 + 2];
    }
    h[idx] = split_pack(val);
}

// ---------- weight pre-split (compact): fp32 -> uint [h|l<<16] ----------
__global__ void __launch_bounds__(256) k_wconv(const float* __restrict__ src, unsigned* __restrict__ dst) {
    const int idx = (blockIdx.x * 256 + threadIdx.x) * 4;
    const float4 w4 = *(const float4*)&src[idx];
    const float v[4] = {w4.x, w4.y, w4.z, w4.w};
    unsigned u[4];
#pragma unroll
    for (int i = 0; i < 4; i++) u[i] = split_pack(v[i]);
    *(uint4*)&dst[idx] = make_uint4(u[0], u[1], u[2], u[3]);
}

// ---------- 3-product split MFMA GEMM ----------
// C = Ah*Wh + Ah*Wl + Al*Wh (l*l dropped, ~2^-18 rel). Non-duplicated h/l
// planes in LDS: fragment reads are 12 b128 per K32 (vs 24 dup'd), MFMAs
// 24 (vs 32), staging bytes halved. K-step = 32 fp32 (full MFMA K-depth),
// 8 steps, single buffer, 2 barriers/step with register prefetch of s+1.
template<int EPI>
__global__ void __launch_bounds__(512, 4) k_gemm(
    const unsigned* __restrict__ Ap, const unsigned* __restrict__ W2,
    const float* __restrict__ bias, const float* __restrict__ g1,
    const float* __restrict__ g2, const int* __restrict__ mask,
    unsigned* __restrict__ out)
{
    __shared__ ushort sAh[4 * 520];            // [chunk][64 rows][8] (+pad 8/chunk)
    __shared__ ushort sAl[4 * 520];
    __shared__ ushort sWh[4 * 2048];           // [chunk][256 cols][8]
    __shared__ ushort sWl[4 * 2048];
    __shared__ float sredA[64][4], sredB[64][4];
    const int t = threadIdx.x;
    const int w = t >> 6, lane = t & 63;
    const int quad = lane >> 4, l16 = lane & 15;
    const int rowbase = 32 * (w >> 2), colbase = 64 * (w & 3);
    const int colg = w & 3;
    const int row0 = blockIdx.x * 64;

    floatx4 acc[2][4];
#pragma unroll
    for (int rt = 0; rt < 2; rt++)
#pragma unroll
        for (int ct = 0; ct < 4; ct++) acc[rt][ct] = (floatx4){0.f, 0.f, 0.f, 0.f};

    // staging assignment: every thread does one A quad (4 fp32) + one W half-row (16 fp32)
    const int arow = t >> 3, akq = t & 7;           // A: 64 rows x 8 k-quads
    const int wrow = t >> 1, whalf = t & 1;         // W: 256 cols x 2 k-halves
    const unsigned* AG = Ap + (size_t)(row0 + arow) * D_ + akq * 4;
    const unsigned* WG = W2 + (size_t)wrow * 256 + whalf * 16;
    const int aidx = (akq >> 1) * 520 + arow * 8 + (akq & 1) * 4;
    const int wi0 = (whalf * 2) * 2048 + wrow * 8;

#define STAGE_GEMM(a4, p0, p1, p2, p3)                                              \
    {                                                                               \
        *(uint2*)&sAh[aidx] = make_uint2(hpair(a4.x, a4.y), hpair(a4.z, a4.w));     \
        *(uint2*)&sAl[aidx] = make_uint2(lpair(a4.x, a4.y), lpair(a4.z, a4.w));     \
        *(uint4*)&sWh[wi0] = make_uint4(hpair(p0.x, p0.y), hpair(p0.z, p0.w),       \
                                        hpair(p1.x, p1.y), hpair(p1.z, p1.w));      \
        *(uint4*)&sWl[wi0] = make_uint4(lpair(p0.x, p0.y), lpair(p0.z, p0.w),       \
                                        lpair(p1.x, p1.y), lpair(p1.z, p1.w));      \
        *(uint4*)&sWh[wi0 + 2048] = make_uint4(hpair(p2.x, p2.y), hpair(p2.z, p2.w),\
                                               hpair(p3.x, p3.y), hpair(p3.z, p3.w));\
        *(uint4*)&sWl[wi0 + 2048] = make_uint4(lpair(p2.x, p2.y), lpair(p2.z, p2.w),\
                                               lpair(p3.x, p3.y), lpair(p3.z, p3.w));\
    }

    {
        const uint4 a4 = *(const uint4*)AG;
        const uint4 p0 = *(const uint4*)(WG);
        const uint4 p1 = *(const uint4*)(WG + 4);
        const uint4 p2 = *(const uint4*)(WG + 8);
        const uint4 p3 = *(const uint4*)(WG + 12);
        STAGE_GEMM(a4, p0, p1, p2, p3);
    }
    __syncthreads();

    for (int s = 0; s < 8; s++) {
        // (1) issue global loads for s+1 into registers
        uint4 a_n, p0_n, p1_n, p2_n, p3_n;
        if (s + 1 < 8) {
            a_n = *(const uint4*)(AG + (s + 1) * 32);
            p0_n = *(const uint4*)(WG + (s + 1) * 32);
            p1_n = *(const uint4*)(WG + (s + 1) * 32 + 4);
            p2_n = *(const uint4*)(WG + (s + 1) * 32 + 8);
            p3_n = *(const uint4*)(WG + (s + 1) * 32 + 12);
        }
        // (2) fragments + 24 MFMAs from LDS
        short8 ah[2], al[2], wh[4], wl[4];
#pragma unroll
        for (int rt = 0; rt < 2; rt++) {
            const int ai = quad * 520 + (rowbase + 16 * rt + l16) * 8;
            ah[rt] = *(const short8*)&sAh[ai];
            al[rt] = *(const short8*)&sAl[ai];
        }
#pragma unroll
        for (int ct = 0; ct < 4; ct++) {
            const int wi = quad * 2048 + (colbase + 16 * ct + l16) * 8;
            wh[ct] = *(const short8*)&sWh[wi];
            wl[ct] = *(const short8*)&sWl[wi];
        }
#pragma unroll
        for (int rt = 0; rt < 2; rt++)
#pragma unroll
            for (int ct = 0; ct < 4; ct++) {
                acc[rt][ct] = __builtin_amdgcn_mfma_f32_16x16x32_bf16(ah[rt], wh[ct], acc[rt][ct], 0, 0, 0);
                acc[rt][ct] = __builtin_amdgcn_mfma_f32_16x16x32_bf16(ah[rt], wl[ct], acc[rt][ct], 0, 0, 0);
                acc[rt][ct] = __builtin_amdgcn_mfma_f32_16x16x32_bf16(al[rt], wh[ct], acc[rt][ct], 0, 0, 0);
            }
        // (3) overwrite LDS with s+1 between two barriers
        if (s + 1 < 8) {
            __syncthreads();
            STAGE_GEMM(a_n, p0_n, p1_n, p2_n, p3_n);
            __syncthreads();
        }
    }
#undef STAGE_GEMM

    int colv[4]; float bv[4];
#pragma unroll
    for (int ct = 0; ct < 4; ct++) { colv[ct] = colbase + 16 * ct + l16; bv[ct] = bias[colv[ct]]; }

    if (EPI <= 1) {
        const int b = row0 >> 7;
#pragma unroll
        for (int rt = 0; rt < 2; rt++)
#pragma unroll
        for (int i = 0; i < 4; i++) {
            const int rl = rowbase + 16 * rt + quad * 4 + i;
            const int n = (row0 + rl) & (S_ - 1);
            float keep = 1.f;
            if (EPI == 1) keep = (n == 0) ? 1.f : (mask[b * N_ + n - 1] ? 0.f : 1.f);
#pragma unroll
            for (int ct = 0; ct < 4; ct++) {
                float c = acc[rt][ct][i] + bv[ct];
                if (EPI == 1) c *= keep;
                const int col = colv[ct];
                out[(((size_t)b * H_ + (col >> 5)) * S_ + n) * DH_ + (col & 31)] = split_pack(c);
            }
        }
    } else if (EPI == 2) {
        float gv[4], bbv[4];
#pragma unroll
        for (int ct = 0; ct < 4; ct++) { gv[ct] = g1[colv[ct]]; bbv[ct] = g2[colv[ct]]; }
#pragma unroll
        for (int rt = 0; rt < 2; rt++)
#pragma unroll
        for (int i = 0; i < 4; i++) {
            const int rl = rowbase + 16 * rt + quad * 4 + i;
            float s = 0.f, s2 = 0.f;
#pragma unroll
            for (int ct = 0; ct < 4; ct++) {
                const float c = acc[rt][ct][i] + bv[ct];
                s += c; s2 += c * c;
            }
#pragma unroll
            for (int o = 8; o > 0; o >>= 1) { s += __shfl_xor(s, o, 64); s2 += __shfl_xor(s2, o, 64); }
            if (l16 == 0) { sredA[rl][colg] = s; sredB[rl][colg] = s2; }
        }
        __syncthreads();
#pragma unroll
        for (int rt = 0; rt < 2; rt++)
#pragma unroll
        for (int i = 0; i < 4; i++) {
            const int rl = rowbase + 16 * rt + quad * 4 + i;
            const float s = sredA[rl][0] + sredA[rl][1] + sredA[rl][2] + sredA[rl][3];
            const float s2 = sredB[rl][0] + sredB[rl][1] + sredB[rl][2] + sredB[rl][3];
            const float mu = s * (1.f / D_);
            const float rs = rsqrtf(s2 * (1.f / D_) - mu * mu + 1e-5f);
#pragma unroll
            for (int ct = 0; ct < 4; ct++) {
                const float c = acc[rt][ct][i] + bv[ct];
                out[(size_t)(row0 + rl) * D_ + colv[ct]] = split_pack((c - mu) * rs * gv[ct] + bbv[ct]);
            }
        }
    } else {
#pragma unroll
        for (int rt = 0; rt < 2; rt++)
#pragma unroll
        for (int i = 0; i < 4; i++) {
            const int rl = rowbase + 16 * rt + quad * 4 + i;
#pragma unroll
            for (int ct = 0; ct < 4; ct++) {
                const float c = acc[rt][ct][i] + bv[ct];
                out[(size_t)(row0 + rl) * D_ + colv[ct]] = split_pack((c >= 0.f) ? c : 0.2f * c);
            }
        }
    }
}

// ---------- reset kmax slots ----------
__global__ void k_reset(int* slots) {
    if (threadIdx.x < 4) {
        const int i = __float_as_int(-INFINITY);
        slots[threadIdx.x] = (i >= 0) ? i : (i ^ 0x7fffffff);
    }
}

// ---------- MFMA global k-max (packed K input) ----------
__global__ void __launch_bounds__(256) k_dmax(
    const unsigned* __restrict__ kg, const unsigned* __restrict__ P2, int* __restrict__ slot)
{
    __shared__ __align__(16) ushort A2s[64 * 136];
    __shared__ __align__(16) ushort Ps[128 * 136];
    __shared__ float sred[4];
    const int t = threadIdx.x;
    const size_t row0 = (size_t)(blockIdx.x >> 1) * 64;
    const int m0 = (blockIdx.x & 1) * 128;
    {
        const int row = t >> 2, kq = (t & 3) * 8;
        const unsigned* src = kg + (row0 + row) * DH_ + kq;
        const uint4 f0 = *(const uint4*)src;
        const uint4 f1 = *(const uint4*)(src + 4);
        const unsigned uu[8] = {f0.x, f0.y, f0.z, f0.w, f1.x, f1.y, f1.z, f1.w};
#pragma unroll
        for (int i = 0; i < 4; i++) {
            *(uint4*)&A2s[row * 136 + ((t & 3) * 4 + i) * 8] =
                make_uint4(dup_lo(uu[2 * i]), dup_hi(uu[2 * i]), dup_lo(uu[2 * i + 1]), dup_hi(uu[2 * i + 1]));
        }
    }
    {
        const int col = t >> 1;
        const unsigned* src = P2 + (m0 + col) * DH_ + (t & 1) * 16;
#pragma unroll
        for (int i = 0; i < 8; i++) {
            const unsigned u0 = src[2 * i], u1 = src[2 * i + 1];
            *(uint4*)&Ps[col * 136 + ((t & 1) * 8 + i) * 8] = make_uint4(u0, u0, u1, u1);
        }
    }
    __syncthreads();
    const int w = t >> 6, lane = t & 63, quad = lane >> 4, l16 = lane & 15;
    floatx4 acc[4][2];
#pragma unroll
    for (int rt = 0; rt < 4; rt++)
#pragma unroll
        for (int ct = 0; ct < 2; ct++) acc[rt][ct] = (floatx4){0.f, 0.f, 0.f, 0.f};
#pragma unroll
    for (int kk = 0; kk < 4; kk++) {
        short8 af[4], bf[2];
#pragma unroll
        for (int rt = 0; rt < 4; rt++)
            af[rt] = *(const short8*)&A2s[(rt * 16 + l16) * 136 + (kk * 4 + quad) * 8];
#pragma unroll
        for (int ct = 0; ct < 2; ct++)
            bf[ct] = *(const short8*)&Ps[((w * 2 + ct) * 16 + l16) * 136 + (kk * 4 + quad) * 8];
#pragma unroll
        for (int rt = 0; rt < 4; rt++)
#pragma unroll
            for (int ct = 0; ct < 2; ct++)
                acc[rt][ct] = __builtin_amdgcn_mfma_f32_16x16x32_bf16(af[rt], bf[ct], acc[rt][ct], 0, 0, 0);
    }
    float mx = -INFINITY;
#pragma unroll
    for (int rt = 0; rt < 4; rt++)
#pragma unroll
        for (int ct = 0; ct < 2; ct++)
#pragma unroll
            for (int i = 0; i < 4; i++) mx = fmaxf(mx, acc[rt][ct][i]);
#pragma unroll
    for (int o = 32; o > 0; o >>= 1) mx = fmaxf(mx, __shfl_xor(mx, o, 64));
    if (lane == 0) sred[w] = mx;
    __syncthreads();
    if (t == 0) {
        const float m4 = fmaxf(fmaxf(sred[0], sred[1]), fmaxf(sred[2], sred[3]))
                       * 0.42044820762685725f;
        const int i = __float_as_int(m4);
        atomicMax(slot, (i >= 0) ? i : (i ^ 0x7fffffff));
    }
}

// ---------- full-MFMA performer attention v2 (packed I/O), 1024 threads ----------
__global__ void __launch_bounds__(1024) k_attn2(
    const unsigned* __restrict__ qg, const unsigned* __restrict__ kg, const unsigned* __restrict__ vg,
    const unsigned* __restrict__ P2, const int* __restrict__ slot,
    unsigned* __restrict__ outp)
{
    extern __shared__ char smem[];
    ushort* sA    = (ushort*)(smem);            // [128][136]: K-split
    ushort* sB    = (ushort*)(smem + 34816);    // [64][136]: P-quarter {h,l,h,l}
    ushort* sBig  = (ushort*)(smem + 52224);    // kpT [64][264]; later oRed f32[4096]
    ushort* sV    = (ushort*)(smem + 86016);    // [32][264]: v dup
    ushort* sCtx  = (ushort*)(smem + 102912);   // [32][520]: ctx dup
    float* sdk    = (float*)(smem + 136192);    // [128]
    float* sdq    = (float*)(smem + 136704);    // [128]
    float* smaxP  = (float*)(smem + 137216);    // [2][128]
    float* sdenP  = (float*)(smem + 138240);    // [2][128]
    float* sksum  = (float*)(smem + 139264);    // [256]
    float* sksP   = (float*)(smem + 140288);    // [16][32]

    const int bh = blockIdx.x;
    const int b = bh >> 3, hh = bh & 7;
    const int t = threadIdx.x;
    const int w = t >> 6, lane = t & 63, quad = lane >> 4, l16 = lane & 15;
    const int wg = w & 7, wh = w >> 3;
    const int nq = wg * 16 + l16;
    const unsigned* kb = kg + (size_t)bh * S_ * DH_;
    const unsigned* qb = qg + (size_t)bh * S_ * DH_;
    const unsigned* vb = vg + (size_t)bh * S_ * DH_;
    const float nrm = 0.42044820762685725f;
    const float diagc = 0.5f * nrm * nrm;
    const float ratio = 0.0625f;

    union U8 { uint4 u; short8 s; };

    // Q B-fragments into regs from packed
    short8 qf[4];
    {
        const unsigned* qrow = qb + (size_t)nq * DH_ + quad * 2;
#pragma unroll
        for (int ks = 0; ks < 4; ks++) {
            const uint2 qv = *(const uint2*)(qrow + ks * 8);
            U8 tmp; tmp.u = make_uint4(dup_lo(qv.x), dup_hi(qv.x), dup_lo(qv.y), dup_hi(qv.y));
            qf[ks] = tmp.s;
        }
    }

    if (t < 512) {
        const int row = t >> 2, seg = t & 3;
        const unsigned* src = kb + row * DH_ + seg * 8;
        const uint4 f0 = *(const uint4*)&src[0];
        const uint4 f1 = *(const uint4*)&src[4];
        const unsigned uu[8] = {f0.x, f0.y, f0.z, f0.w, f1.x, f1.y, f1.z, f1.w};
#pragma unroll
        for (int p = 0; p < 4; p++) {
            *(uint4*)&sA[row * 136 + seg * 32 + p * 8] =
                make_uint4(dup_lo(uu[2 * p]), dup_hi(uu[2 * p]), dup_lo(uu[2 * p + 1]), dup_hi(uu[2 * p + 1]));
        }
    } else {
        const int tt2 = t - 512;
        const int n = tt2 & 127, d0 = (tt2 >> 7) * 8;
        const unsigned* src = vb + n * DH_ + d0;
        const uint4 f0 = *(const uint4*)&src[0];
        const uint4 f1 = *(const uint4*)&src[4];
        const unsigned uu[8] = {f0.x, f0.y, f0.z, f0.w, f1.x, f1.y, f1.z, f1.w};
        unsigned* dst = (unsigned*)sV;
#pragma unroll
        for (int j = 0; j < 8; j++)
            dst[(d0 + j) * 132 + n] = dup_lo(uu[j]);
    }
    if (t < 128) {
        float s = 0.f, s2 = 0.f;
#pragma unroll
        for (int d4 = 0; d4 < DH_ / 4; d4++) {
            const uint4 kk = *(const uint4*)&kb[t * DH_ + d4 * 4];
            const float k0 = rec(kk.x), k1 = rec(kk.y), k2 = rec(kk.z), k3 = rec(kk.w);
            s += k0 * k0 + k1 * k1 + k2 * k2 + k3 * k3;
            const uint4 qq = *(const uint4*)&qb[t * DH_ + d4 * 4];
            const float q0 = rec(qq.x), q1 = rec(qq.y), q2 = rec(qq.z), q3 = rec(qq.w);
            s2 += q0 * q0 + q1 * q1 + q2 * q2 + q3 * q3;
        }
        sdk[t] = s * diagc;
        sdq[t] = s2 * diagc;
    }
    float kmaxv;
    { const int iv = *slot; kmaxv = __int_as_float((iv >= 0) ? iv : (iv ^ 0x7fffffff)); }
    __syncthreads();

    // adq[j][mtl]: qp dd for this wave's qds (wh=1 -> qd {0,2}; wh=0 -> qd {1,3})
    floatx4 adq[2][4];
#pragma unroll
    for (int j = 0; j < 2; j++)
#pragma unroll
        for (int mtl = 0; mtl < 4; mtl++) adq[j][mtl] = (floatx4){0.f, 0.f, 0.f, 0.f};

#pragma unroll
    for (int qd = 0; qd < 4; qd++) {
        // stage P quarter
        {
            const int col = t >> 4, ch2 = t & 15;
            const unsigned* src = P2 + (size_t)(qd * 64 + col) * DH_ + ch2 * 2;
            const unsigned u0 = src[0], u1 = src[1];
            *(uint4*)&sB[col * 136 + ch2 * 8] = make_uint4(u0, u0, u1, u1);
        }
        __syncthreads();
        // phase B: kp MFMAs (all 16 waves) + exp/split/pack + ksum partials
        floatx4 acc[2];
        acc[0] = (floatx4){0.f, 0.f, 0.f, 0.f};
        acc[1] = (floatx4){0.f, 0.f, 0.f, 0.f};
#pragma unroll
        for (int ks = 0; ks < 4; ks++) {
            const short8 af = *(const short8*)&sA[nq * 136 + ks * 32 + quad * 8];
            short8 bf[2];
#pragma unroll
            for (int ctl = 0; ctl < 2; ctl++)
                bf[ctl] = *(const short8*)&sB[((2 * wh + ctl) * 16 + l16) * 136 + ks * 32 + quad * 8];
#pragma unroll
            for (int ctl = 0; ctl < 2; ctl++)
                acc[ctl] = __builtin_amdgcn_mfma_f32_16x16x32_bf16(af, bf[ctl], acc[ctl], 0, 0, 0);
        }
        unsigned* kpT = (unsigned*)sBig;
        float kc[2];
#pragma unroll
        for (int ctl = 0; ctl < 2; ctl++) {
            float kcl = 0.f;
            unsigned pk[4];
#pragma unroll
            for (int i = 0; i < 4; i++) {
                const int n = wg * 16 + quad * 4 + i;
                const float kp = ratio * (exp2f((acc[ctl][i] * nrm - sdk[n] - kmaxv) * LOG2E) + 1e-4f);
                kcl += kp;
                pk[i] = split_pack(kp);
            }
            *(uint4*)&kpT[((2 * wh + ctl) * 16 + l16) * 132 + wg * 16 + quad * 4] =
                make_uint4(pk[0], pk[1], pk[2], pk[3]);
            kc[ctl] = kcl;
        }
#pragma unroll
        for (int ctl = 0; ctl < 2; ctl++) {
            kc[ctl] += __shfl_xor(kc[ctl], 16, 64);
            kc[ctl] += __shfl_xor(kc[ctl], 32, 64);
        }
        if (quad == 0) {
            sksP[w * 32 + l16] = kc[0];
            sksP[w * 32 + 16 + l16] = kc[1];
        }
        __syncthreads();
        // phase C: one half does qp MFMAs (B from regs), other half does ctx MFMAs
        const int qown = (qd & 1) ^ 1;
        if (wh == qown) {
            const int aidx = qd >> 1;
#pragma unroll
            for (int mtl = 0; mtl < 4; mtl++)
#pragma unroll
                for (int ks = 0; ks < 4; ks++) {
                    const short8 af2 = *(const short8*)&sB[(mtl * 16 + l16) * 136 + ks * 32 + quad * 8];
                    adq[aidx][mtl] = __builtin_amdgcn_mfma_f32_16x16x32_bf16(af2, qf[ks], adq[aidx][mtl], 0, 0, 0);
                }
        } else {
            const int mt = wg & 3, dt = wg >> 2;
            floatx4 cacc = (floatx4){0.f, 0.f, 0.f, 0.f};
#pragma unroll
            for (int ks = 0; ks < 8; ks++) {
                const short8 a = *(const short8*)&sBig[(mt * 16 + l16) * 264 + ks * 32 + quad * 8];
                const short8 bvv = *(const short8*)&sV[(dt * 16 + l16) * 264 + ks * 32 + quad * 8];
                cacc = __builtin_amdgcn_mfma_f32_16x16x32_bf16(a, bvv, cacc, 0, 0, 0);
            }
            unsigned* ctxB = (unsigned*)sCtx;
            unsigned pk2[4];
#pragma unroll
            for (int i = 0; i < 4; i++) pk2[i] = (unsigned)bf16_rn(cacc[i]) * 0x10001u;
            *(uint4*)&ctxB[(dt * 16 + l16) * 260 + qd * 64 + mt * 16 + quad * 4] =
                make_uint4(pk2[0], pk2[1], pk2[2], pk2[3]);
        }
        if (t < 64) {
            float s = 0.f;
#pragma unroll
            for (int wg2 = 0; wg2 < 8; wg2++)
                s += sksP[((t >> 5) * 8 + wg2) * 32 + (t & 31)];
            sksum[qd * 64 + t] = s;
        }
        __syncthreads();
    }

    // row max over this wave's half of (qd,m); union across wh = full m range
    {
        float mxn = -INFINITY;
#pragma unroll
        for (int j = 0; j < 2; j++)
#pragma unroll
            for (int mtl = 0; mtl < 4; mtl++)
#pragma unroll
                for (int i = 0; i < 4; i++) mxn = fmaxf(mxn, adq[j][mtl][i]);
        mxn = fmaxf(mxn, __shfl_xor(mxn, 16, 64));
        mxn = fmaxf(mxn, __shfl_xor(mxn, 32, 64));
        if (quad == 0) smaxP[wh * 128 + nq] = mxn;
    }
    __syncthreads();
    const float dmq = sdq[nq] + fmaxf(smaxP[nq], smaxP[128 + nq]) * nrm;

    // o^T[d][n]: A = ctx^T from sCtx (dup), B = exp+split of adq straight from regs.
    floatx4 oT[2];
    oT[0] = (floatx4){0.f, 0.f, 0.f, 0.f};
    oT[1] = (floatx4){0.f, 0.f, 0.f, 0.f};
    float dp = 0.f;
#pragma unroll
    for (int j = 0; j < 2; j++) {
        const int qdo = 2 * j + (wh ^ 1);
#pragma unroll
        for (int mtl = 0; mtl < 4; mtl++) {
            unsigned pk[4];
#pragma unroll
            for (int i = 0; i < 4; i++) {
                const float qp = ratio * (exp2f((adq[j][mtl][i] * nrm - dmq) * LOG2E) + 1e-4f);
                dp += qp * sksum[qdo * 64 + mtl * 16 + quad * 4 + i];
                pk[i] = split_pack(qp);
            }
            U8 tb; tb.u = make_uint4(pk[0], pk[1], pk[2], pk[3]);
#pragma unroll
            for (int dt = 0; dt < 2; dt++) {
                const short8 actx = *(const short8*)&sCtx[(dt * 16 + l16) * 520 + qdo * 128 + mtl * 32 + quad * 8];
                oT[dt] = __builtin_amdgcn_mfma_f32_16x16x32_bf16(actx, tb.s, oT[dt], 0, 0, 0);
            }
        }
    }
    dp += __shfl_xor(dp, 16, 64);
    dp += __shfl_xor(dp, 32, 64);
    if (quad == 0) sdenP[wh * 128 + nq] = dp;

    // cross-half o reduction through dead kpT space, then coalesced packed store
    float* oRed = (float*)sBig;
    if (wh == 1) {
#pragma unroll
        for (int dt = 0; dt < 2; dt++)
            *(floatx4*)&oRed[((wg * 2 + dt) * 64 + lane) * 4] = oT[dt];
    }
    __syncthreads();
    if (wh == 0) {
        const float inv = 1.0f / (sdenP[nq] + sdenP[128 + nq]);
#pragma unroll
        for (int dt = 0; dt < 2; dt++) {
            const floatx4 o2 = *(const floatx4*)&oRed[((wg * 2 + dt) * 64 + lane) * 4];
            const unsigned r0 = split_pack((oT[dt][0] + o2[0]) * inv);
            const unsigned r1 = split_pack((oT[dt][1] + o2[1]) * inv);
            const unsigned r2 = split_pack((oT[dt][2] + o2[2]) * inv);
            const unsigned r3 = split_pack((oT[dt][3] + o2[3]) * inv);
            *(uint4*)&outp[((size_t)b * S_ + nq) * D_ + hh * DH_ + dt * 16 + quad * 4] =
                make_uint4(r0, r1, r2, r3);
        }
    }
}

// ---------- classification head (packed input) ----------
__global__ void __launch_bounds__(256) k_head(
    const unsigned* __restrict__ hfin, const float* __restrict__ h1w, const float* __restrict__ h1b,
    const float* __restrict__ h2w, const float* __restrict__ h2b,
    const float* __restrict__ ow, const float* __restrict__ ob, float* __restrict__ outp)
{
    __shared__ float c0[D_];
    __shared__ float c1[2 * HID_];
    __shared__ float sred[4];
    const int t = threadIdx.x;
    const int b = blockIdx.x;
    c0[t] = rec(hfin[(size_t)b * S_ * D_ + t]);
    __syncthreads();
#pragma unroll
    for (int half = 0; half < 2; half++) {
        const int j = half * 256 + t;
        float a = h1b[j];
        const float* w = h1w + (size_t)j * D_;
        for (int d = 0; d < D_; d += 4) {
            const float4 w4 = *(const float4*)&w[d];
            const float4 x4 = *(const float4*)&c0[d];
            a += x4.x * w4.x + x4.y * w4.y + x4.z * w4.z + x4.w * w4.w;
        }
        c1[j] = (a >= 0.f) ? a : 0.2f * a;
    }
    __syncthreads();
    float a2 = h2b[t];
    const float* w2 = h2w + (size_t)t * (2 * HID_);
    for (int j = 0; j < 2 * HID_; j += 4) {
        const float4 w4 = *(const float4*)&w2[j];
        const float4 x4 = *(const float4*)&c1[j];
        a2 += x4.x * w4.x + x4.y * w4.y + x4.z * w4.z + x4.w * w4.w;
    }
    const float c2 = (a2 >= 0.f) ? a2 : 0.2f * a2;
    const float s = blk_sum(c2 * ow[t], sred);
    if (t == 0) outp[b] = s + ob[0];
}

extern "C" void kernel_launch(void* const* d_in, const int* in_sizes, int n_in,
                              void* d_out, int out_size, void* d_ws, size_t ws_size,
                              hipStream_t stream)
{
    const float* x     = (const float*)d_in[0];
    const int*   mask  = (const int*)d_in[1];
    const float* emb_w = (const float*)d_in[2];
    const float* emb_b = (const float*)d_in[3];
    const float* Wq    = (const float*)d_in[4];
    const float* bq    = (const float*)d_in[5];
    const float* Wk    = (const float*)d_in[6];
    const float* bk    = (const float*)d_in[7];
    const float* Wv    = (const float*)d_in[8];
    const float* bv    = (const float*)d_in[9];
    const float* Wo    = (const float*)d_in[10];
    const float* bo    = (const float*)d_in[11];
    const float* proj  = (const float*)d_in[12];
    const float* n1w   = (const float*)d_in[13];
    const float* n1b   = (const float*)d_in[14];
    const float* n2w   = (const float*)d_in[15];
    const float* n2b   = (const float*)d_in[16];
    const float* f1w   = (const float*)d_in[17];
    const float* f1b   = (const float*)d_in[18];
    const float* f2w   = (const float*)d_in[19];
    const float* f2b   = (const float*)d_in[20];
    const float* h1w   = (const float*)d_in[21];
    const float* h1b   = (const float*)d_in[22];
    const float* h2w   = (const float*)d_in[23];
    const float* h2b   = (const float*)d_in[24];
    const float* ow    = (const float*)d_in[25];
    const float* ob    = (const float*)d_in[26];

    const size_t BSD = (size_t)B_ * S_ * D_;
    unsigned* A = (unsigned*)d_ws;                 // packed activations
    unsigned* Q = A + BSD;
    unsigned* K = Q + BSD;
    unsigned* V = K + BSD;
    unsigned* T = K;                               // post-LN1 alias (K dead after attn)
    unsigned* W2 = V + BSD;                        // compact split weights: 6 x L x 65536 uints
    const size_t WT = (size_t)L_ * 256 * 256;
    const size_t WM = (size_t)256 * 256;
    unsigned* P2 = W2 + 6 * WT;                    // compact split proj: L x 256 x 32 uints
    int* slots = (int*)(P2 + (size_t)L_ * M_ * DH_);

    k_wconv<<<256, 256, 0, stream>>>(Wq,  W2 + 0 * WT);
    k_wconv<<<256, 256, 0, stream>>>(Wk,  W2 + 1 * WT);
    k_wconv<<<256, 256, 0, stream>>>(Wv,  W2 + 2 * WT);
    k_wconv<<<256, 256, 0, stream>>>(Wo,  W2 + 3 * WT);
    k_wconv<<<256, 256, 0, stream>>>(f1w, W2 + 4 * WT);
    k_wconv<<<256, 256, 0, stream>>>(f2w, W2 + 5 * WT);
    k_wconv<<<32, 256, 0, stream>>>(proj, P2);
    k_reset<<<1, 64, 0, stream>>>(slots);

    const int GB = B_ * S_ / 64;               // 512 blocks per GEMM
    const int DB = B_ * H_ * S_ / 64 * 2;      // 8192 blocks for k_dmax
    const size_t ATTN_LDS = 142336;            // 139 KB dynamic LDS

    k_embed<<<B_ * S_ * D_ / 256, 256, 0, stream>>>(x, emb_w, emb_b, A);
    for (int l = 0; l < L_; l++) {
        const unsigned* P2l = P2 + (size_t)l * M_ * DH_;
        k_gemm<0><<<GB, 512, 0, stream>>>(A, W2 + 0 * WT + l * WM, bq + l * D_, nullptr, nullptr, nullptr, Q);
        k_gemm<0><<<GB, 512, 0, stream>>>(A, W2 + 1 * WT + l * WM, bk + l * D_, nullptr, nullptr, nullptr, K);
        k_gemm<1><<<GB, 512, 0, stream>>>(A, W2 + 2 * WT + l * WM, bv + l * D_, nullptr, nullptr, mask, V);
        k_dmax<<<DB, 256, 0, stream>>>(K, P2l, slots + l);
        k_attn2<<<B_ * H_, 1024, ATTN_LDS, stream>>>(Q, K, V, P2l, slots + l, A);
        k_gemm<2><<<GB, 512, 0, stream>>>(A, W2 + 3 * WT + l * WM, bo + l * D_, n1w + l * D_, n1b + l * D_, nullptr, T);
        k_gemm<3><<<GB, 512, 0, stream>>>(T, W2 + 4 * WT + l * WM, f1b + l * HID_, nullptr, nullptr, nullptr, Q);
        k_gemm<2><<<GB, 512, 0, stream>>>(Q, W2 + 5 * WT + l * WM, f2b + l * D_, n2w + l * D_, n2b + l * D_, nullptr, A);
    }
    k_head<<<B_, 256, 0, stream>>>(A, h1w, h1b, h2w, h2b, ow, ob, (float*)d_out);
}

// Round 4
// 1729.433 us; speedup vs baseline: 1.1752x; 1.0226x over previous
//
#include <hip/hip_runtime.h>
#include <math.h>

#define B_ 256
#define N_ 127
#define S_ 128
#define NDIM_ 3
#define D_ 256
#define H_ 8
#define DH_ 32
#define M_ 256
#define HID_ 256
#define L_ 4
#define LOG2E 1.44269504088896340736f

typedef __attribute__((ext_vector_type(8))) short short8;
typedef __attribute__((ext_vector_type(4))) float floatx4;

// ---------- bf16 split helpers ----------
// Canonical activation format: packed uint  u = h | (l<<16)  where
// h = bf16_rn(x), l = bf16_rn(x - h). Same 4 B as fp32.
__device__ __forceinline__ ushort bf16_rn(float x) {
    unsigned u = __float_as_uint(x);
    u = (u + 0x7fffu + ((u >> 16) & 1u)) >> 16;
    return (ushort)u;
}
__device__ __forceinline__ unsigned split_pack(float x) {
    const ushort h = bf16_rn(x);
    const float r = x - __uint_as_float(((unsigned)h) << 16);
    const ushort l = bf16_rn(r);
    return (unsigned)h | ((unsigned)l << 16);
}
// {h,h} as two bf16 lanes
__device__ __forceinline__ unsigned dup_lo(unsigned u) {
    const unsigned h = u & 0xffffu;
    return h | (h << 16);
}
// {l,l} as two bf16 lanes
__device__ __forceinline__ unsigned dup_hi(unsigned u) {
    const unsigned l = u >> 16;
    return l | (l << 16);
}
// reconstruct fp32 ~= h + l (error ~2^-17 relative)
__device__ __forceinline__ float rec(unsigned u) {
    return __uint_as_float(u << 16) + __uint_as_float(u & 0xffff0000u);
}
// pack low halves of two packed uints: {h0, h1} as bf16x2
__device__ __forceinline__ unsigned hpair(unsigned u0, unsigned u1) {
    return (u0 & 0xffffu) | (u1 << 16);
}
// pack high halves: {l0, l1} as bf16x2
__device__ __forceinline__ unsigned lpair(unsigned u0, unsigned u1) {
    return (u0 >> 16) | (u1 & 0xffff0000u);
}

// ---------- block reductions ----------
__device__ __forceinline__ float blk_sum(float v, float* sred) {
#pragma unroll
    for (int o = 32; o > 0; o >>= 1) v += __shfl_xor(v, o, 64);
    if ((threadIdx.x & 63) == 0) sred[threadIdx.x >> 6] = v;
    __syncthreads();
    v = sred[0] + sred[1] + sred[2] + sred[3];
    __syncthreads();
    return v;
}

// ---------- embedding (emits packed) ----------
__global__ void k_embed(const float* __restrict__ x, const float* __restrict__ ew,
                        const float* __restrict__ eb, unsigned* __restrict__ h) {
    const int idx = blockIdx.x * 256 + threadIdx.x;
    const int d = idx & (D_ - 1);
    const int n = (idx >> 8) & (S_ - 1);
    const int b = idx >> 15;
    float val = 0.f;
    if (n > 0) {
        const float* xr = x + ((size_t)b * N_ + (n - 1)) * NDIM_;
        val = eb[d] + xr[0] * ew[d * 3 + 0] + xr[1] * ew[d * 3 + 1] + xr[2] * ew[d * 3 + 2];
    }
    h[idx] = split_pack(val);
}

// ---------- weight pre-split (compact packed, for proj): fp32 -> uint [h|l<<16] ----------
__global__ void __launch_bounds__(256) k_wconv(const float* __restrict__ src, unsigned* __restrict__ dst) {
    const int idx = (blockIdx.x * 256 + threadIdx.x) * 4;
    const float4 w4 = *(const float4*)&src[idx];
    const float v[4] = {w4.x, w4.y, w4.z, w4.w};
    unsigned u[4];
#pragma unroll
    for (int i = 0; i < 4; i++) u[i] = split_pack(v[i]);
    *(uint4*)&dst[idx] = make_uint4(u[0], u[1], u[2], u[3]);
}

// ---------- weight pre-split into MFMA fragment-order bf16 planes ----------
// Per layer matrix (256 cols x 256 k): emit h-plane and l-plane with layout
// [kc(32)][col(256)][8 ushorts]  where element k = kc*8 + j. This IS the
// B-fragment image, so k_gemm loads fragments straight from global (L1/L2-hot).
// Covers 4 layers per tensor: 128 blocks x 256 threads = 4 x 8192.
__global__ void __launch_bounds__(256) k_wconvp(const float* __restrict__ src,
                                                ushort* __restrict__ dh, ushort* __restrict__ dl) {
    const int tid = blockIdx.x * 256 + threadIdx.x;
    const int l = tid >> 13;
    const int col = (tid >> 5) & 255, kc = tid & 31;
    const float* sp = src + ((size_t)l << 16) + col * 256 + kc * 8;
    float v[8];
    *(float4*)&v[0] = *(const float4*)sp;
    *(float4*)&v[4] = *(const float4*)(sp + 4);
    unsigned hu[4], lu[4];
#pragma unroll
    for (int i = 0; i < 4; i++) {
        const unsigned u0 = split_pack(v[2 * i]);
        const unsigned u1 = split_pack(v[2 * i + 1]);
        hu[i] = hpair(u0, u1);
        lu[i] = lpair(u0, u1);
    }
    const size_t off = ((size_t)l << 16) + ((size_t)(kc * 256 + col)) * 8;
    *(uint4*)&dh[off] = make_uint4(hu[0], hu[1], hu[2], hu[3]);
    *(uint4*)&dl[off] = make_uint4(lu[0], lu[1], lu[2], lu[3]);
}

// ---------- 3-product split MFMA GEMM, W direct-from-global ----------
// C = Ah*Wh + Ah*Wl + Al*Wh. W fragments are loaded straight from the
// pre-transposed global planes (coalesced 16 B/lane; W is 256 KB/layer and
// L2-resident, step-chunk L1-resident). LDS holds only the A tile, double
// buffered (16.6 KB) -> LDS traffic/block-step drops 137 KB -> 40 KB, and
// one barrier per step instead of two.
template<int EPI>
__global__ void __launch_bounds__(512, 4) k_gemm(
    const unsigned* __restrict__ Ap, const ushort* __restrict__ WH,
    const ushort* __restrict__ WL,
    const float* __restrict__ bias, const float* __restrict__ g1,
    const float* __restrict__ g2, const int* __restrict__ mask,
    unsigned* __restrict__ out)
{
    __shared__ ushort sAh[2][2080];            // [buf][chunk(4)][64 rows][8] (+pad 8/chunk)
    __shared__ ushort sAl[2][2080];
    __shared__ float sredA[64][4], sredB[64][4];
    const int t = threadIdx.x;
    const int w = t >> 6, lane = t & 63;
    const int quad = lane >> 4, l16 = lane & 15;
    const int rowbase = 32 * (w >> 2), colbase = 64 * (w & 3);
    const int colg = w & 3;
    const int row0 = blockIdx.x * 64;

    floatx4 acc[2][4];
#pragma unroll
    for (int rt = 0; rt < 2; rt++)
#pragma unroll
        for (int ct = 0; ct < 4; ct++) acc[rt][ct] = (floatx4){0.f, 0.f, 0.f, 0.f};

    // A staging: each thread handles one 4-fp32 quad of one row
    const int arow = t >> 3, akq = t & 7;
    const unsigned* AG = Ap + (size_t)(row0 + arow) * D_ + akq * 4;
    const int aidx = (akq >> 1) * 520 + arow * 8 + (akq & 1) * 4;

    {
        const uint4 a4 = *(const uint4*)AG;
        *(uint2*)&sAh[0][aidx] = make_uint2(hpair(a4.x, a4.y), hpair(a4.z, a4.w));
        *(uint2*)&sAl[0][aidx] = make_uint2(lpair(a4.x, a4.y), lpair(a4.z, a4.w));
    }
    __syncthreads();

    for (int s = 0; s < 8; s++) {
        const int p = s & 1;
        // (1) issue global A load for s+1 into registers
        uint4 a_n;
        if (s + 1 < 8) a_n = *(const uint4*)(AG + (s + 1) * 32);
        // (2) W fragments direct from global planes; A fragments from LDS[p]
        const size_t wbase = ((size_t)((s * 4 + quad) * 256 + colbase + l16)) * 8;
        const ushort* WHf = WH + wbase;
        const ushort* WLf = WL + wbase;
        short8 ah[2], al[2], wh[4], wl[4];
#pragma unroll
        for (int ct = 0; ct < 4; ct++) {
            wh[ct] = *(const short8*)&WHf[ct * 128];
            wl[ct] = *(const short8*)&WLf[ct * 128];
        }
#pragma unroll
        for (int rt = 0; rt < 2; rt++) {
            const int ai = quad * 520 + (rowbase + 16 * rt + l16) * 8;
            ah[rt] = *(const short8*)&sAh[p][ai];
            al[rt] = *(const short8*)&sAl[p][ai];
        }
#pragma unroll
        for (int rt = 0; rt < 2; rt++)
#pragma unroll
            for (int ct = 0; ct < 4; ct++) {
                acc[rt][ct] = __builtin_amdgcn_mfma_f32_16x16x32_bf16(ah[rt], wh[ct], acc[rt][ct], 0, 0, 0);
                acc[rt][ct] = __builtin_amdgcn_mfma_f32_16x16x32_bf16(ah[rt], wl[ct], acc[rt][ct], 0, 0, 0);
                acc[rt][ct] = __builtin_amdgcn_mfma_f32_16x16x32_bf16(al[rt], wh[ct], acc[rt][ct], 0, 0, 0);
            }
        // (3) write s+1 into the other buffer, one barrier
        if (s + 1 < 8) {
            *(uint2*)&sAh[p ^ 1][aidx] = make_uint2(hpair(a_n.x, a_n.y), hpair(a_n.z, a_n.w));
            *(uint2*)&sAl[p ^ 1][aidx] = make_uint2(lpair(a_n.x, a_n.y), lpair(a_n.z, a_n.w));
        }
        __syncthreads();
    }

    int colv[4]; float bv[4];
#pragma unroll
    for (int ct = 0; ct < 4; ct++) { colv[ct] = colbase + 16 * ct + l16; bv[ct] = bias[colv[ct]]; }

    if (EPI <= 1) {
        const int b = row0 >> 7;
#pragma unroll
        for (int rt = 0; rt < 2; rt++)
#pragma unroll
        for (int i = 0; i < 4; i++) {
            const int rl = rowbase + 16 * rt + quad * 4 + i;
            const int n = (row0 + rl) & (S_ - 1);
            float keep = 1.f;
            if (EPI == 1) keep = (n == 0) ? 1.f : (mask[b * N_ + n - 1] ? 0.f : 1.f);
#pragma unroll
            for (int ct = 0; ct < 4; ct++) {
                float c = acc[rt][ct][i] + bv[ct];
                if (EPI == 1) c *= keep;
                const int col = colv[ct];
                out[(((size_t)b * H_ + (col >> 5)) * S_ + n) * DH_ + (col & 31)] = split_pack(c);
            }
        }
    } else if (EPI == 2) {
        float gv[4], bbv[4];
#pragma unroll
        for (int ct = 0; ct < 4; ct++) { gv[ct] = g1[colv[ct]]; bbv[ct] = g2[colv[ct]]; }
#pragma unroll
        for (int rt = 0; rt < 2; rt++)
#pragma unroll
        for (int i = 0; i < 4; i++) {
            const int rl = rowbase + 16 * rt + quad * 4 + i;
            float s = 0.f, s2 = 0.f;
#pragma unroll
            for (int ct = 0; ct < 4; ct++) {
                const float c = acc[rt][ct][i] + bv[ct];
                s += c; s2 += c * c;
            }
#pragma unroll
            for (int o = 8; o > 0; o >>= 1) { s += __shfl_xor(s, o, 64); s2 += __shfl_xor(s2, o, 64); }
            if (l16 == 0) { sredA[rl][colg] = s; sredB[rl][colg] = s2; }
        }
        __syncthreads();
#pragma unroll
        for (int rt = 0; rt < 2; rt++)
#pragma unroll
        for (int i = 0; i < 4; i++) {
            const int rl = rowbase + 16 * rt + quad * 4 + i;
            const float s = sredA[rl][0] + sredA[rl][1] + sredA[rl][2] + sredA[rl][3];
            const float s2 = sredB[rl][0] + sredB[rl][1] + sredB[rl][2] + sredB[rl][3];
            const float mu = s * (1.f / D_);
            const float rs = rsqrtf(s2 * (1.f / D_) - mu * mu + 1e-5f);
#pragma unroll
            for (int ct = 0; ct < 4; ct++) {
                const float c = acc[rt][ct][i] + bv[ct];
                out[(size_t)(row0 + rl) * D_ + colv[ct]] = split_pack((c - mu) * rs * gv[ct] + bbv[ct]);
            }
        }
    } else {
#pragma unroll
        for (int rt = 0; rt < 2; rt++)
#pragma unroll
        for (int i = 0; i < 4; i++) {
            const int rl = rowbase + 16 * rt + quad * 4 + i;
#pragma unroll
            for (int ct = 0; ct < 4; ct++) {
                const float c = acc[rt][ct][i] + bv[ct];
                out[(size_t)(row0 + rl) * D_ + colv[ct]] = split_pack((c >= 0.f) ? c : 0.2f * c);
            }
        }
    }
}

// ---------- reset kmax slots ----------
__global__ void k_reset(int* slots) {
    if (threadIdx.x < 4) {
        const int i = __float_as_int(-INFINITY);
        slots[threadIdx.x] = (i >= 0) ? i : (i ^ 0x7fffffff);
    }
}

// ---------- MFMA global k-max (packed K input) ----------
__global__ void __launch_bounds__(256) k_dmax(
    const unsigned* __restrict__ kg, const unsigned* __restrict__ P2, int* __restrict__ slot)
{
    __shared__ __align__(16) ushort A2s[64 * 136];
    __shared__ __align__(16) ushort Ps[128 * 136];
    __shared__ float sred[4];
    const int t = threadIdx.x;
    const size_t row0 = (size_t)(blockIdx.x >> 1) * 64;
    const int m0 = (blockIdx.x & 1) * 128;
    {
        const int row = t >> 2, kq = (t & 3) * 8;
        const unsigned* src = kg + (row0 + row) * DH_ + kq;
        const uint4 f0 = *(const uint4*)src;
        const uint4 f1 = *(const uint4*)(src + 4);
        const unsigned uu[8] = {f0.x, f0.y, f0.z, f0.w, f1.x, f1.y, f1.z, f1.w};
#pragma unroll
        for (int i = 0; i < 4; i++) {
            *(uint4*)&A2s[row * 136 + ((t & 3) * 4 + i) * 8] =
                make_uint4(dup_lo(uu[2 * i]), dup_hi(uu[2 * i]), dup_lo(uu[2 * i + 1]), dup_hi(uu[2 * i + 1]));
        }
    }
    {
        const int col = t >> 1;
        const unsigned* src = P2 + (m0 + col) * DH_ + (t & 1) * 16;
#pragma unroll
        for (int i = 0; i < 8; i++) {
            const unsigned u0 = src[2 * i], u1 = src[2 * i + 1];
            *(uint4*)&Ps[col * 136 + ((t & 1) * 8 + i) * 8] = make_uint4(u0, u0, u1, u1);
        }
    }
    __syncthreads();
    const int w = t >> 6, lane = t & 63, quad = lane >> 4, l16 = lane & 15;
    floatx4 acc[4][2];
#pragma unroll
    for (int rt = 0; rt < 4; rt++)
#pragma unroll
        for (int ct = 0; ct < 2; ct++) acc[rt][ct] = (floatx4){0.f, 0.f, 0.f, 0.f};
#pragma unroll
    for (int kk = 0; kk < 4; kk++) {
        short8 af[4], bf[2];
#pragma unroll
        for (int rt = 0; rt < 4; rt++)
            af[rt] = *(const short8*)&A2s[(rt * 16 + l16) * 136 + (kk * 4 + quad) * 8];
#pragma unroll
        for (int ct = 0; ct < 2; ct++)
            bf[ct] = *(const short8*)&Ps[((w * 2 + ct) * 16 + l16) * 136 + (kk * 4 + quad) * 8];
#pragma unroll
        for (int rt = 0; rt < 4; rt++)
#pragma unroll
            for (int ct = 0; ct < 2; ct++)
                acc[rt][ct] = __builtin_amdgcn_mfma_f32_16x16x32_bf16(af[rt], bf[ct], acc[rt][ct], 0, 0, 0);
    }
    float mx = -INFINITY;
#pragma unroll
    for (int rt = 0; rt < 4; rt++)
#pragma unroll
        for (int ct = 0; ct < 2; ct++)
#pragma unroll
            for (int i = 0; i < 4; i++) mx = fmaxf(mx, acc[rt][ct][i]);
#pragma unroll
    for (int o = 32; o > 0; o >>= 1) mx = fmaxf(mx, __shfl_xor(mx, o, 64));
    if (lane == 0) sred[w] = mx;
    __syncthreads();
    if (t == 0) {
        const float m4 = fmaxf(fmaxf(sred[0], sred[1]), fmaxf(sred[2], sred[3]))
                       * 0.42044820762685725f;
        const int i = __float_as_int(m4);
        atomicMax(slot, (i >= 0) ? i : (i ^ 0x7fffffff));
    }
}

// ---------- full-MFMA performer attention v2 (packed I/O), 1024 threads ----------
__global__ void __launch_bounds__(1024) k_attn2(
    const unsigned* __restrict__ qg, const unsigned* __restrict__ kg, const unsigned* __restrict__ vg,
    const unsigned* __restrict__ P2, const int* __restrict__ slot,
    unsigned* __restrict__ outp)
{
    extern __shared__ char smem[];
    ushort* sA    = (ushort*)(smem);            // [128][136]: K-split
    ushort* sB    = (ushort*)(smem + 34816);    // [64][136]: P-quarter {h,l,h,l}
    ushort* sBig  = (ushort*)(smem + 52224);    // kpT [64][264]; later oRed f32[4096]
    ushort* sV    = (ushort*)(smem + 86016);    // [32][264]: v dup
    ushort* sCtx  = (ushort*)(smem + 102912);   // [32][520]: ctx dup
    float* sdk    = (float*)(smem + 136192);    // [128]
    float* sdq    = (float*)(smem + 136704);    // [128]
    float* smaxP  = (float*)(smem + 137216);    // [2][128]
    float* sdenP  = (float*)(smem + 138240);    // [2][128]
    float* sksum  = (float*)(smem + 139264);    // [256]
    float* sksP   = (float*)(smem + 140288);    // [16][32]

    const int bh = blockIdx.x;
    const int b = bh >> 3, hh = bh & 7;
    const int t = threadIdx.x;
    const int w = t >> 6, lane = t & 63, quad = lane >> 4, l16 = lane & 15;
    const int wg = w & 7, wh = w >> 3;
    const int nq = wg * 16 + l16;
    const unsigned* kb = kg + (size_t)bh * S_ * DH_;
    const unsigned* qb = qg + (size_t)bh * S_ * DH_;
    const unsigned* vb = vg + (size_t)bh * S_ * DH_;
    const float nrm = 0.42044820762685725f;
    const float diagc = 0.5f * nrm * nrm;
    const float ratio = 0.0625f;

    union U8 { uint4 u; short8 s; };

    // Q B-fragments into regs from packed
    short8 qf[4];
    {
        const unsigned* qrow = qb + (size_t)nq * DH_ + quad * 2;
#pragma unroll
        for (int ks = 0; ks < 4; ks++) {
            const uint2 qv = *(const uint2*)(qrow + ks * 8);
            U8 tmp; tmp.u = make_uint4(dup_lo(qv.x), dup_hi(qv.x), dup_lo(qv.y), dup_hi(qv.y));
            qf[ks] = tmp.s;
        }
    }

    if (t < 512) {
        const int row = t >> 2, seg = t & 3;
        const unsigned* src = kb + row * DH_ + seg * 8;
        const uint4 f0 = *(const uint4*)&src[0];
        const uint4 f1 = *(const uint4*)&src[4];
        const unsigned uu[8] = {f0.x, f0.y, f0.z, f0.w, f1.x, f1.y, f1.z, f1.w};
#pragma unroll
        for (int p = 0; p < 4; p++) {
            *(uint4*)&sA[row * 136 + seg * 32 + p * 8] =
                make_uint4(dup_lo(uu[2 * p]), dup_hi(uu[2 * p]), dup_lo(uu[2 * p + 1]), dup_hi(uu[2 * p + 1]));
        }
    } else {
        const int tt2 = t - 512;
        const int n = tt2 & 127, d0 = (tt2 >> 7) * 8;
        const unsigned* src = vb + n * DH_ + d0;
        const uint4 f0 = *(const uint4*)&src[0];
        const uint4 f1 = *(const uint4*)&src[4];
        const unsigned uu[8] = {f0.x, f0.y, f0.z, f0.w, f1.x, f1.y, f1.z, f1.w};
        unsigned* dst = (unsigned*)sV;
#pragma unroll
        for (int j = 0; j < 8; j++)
            dst[(d0 + j) * 132 + n] = dup_lo(uu[j]);
    }
    if (t < 128) {
        float s = 0.f, s2 = 0.f;
#pragma unroll
        for (int d4 = 0; d4 < DH_ / 4; d4++) {
            const uint4 kk = *(const uint4*)&kb[t * DH_ + d4 * 4];
            const float k0 = rec(kk.x), k1 = rec(kk.y), k2 = rec(kk.z), k3 = rec(kk.w);
            s += k0 * k0 + k1 * k1 + k2 * k2 + k3 * k3;
            const uint4 qq = *(const uint4*)&qb[t * DH_ + d4 * 4];
            const float q0 = rec(qq.x), q1 = rec(qq.y), q2 = rec(qq.z), q3 = rec(qq.w);
            s2 += q0 * q0 + q1 * q1 + q2 * q2 + q3 * q3;
        }
        sdk[t] = s * diagc;
        sdq[t] = s2 * diagc;
    }
    float kmaxv;
    { const int iv = *slot; kmaxv = __int_as_float((iv >= 0) ? iv : (iv ^ 0x7fffffff)); }
    __syncthreads();

    // adq[j][mtl]: qp dd for this wave's qds (wh=1 -> qd {0,2}; wh=0 -> qd {1,3})
    floatx4 adq[2][4];
#pragma unroll
    for (int j = 0; j < 2; j++)
#pragma unroll
        for (int mtl = 0; mtl < 4; mtl++) adq[j][mtl] = (floatx4){0.f, 0.f, 0.f, 0.f};

#pragma unroll
    for (int qd = 0; qd < 4; qd++) {
        // stage P quarter
        {
            const int col = t >> 4, ch2 = t & 15;
            const unsigned* src = P2 + (size_t)(qd * 64 + col) * DH_ + ch2 * 2;
            const unsigned u0 = src[0], u1 = src[1];
            *(uint4*)&sB[col * 136 + ch2 * 8] = make_uint4(u0, u0, u1, u1);
        }
        __syncthreads();
        // phase B: kp MFMAs (all 16 waves) + exp/split/pack + ksum partials
        floatx4 acc[2];
        acc[0] = (floatx4){0.f, 0.f, 0.f, 0.f};
        acc[1] = (floatx4){0.f, 0.f, 0.f, 0.f};
#pragma unroll
        for (int ks = 0; ks < 4; ks++) {
            const short8 af = *(const short8*)&sA[nq * 136 + ks * 32 + quad * 8];
            short8 bf[2];
#pragma unroll
            for (int ctl = 0; ctl < 2; ctl++)
                bf[ctl] = *(const short8*)&sB[((2 * wh + ctl) * 16 + l16) * 136 + ks * 32 + quad * 8];
#pragma unroll
            for (int ctl = 0; ctl < 2; ctl++)
                acc[ctl] = __builtin_amdgcn_mfma_f32_16x16x32_bf16(af, bf[ctl], acc[ctl], 0, 0, 0);
        }
        unsigned* kpT = (unsigned*)sBig;
        float kc[2];
#pragma unroll
        for (int ctl = 0; ctl < 2; ctl++) {
            float kcl = 0.f;
            unsigned pk[4];
#pragma unroll
            for (int i = 0; i < 4; i++) {
                const int n = wg * 16 + quad * 4 + i;
                const float kp = ratio * (exp2f((acc[ctl][i] * nrm - sdk[n] - kmaxv) * LOG2E) + 1e-4f);
                kcl += kp;
                pk[i] = split_pack(kp);
            }
            *(uint4*)&kpT[((2 * wh + ctl) * 16 + l16) * 132 + wg * 16 + quad * 4] =
                make_uint4(pk[0], pk[1], pk[2], pk[3]);
            kc[ctl] = kcl;
        }
#pragma unroll
        for (int ctl = 0; ctl < 2; ctl++) {
            kc[ctl] += __shfl_xor(kc[ctl], 16, 64);
            kc[ctl] += __shfl_xor(kc[ctl], 32, 64);
        }
        if (quad == 0) {
            sksP[w * 32 + l16] = kc[0];
            sksP[w * 32 + 16 + l16] = kc[1];
        }
        __syncthreads();
        // phase C: one half does qp MFMAs (B from regs), other half does ctx MFMAs
        const int qown = (qd & 1) ^ 1;
        if (wh == qown) {
            const int aidx = qd >> 1;
#pragma unroll
            for (int mtl = 0; mtl < 4; mtl++)
#pragma unroll
                for (int ks = 0; ks < 4; ks++) {
                    const short8 af2 = *(const short8*)&sB[(mtl * 16 + l16) * 136 + ks * 32 + quad * 8];
                    adq[aidx][mtl] = __builtin_amdgcn_mfma_f32_16x16x32_bf16(af2, qf[ks], adq[aidx][mtl], 0, 0, 0);
                }
        } else {
            const int mt = wg & 3, dt = wg >> 2;
            floatx4 cacc = (floatx4){0.f, 0.f, 0.f, 0.f};
#pragma unroll
            for (int ks = 0; ks < 8; ks++) {
                const short8 a = *(const short8*)&sBig[(mt * 16 + l16) * 264 + ks * 32 + quad * 8];
                const short8 bvv = *(const short8*)&sV[(dt * 16 + l16) * 264 + ks * 32 + quad * 8];
                cacc = __builtin_amdgcn_mfma_f32_16x16x32_bf16(a, bvv, cacc, 0, 0, 0);
            }
            unsigned* ctxB = (unsigned*)sCtx;
            unsigned pk2[4];
#pragma unroll
            for (int i = 0; i < 4; i++) pk2[i] = (unsigned)bf16_rn(cacc[i]) * 0x10001u;
            *(uint4*)&ctxB[(dt * 16 + l16) * 260 + qd * 64 + mt * 16 + quad * 4] =
                make_uint4(pk2[0], pk2[1], pk2[2], pk2[3]);
        }
        if (t < 64) {
            float s = 0.f;
#pragma unroll
            for (int wg2 = 0; wg2 < 8; wg2++)
                s += sksP[((t >> 5) * 8 + wg2) * 32 + (t & 31)];
            sksum[qd * 64 + t] = s;
        }
        __syncthreads();
    }

    // row max over this wave's half of (qd,m); union across wh = full m range
    {
        float mxn = -INFINITY;
#pragma unroll
        for (int j = 0; j < 2; j++)
#pragma unroll
            for (int mtl = 0; mtl < 4; mtl++)
#pragma unroll
                for (int i = 0; i < 4; i++) mxn = fmaxf(mxn, adq[j][mtl][i]);
        mxn = fmaxf(mxn, __shfl_xor(mxn, 16, 64));
        mxn = fmaxf(mxn, __shfl_xor(mxn, 32, 64));
        if (quad == 0) smaxP[wh * 128 + nq] = mxn;
    }
    __syncthreads();
    const float dmq = sdq[nq] + fmaxf(smaxP[nq], smaxP[128 + nq]) * nrm;

    // o^T[d][n]: A = ctx^T from sCtx (dup), B = exp+split of adq straight from regs.
    floatx4 oT[2];
    oT[0] = (floatx4){0.f, 0.f, 0.f, 0.f};
    oT[1] = (floatx4){0.f, 0.f, 0.f, 0.f};
    float dp = 0.f;
#pragma unroll
    for (int j = 0; j < 2; j++) {
        const int qdo = 2 * j + (wh ^ 1);
#pragma unroll
        for (int mtl = 0; mtl < 4; mtl++) {
            unsigned pk[4];
#pragma unroll
            for (int i = 0; i < 4; i++) {
                const float qp = ratio * (exp2f((adq[j][mtl][i] * nrm - dmq) * LOG2E) + 1e-4f);
                dp += qp * sksum[qdo * 64 + mtl * 16 + quad * 4 + i];
                pk[i] = split_pack(qp);
            }
            U8 tb; tb.u = make_uint4(pk[0], pk[1], pk[2], pk[3]);
#pragma unroll
            for (int dt = 0; dt < 2; dt++) {
                const short8 actx = *(const short8*)&sCtx[(dt * 16 + l16) * 520 + qdo * 128 + mtl * 32 + quad * 8];
                oT[dt] = __builtin_amdgcn_mfma_f32_16x16x32_bf16(actx, tb.s, oT[dt], 0, 0, 0);
            }
        }
    }
    dp += __shfl_xor(dp, 16, 64);
    dp += __shfl_xor(dp, 32, 64);
    if (quad == 0) sdenP[wh * 128 + nq] = dp;

    // cross-half o reduction through dead kpT space, then coalesced packed store
    float* oRed = (float*)sBig;
    if (wh == 1) {
#pragma unroll
        for (int dt = 0; dt < 2; dt++)
            *(floatx4*)&oRed[((wg * 2 + dt) * 64 + lane) * 4] = oT[dt];
    }
    __syncthreads();
    if (wh == 0) {
        const float inv = 1.0f / (sdenP[nq] + sdenP[128 + nq]);
#pragma unroll
        for (int dt = 0; dt < 2; dt++) {
            const floatx4 o2 = *(const floatx4*)&oRed[((wg * 2 + dt) * 64 + lane) * 4];
            const unsigned r0 = split_pack((oT[dt][0] + o2[0]) * inv);
            const unsigned r1 = split_pack((oT[dt][1] + o2[1]) * inv);
            const unsigned r2 = split_pack((oT[dt][2] + o2[2]) * inv);
            const unsigned r3 = split_pack((oT[dt][3] + o2[3]) * inv);
            *(uint4*)&outp[((size_t)b * S_ + nq) * D_ + hh * DH_ + dt * 16 + quad * 4] =
                make_uint4(r0, r1, r2, r3);
        }
    }
}

// ---------- classification head (packed input) ----------
__global__ void __launch_bounds__(256) k_head(
    const unsigned* __restrict__ hfin, const float* __restrict__ h1w, const float* __restrict__ h1b,
    const float* __restrict__ h2w, const float* __restrict__ h2b,
    const float* __restrict__ ow, const float* __restrict__ ob, float* __restrict__ outp)
{
    __shared__ float c0[D_];
    __shared__ float c1[2 * HID_];
    __shared__ float sred[4];
    const int t = threadIdx.x;
    const int b = blockIdx.x;
    c0[t] = rec(hfin[(size_t)b * S_ * D_ + t]);
    __syncthreads();
#pragma unroll
    for (int half = 0; half < 2; half++) {
        const int j = half * 256 + t;
        float a = h1b[j];
        const float* w = h1w + (size_t)j * D_;
        for (int d = 0; d < D_; d += 4) {
            const float4 w4 = *(const float4*)&w[d];
            const float4 x4 = *(const float4*)&c0[d];
            a += x4.x * w4.x + x4.y * w4.y + x4.z * w4.z + x4.w * w4.w;
        }
        c1[j] = (a >= 0.f) ? a : 0.2f * a;
    }
    __syncthreads();
    float a2 = h2b[t];
    const float* w2 = h2w + (size_t)t * (2 * HID_);
    for (int j = 0; j < 2 * HID_; j += 4) {
        const float4 w4 = *(const float4*)&w2[j];
        const float4 x4 = *(const float4*)&c1[j];
        a2 += x4.x * w4.x + x4.y * w4.y + x4.z * w4.z + x4.w * w4.w;
    }
    const float c2 = (a2 >= 0.f) ? a2 : 0.2f * a2;
    const float s = blk_sum(c2 * ow[t], sred);
    if (t == 0) outp[b] = s + ob[0];
}

extern "C" void kernel_launch(void* const* d_in, const int* in_sizes, int n_in,
                              void* d_out, int out_size, void* d_ws, size_t ws_size,
                              hipStream_t stream)
{
    const float* x     = (const float*)d_in[0];
    const int*   mask  = (const int*)d_in[1];
    const float* emb_w = (const float*)d_in[2];
    const float* emb_b = (const float*)d_in[3];
    const float* Wq    = (const float*)d_in[4];
    const float* bq    = (const float*)d_in[5];
    const float* Wk    = (const float*)d_in[6];
    const float* bk    = (const float*)d_in[7];
    const float* Wv    = (const float*)d_in[8];
    const float* bv    = (const float*)d_in[9];
    const float* Wo    = (const float*)d_in[10];
    const float* bo    = (const float*)d_in[11];
    const float* proj  = (const float*)d_in[12];
    const float* n1w   = (const float*)d_in[13];
    const float* n1b   = (const float*)d_in[14];
    const float* n2w   = (const float*)d_in[15];
    const float* n2b   = (const float*)d_in[16];
    const float* f1w   = (const float*)d_in[17];
    const float* f1b   = (const float*)d_in[18];
    const float* f2w   = (const float*)d_in[19];
    const float* f2b   = (const float*)d_in[20];
    const float* h1w   = (const float*)d_in[21];
    const float* h1b   = (const float*)d_in[22];
    const float* h2w   = (const float*)d_in[23];
    const float* h2b   = (const float*)d_in[24];
    const float* ow    = (const float*)d_in[25];
    const float* ob    = (const float*)d_in[26];

    const size_t BSD = (size_t)B_ * S_ * D_;
    unsigned* A = (unsigned*)d_ws;                 // packed activations
    unsigned* Q = A + BSD;
    unsigned* K = Q + BSD;
    unsigned* V = K + BSD;
    unsigned* T = K;                               // post-LN1 alias (K dead after attn)
    const size_t WMU = 65536;                      // ushorts per matrix plane (256x256)
    ushort* WH = (ushort*)(V + BSD);               // 6 x L x 65536 ushorts (h planes)
    ushort* WL = WH + 6 * L_ * WMU;                // 6 x L x 65536 ushorts (l planes)
    unsigned* P2 = (unsigned*)(WL + 6 * L_ * WMU); // compact split proj: L x 256 x 32 uints
    int* slots = (int*)(P2 + (size_t)L_ * M_ * DH_);

    k_wconvp<<<128, 256, 0, stream>>>(Wq,  WH + 0 * L_ * WMU, WL + 0 * L_ * WMU);
    k_wconvp<<<128, 256, 0, stream>>>(Wk,  WH + 1 * L_ * WMU, WL + 1 * L_ * WMU);
    k_wconvp<<<128, 256, 0, stream>>>(Wv,  WH + 2 * L_ * WMU, WL + 2 * L_ * WMU);
    k_wconvp<<<128, 256, 0, stream>>>(Wo,  WH + 3 * L_ * WMU, WL + 3 * L_ * WMU);
    k_wconvp<<<128, 256, 0, stream>>>(f1w, WH + 4 * L_ * WMU, WL + 4 * L_ * WMU);
    k_wconvp<<<128, 256, 0, stream>>>(f2w, WH + 5 * L_ * WMU, WL + 5 * L_ * WMU);
    k_wconv<<<32, 256, 0, stream>>>(proj, P2);
    k_reset<<<1, 64, 0, stream>>>(slots);

    const int GB = B_ * S_ / 64;               // 512 blocks per GEMM
    const int DB = B_ * H_ * S_ / 64 * 2;      // 8192 blocks for k_dmax
    const size_t ATTN_LDS = 142336;            // 139 KB dynamic LDS

    k_embed<<<B_ * S_ * D_ / 256, 256, 0, stream>>>(x, emb_w, emb_b, A);
    for (int l = 0; l < L_; l++) {
        const unsigned* P2l = P2 + (size_t)l * M_ * DH_;
        k_gemm<0><<<GB, 512, 0, stream>>>(A, WH + (0 * L_ + l) * WMU, WL + (0 * L_ + l) * WMU, bq + l * D_, nullptr, nullptr, nullptr, Q);
        k_gemm<0><<<GB, 512, 0, stream>>>(A, WH + (1 * L_ + l) * WMU, WL + (1 * L_ + l) * WMU, bk + l * D_, nullptr, nullptr, nullptr, K);
        k_gemm<1><<<GB, 512, 0, stream>>>(A, WH + (2 * L_ + l) * WMU, WL + (2 * L_ + l) * WMU, bv + l * D_, nullptr, nullptr, mask, V);
        k_dmax<<<DB, 256, 0, stream>>>(K, P2l, slots + l);
        k_attn2<<<B_ * H_, 1024, ATTN_LDS, stream>>>(Q, K, V, P2l, slots + l, A);
        k_gemm<2><<<GB, 512, 0, stream>>>(A, WH + (3 * L_ + l) * WMU, WL + (3 * L_ + l) * WMU, bo + l * D_, n1w + l * D_, n1b + l * D_, nullptr, T);
        k_gemm<3><<<GB, 512, 0, stream>>>(T, WH + (4 * L_ + l) * WMU, WL + (4 * L_ + l) * WMU, f1b + l * HID_, nullptr, nullptr, nullptr, Q);
        k_gemm<2><<<GB, 512, 0, stream>>>(Q, WH + (5 * L_ + l) * WMU, WL + (5 * L_ + l) * WMU, f2b + l * D_, n2w + l * D_, n2b + l * D_, nullptr, A);
    }
    k_head<<<B_, 256, 0, stream>>>(A, h1w, h1b, h2w, h2b, ow, ob, (float*)d_out);
}

// Round 5
// 1638.161 us; speedup vs baseline: 1.2407x; 1.0557x over previous
//
#include <hip/hip_runtime.h>
#include <math.h>

#define B_ 256
#define N_ 127
#define S_ 128
#define NDIM_ 3
#define D_ 256
#define H_ 8
#define DH_ 32
#define M_ 256
#define HID_ 256
#define L_ 4
#define LOG2E 1.44269504088896340736f

typedef __attribute__((ext_vector_type(8))) short short8;
typedef __attribute__((ext_vector_type(4))) float floatx4;

// ---------- bf16 split helpers ----------
// Canonical activation format: packed uint  u = h | (l<<16)  where
// h = bf16_rn(x), l = bf16_rn(x - h). Same 4 B as fp32.
__device__ __forceinline__ ushort bf16_rn(float x) {
    unsigned u = __float_as_uint(x);
    u = (u + 0x7fffu + ((u >> 16) & 1u)) >> 16;
    return (ushort)u;
}
__device__ __forceinline__ unsigned split_pack(float x) {
    const ushort h = bf16_rn(x);
    const float r = x - __uint_as_float(((unsigned)h) << 16);
    const ushort l = bf16_rn(r);
    return (unsigned)h | ((unsigned)l << 16);
}
// Fast 5-inst split for attn-internal kp/qp values: h = trunc-to-bf16 (exact
// residual), l = trunc-to-bf16 of residual. Reconstruction err <= 2^-16 |x|
// (vs 2^-17 RNE) -- negligible next to the single-bf16 V/ctx path.
__device__ __forceinline__ unsigned split_pack_fast(float x) {
    const unsigned xu = __float_as_uint(x);
    const unsigned hb = xu & 0xffff0000u;
    const float r = x - __uint_as_float(hb);
    return (hb >> 16) | (__float_as_uint(r) & 0xffff0000u);
}
// {h,h} as two bf16 lanes
__device__ __forceinline__ unsigned dup_lo(unsigned u) {
    const unsigned h = u & 0xffffu;
    return h | (h << 16);
}
// {l,l} as two bf16 lanes
__device__ __forceinline__ unsigned dup_hi(unsigned u) {
    const unsigned l = u >> 16;
    return l | (l << 16);
}
// reconstruct fp32 ~= h + l (error ~2^-17 relative)
__device__ __forceinline__ float rec(unsigned u) {
    return __uint_as_float(u << 16) + __uint_as_float(u & 0xffff0000u);
}
// pack low halves of two packed uints: {h0, h1} as bf16x2
__device__ __forceinline__ unsigned hpair(unsigned u0, unsigned u1) {
    return (u0 & 0xffffu) | (u1 << 16);
}
// pack high halves: {l0, l1} as bf16x2
__device__ __forceinline__ unsigned lpair(unsigned u0, unsigned u1) {
    return (u0 >> 16) | (u1 & 0xffff0000u);
}

// ---------- block reductions ----------
__device__ __forceinline__ float blk_sum(float v, float* sred) {
#pragma unroll
    for (int o = 32; o > 0; o >>= 1) v += __shfl_xor(v, o, 64);
    if ((threadIdx.x & 63) == 0) sred[threadIdx.x >> 6] = v;
    __syncthreads();
    v = sred[0] + sred[1] + sred[2] + sred[3];
    __syncthreads();
    return v;
}

// ---------- embedding (emits packed) ----------
__global__ void k_embed(const float* __restrict__ x, const float* __restrict__ ew,
                        const float* __restrict__ eb, unsigned* __restrict__ h) {
    const int idx = blockIdx.x * 256 + threadIdx.x;
    const int d = idx & (D_ - 1);
    const int n = (idx >> 8) & (S_ - 1);
    const int b = idx >> 15;
    float val = 0.f;
    if (n > 0) {
        const float* xr = x + ((size_t)b * N_ + (n - 1)) * NDIM_;
        val = eb[d] + xr[0] * ew[d * 3 + 0] + xr[1] * ew[d * 3 + 1] + xr[2] * ew[d * 3 + 2];
    }
    h[idx] = split_pack(val);
}

// ---------- weight pre-split (compact packed, for proj): fp32 -> uint [h|l<<16] ----------
__global__ void __launch_bounds__(256) k_wconv(const float* __restrict__ src, unsigned* __restrict__ dst) {
    const int idx = (blockIdx.x * 256 + threadIdx.x) * 4;
    const float4 w4 = *(const float4*)&src[idx];
    const float v[4] = {w4.x, w4.y, w4.z, w4.w};
    unsigned u[4];
#pragma unroll
    for (int i = 0; i < 4; i++) u[i] = split_pack(v[i]);
    *(uint4*)&dst[idx] = make_uint4(u[0], u[1], u[2], u[3]);
}

// ---------- weight pre-split into MFMA fragment-order bf16 planes ----------
__global__ void __launch_bounds__(256) k_wconvp(const float* __restrict__ src,
                                                ushort* __restrict__ dh, ushort* __restrict__ dl) {
    const int tid = blockIdx.x * 256 + threadIdx.x;
    const int l = tid >> 13;
    const int col = (tid >> 5) & 255, kc = tid & 31;
    const float* sp = src + ((size_t)l << 16) + col * 256 + kc * 8;
    float v[8];
    *(float4*)&v[0] = *(const float4*)sp;
    *(float4*)&v[4] = *(const float4*)(sp + 4);
    unsigned hu[4], lu[4];
#pragma unroll
    for (int i = 0; i < 4; i++) {
        const unsigned u0 = split_pack(v[2 * i]);
        const unsigned u1 = split_pack(v[2 * i + 1]);
        hu[i] = hpair(u0, u1);
        lu[i] = lpair(u0, u1);
    }
    const size_t off = ((size_t)l << 16) + ((size_t)(kc * 256 + col)) * 8;
    *(uint4*)&dh[off] = make_uint4(hu[0], hu[1], hu[2], hu[3]);
    *(uint4*)&dl[off] = make_uint4(lu[0], lu[1], lu[2], lu[3]);
}

// ---------- 3-product split MFMA GEMM, W direct-from-global ----------
template<int EPI>
__global__ void __launch_bounds__(512, 4) k_gemm(
    const unsigned* __restrict__ Ap, const ushort* __restrict__ WH,
    const ushort* __restrict__ WL,
    const float* __restrict__ bias, const float* __restrict__ g1,
    const float* __restrict__ g2, const int* __restrict__ mask,
    unsigned* __restrict__ out)
{
    __shared__ ushort sAh[2][2080];            // [buf][chunk(4)][64 rows][8] (+pad 8/chunk)
    __shared__ ushort sAl[2][2080];
    __shared__ float sredA[64][4], sredB[64][4];
    const int t = threadIdx.x;
    const int w = t >> 6, lane = t & 63;
    const int quad = lane >> 4, l16 = lane & 15;
    const int rowbase = 32 * (w >> 2), colbase = 64 * (w & 3);
    const int colg = w & 3;
    const int row0 = blockIdx.x * 64;

    floatx4 acc[2][4];
#pragma unroll
    for (int rt = 0; rt < 2; rt++)
#pragma unroll
        for (int ct = 0; ct < 4; ct++) acc[rt][ct] = (floatx4){0.f, 0.f, 0.f, 0.f};

    // A staging: each thread handles one 4-fp32 quad of one row
    const int arow = t >> 3, akq = t & 7;
    const unsigned* AG = Ap + (size_t)(row0 + arow) * D_ + akq * 4;
    const int aidx = (akq >> 1) * 520 + arow * 8 + (akq & 1) * 4;

    {
        const uint4 a4 = *(const uint4*)AG;
        *(uint2*)&sAh[0][aidx] = make_uint2(hpair(a4.x, a4.y), hpair(a4.z, a4.w));
        *(uint2*)&sAl[0][aidx] = make_uint2(lpair(a4.x, a4.y), lpair(a4.z, a4.w));
    }
    __syncthreads();

    for (int s = 0; s < 8; s++) {
        const int p = s & 1;
        // (1) issue global A load for s+1 into registers
        uint4 a_n;
        if (s + 1 < 8) a_n = *(const uint4*)(AG + (s + 1) * 32);
        // (2) W fragments direct from global planes; A fragments from LDS[p]
        const size_t wbase = ((size_t)((s * 4 + quad) * 256 + colbase + l16)) * 8;
        const ushort* WHf = WH + wbase;
        const ushort* WLf = WL + wbase;
        short8 ah[2], al[2], wh[4], wl[4];
#pragma unroll
        for (int ct = 0; ct < 4; ct++) {
            wh[ct] = *(const short8*)&WHf[ct * 128];
            wl[ct] = *(const short8*)&WLf[ct * 128];
        }
#pragma unroll
        for (int rt = 0; rt < 2; rt++) {
            const int ai = quad * 520 + (rowbase + 16 * rt + l16) * 8;
            ah[rt] = *(const short8*)&sAh[p][ai];
            al[rt] = *(const short8*)&sAl[p][ai];
        }
#pragma unroll
        for (int rt = 0; rt < 2; rt++)
#pragma unroll
            for (int ct = 0; ct < 4; ct++) {
                acc[rt][ct] = __builtin_amdgcn_mfma_f32_16x16x32_bf16(ah[rt], wh[ct], acc[rt][ct], 0, 0, 0);
                acc[rt][ct] = __builtin_amdgcn_mfma_f32_16x16x32_bf16(ah[rt], wl[ct], acc[rt][ct], 0, 0, 0);
                acc[rt][ct] = __builtin_amdgcn_mfma_f32_16x16x32_bf16(al[rt], wh[ct], acc[rt][ct], 0, 0, 0);
            }
        // (3) write s+1 into the other buffer, one barrier
        if (s + 1 < 8) {
            *(uint2*)&sAh[p ^ 1][aidx] = make_uint2(hpair(a_n.x, a_n.y), hpair(a_n.z, a_n.w));
            *(uint2*)&sAl[p ^ 1][aidx] = make_uint2(lpair(a_n.x, a_n.y), lpair(a_n.z, a_n.w));
        }
        __syncthreads();
    }

    int colv[4]; float bv[4];
#pragma unroll
    for (int ct = 0; ct < 4; ct++) { colv[ct] = colbase + 16 * ct + l16; bv[ct] = bias[colv[ct]]; }

    if (EPI <= 1) {
        const int b = row0 >> 7;
#pragma unroll
        for (int rt = 0; rt < 2; rt++)
#pragma unroll
        for (int i = 0; i < 4; i++) {
            const int rl = rowbase + 16 * rt + quad * 4 + i;
            const int n = (row0 + rl) & (S_ - 1);
            float keep = 1.f;
            if (EPI == 1) keep = (n == 0) ? 1.f : (mask[b * N_ + n - 1] ? 0.f : 1.f);
#pragma unroll
            for (int ct = 0; ct < 4; ct++) {
                float c = acc[rt][ct][i] + bv[ct];
                if (EPI == 1) c *= keep;
                const int col = colv[ct];
                out[(((size_t)b * H_ + (col >> 5)) * S_ + n) * DH_ + (col & 31)] = split_pack(c);
            }
        }
    } else if (EPI == 2) {
        float gv[4], bbv[4];
#pragma unroll
        for (int ct = 0; ct < 4; ct++) { gv[ct] = g1[colv[ct]]; bbv[ct] = g2[colv[ct]]; }
#pragma unroll
        for (int rt = 0; rt < 2; rt++)
#pragma unroll
        for (int i = 0; i < 4; i++) {
            const int rl = rowbase + 16 * rt + quad * 4 + i;
            float s = 0.f, s2 = 0.f;
#pragma unroll
            for (int ct = 0; ct < 4; ct++) {
                const float c = acc[rt][ct][i] + bv[ct];
                s += c; s2 += c * c;
            }
#pragma unroll
            for (int o = 8; o > 0; o >>= 1) { s += __shfl_xor(s, o, 64); s2 += __shfl_xor(s2, o, 64); }
            if (l16 == 0) { sredA[rl][colg] = s; sredB[rl][colg] = s2; }
        }
        __syncthreads();
#pragma unroll
        for (int rt = 0; rt < 2; rt++)
#pragma unroll
        for (int i = 0; i < 4; i++) {
            const int rl = rowbase + 16 * rt + quad * 4 + i;
            const float s = sredA[rl][0] + sredA[rl][1] + sredA[rl][2] + sredA[rl][3];
            const float s2 = sredB[rl][0] + sredB[rl][1] + sredB[rl][2] + sredB[rl][3];
            const float mu = s * (1.f / D_);
            const float rs = rsqrtf(s2 * (1.f / D_) - mu * mu + 1e-5f);
#pragma unroll
            for (int ct = 0; ct < 4; ct++) {
                const float c = acc[rt][ct][i] + bv[ct];
                out[(size_t)(row0 + rl) * D_ + colv[ct]] = split_pack((c - mu) * rs * gv[ct] + bbv[ct]);
            }
        }
    } else {
#pragma unroll
        for (int rt = 0; rt < 2; rt++)
#pragma unroll
        for (int i = 0; i < 4; i++) {
            const int rl = rowbase + 16 * rt + quad * 4 + i;
#pragma unroll
            for (int ct = 0; ct < 4; ct++) {
                const float c = acc[rt][ct][i] + bv[ct];
                out[(size_t)(row0 + rl) * D_ + colv[ct]] = split_pack((c >= 0.f) ? c : 0.2f * c);
            }
        }
    }
}

// ---------- reset kmax slots ----------
__global__ void k_reset(int* slots) {
    if (threadIdx.x < 4) {
        const int i = __float_as_int(-INFINITY);
        slots[threadIdx.x] = (i >= 0) ? i : (i ^ 0x7fffffff);
    }
}

// ---------- MFMA global k-max (packed K input) ----------
__global__ void __launch_bounds__(256) k_dmax(
    const unsigned* __restrict__ kg, const unsigned* __restrict__ P2, int* __restrict__ slot)
{
    __shared__ __align__(16) ushort A2s[64 * 136];
    __shared__ __align__(16) ushort Ps[128 * 136];
    __shared__ float sred[4];
    const int t = threadIdx.x;
    const size_t row0 = (size_t)(blockIdx.x >> 1) * 64;
    const int m0 = (blockIdx.x & 1) * 128;
    {
        const int row = t >> 2, kq = (t & 3) * 8;
        const unsigned* src = kg + (row0 + row) * DH_ + kq;
        const uint4 f0 = *(const uint4*)src;
        const uint4 f1 = *(const uint4*)(src + 4);
        const unsigned uu[8] = {f0.x, f0.y, f0.z, f0.w, f1.x, f1.y, f1.z, f1.w};
#pragma unroll
        for (int i = 0; i < 4; i++) {
            *(uint4*)&A2s[row * 136 + ((t & 3) * 4 + i) * 8] =
                make_uint4(dup_lo(uu[2 * i]), dup_hi(uu[2 * i]), dup_lo(uu[2 * i + 1]), dup_hi(uu[2 * i + 1]));
        }
    }
    {
        const int col = t >> 1;
        const unsigned* src = P2 + (m0 + col) * DH_ + (t & 1) * 16;
#pragma unroll
        for (int i = 0; i < 8; i++) {
            const unsigned u0 = src[2 * i], u1 = src[2 * i + 1];
            *(uint4*)&Ps[col * 136 + ((t & 1) * 8 + i) * 8] = make_uint4(u0, u0, u1, u1);
        }
    }
    __syncthreads();
    const int w = t >> 6, lane = t & 63, quad = lane >> 4, l16 = lane & 15;
    floatx4 acc[4][2];
#pragma unroll
    for (int rt = 0; rt < 4; rt++)
#pragma unroll
        for (int ct = 0; ct < 2; ct++) acc[rt][ct] = (floatx4){0.f, 0.f, 0.f, 0.f};
#pragma unroll
    for (int kk = 0; kk < 4; kk++) {
        short8 af[4], bf[2];
#pragma unroll
        for (int rt = 0; rt < 4; rt++)
            af[rt] = *(const short8*)&A2s[(rt * 16 + l16) * 136 + (kk * 4 + quad) * 8];
#pragma unroll
        for (int ct = 0; ct < 2; ct++)
            bf[ct] = *(const short8*)&Ps[((w * 2 + ct) * 16 + l16) * 136 + (kk * 4 + quad) * 8];
#pragma unroll
        for (int rt = 0; rt < 4; rt++)
#pragma unroll
            for (int ct = 0; ct < 2; ct++)
                acc[rt][ct] = __builtin_amdgcn_mfma_f32_16x16x32_bf16(af[rt], bf[ct], acc[rt][ct], 0, 0, 0);
    }
    float mx = -INFINITY;
#pragma unroll
    for (int rt = 0; rt < 4; rt++)
#pragma unroll
        for (int ct = 0; ct < 2; ct++)
#pragma unroll
            for (int i = 0; i < 4; i++) mx = fmaxf(mx, acc[rt][ct][i]);
#pragma unroll
    for (int o = 32; o > 0; o >>= 1) mx = fmaxf(mx, __shfl_xor(mx, o, 64));
    if (lane == 0) sred[w] = mx;
    __syncthreads();
    if (t == 0) {
        const float m4 = fmaxf(fmaxf(sred[0], sred[1]), fmaxf(sred[2], sred[3]))
                       * 0.42044820762685725f;
        const int i = __float_as_int(m4);
        atomicMax(slot, (i >= 0) ? i : (i ^ 0x7fffffff));
    }
}

// ---------- full-MFMA performer attention v3 (fast exp + fast split), 1024 threads ----------
// VALU diet vs v2: __expf (2 insts) instead of lib exp2f; kmax folded into
// sdk at producer; kp/qp packing via 5-inst split_pack_fast. ~-40% VALU/thread.
__global__ void __launch_bounds__(1024) k_attn2(
    const unsigned* __restrict__ qg, const unsigned* __restrict__ kg, const unsigned* __restrict__ vg,
    const unsigned* __restrict__ P2, const int* __restrict__ slot,
    unsigned* __restrict__ outp)
{
    extern __shared__ char smem[];
    ushort* sA    = (ushort*)(smem);            // [128][136]: K-split
    ushort* sB    = (ushort*)(smem + 34816);    // [64][136]: P-quarter {h,l,h,l}
    ushort* sBig  = (ushort*)(smem + 52224);    // kpT [64][264]; later oRed f32[4096]
    ushort* sV    = (ushort*)(smem + 86016);    // [32][264]: v dup
    ushort* sCtx  = (ushort*)(smem + 102912);   // [32][520]: ctx dup
    float* sdk    = (float*)(smem + 136192);    // [128]  (includes +kmax fold)
    float* sdq    = (float*)(smem + 136704);    // [128]
    float* smaxP  = (float*)(smem + 137216);    // [2][128]
    float* sdenP  = (float*)(smem + 138240);    // [2][128]
    float* sksum  = (float*)(smem + 139264);    // [256]
    float* sksP   = (float*)(smem + 140288);    // [16][32]

    const int bh = blockIdx.x;
    const int b = bh >> 3, hh = bh & 7;
    const int t = threadIdx.x;
    const int w = t >> 6, lane = t & 63, quad = lane >> 4, l16 = lane & 15;
    const int wg = w & 7, wh = w >> 3;
    const int nq = wg * 16 + l16;
    const unsigned* kb = kg + (size_t)bh * S_ * DH_;
    const unsigned* qb = qg + (size_t)bh * S_ * DH_;
    const unsigned* vb = vg + (size_t)bh * S_ * DH_;
    const float nrm = 0.42044820762685725f;
    const float diagc = 0.5f * nrm * nrm;
    const float ratio = 0.0625f;

    union U8 { uint4 u; short8 s; };

    // global k-max (read early; folded into sdk below)
    float kmaxv;
    { const int iv = *slot; kmaxv = __int_as_float((iv >= 0) ? iv : (iv ^ 0x7fffffff)); }

    // Q B-fragments into regs from packed
    short8 qf[4];
    {
        const unsigned* qrow = qb + (size_t)nq * DH_ + quad * 2;
#pragma unroll
        for (int ks = 0; ks < 4; ks++) {
            const uint2 qv = *(const uint2*)(qrow + ks * 8);
            U8 tmp; tmp.u = make_uint4(dup_lo(qv.x), dup_hi(qv.x), dup_lo(qv.y), dup_hi(qv.y));
            qf[ks] = tmp.s;
        }
    }

    if (t < 512) {
        const int row = t >> 2, seg = t & 3;
        const unsigned* src = kb + row * DH_ + seg * 8;
        const uint4 f0 = *(const uint4*)&src[0];
        const uint4 f1 = *(const uint4*)&src[4];
        const unsigned uu[8] = {f0.x, f0.y, f0.z, f0.w, f1.x, f1.y, f1.z, f1.w};
#pragma unroll
        for (int p = 0; p < 4; p++) {
            *(uint4*)&sA[row * 136 + seg * 32 + p * 8] =
                make_uint4(dup_lo(uu[2 * p]), dup_hi(uu[2 * p]), dup_lo(uu[2 * p + 1]), dup_hi(uu[2 * p + 1]));
        }
    } else {
        const int tt2 = t - 512;
        const int n = tt2 & 127, d0 = (tt2 >> 7) * 8;
        const unsigned* src = vb + n * DH_ + d0;
        const uint4 f0 = *(const uint4*)&src[0];
        const uint4 f1 = *(const uint4*)&src[4];
        const unsigned uu[8] = {f0.x, f0.y, f0.z, f0.w, f1.x, f1.y, f1.z, f1.w};
        unsigned* dst = (unsigned*)sV;
#pragma unroll
        for (int j = 0; j < 8; j++)
            dst[(d0 + j) * 132 + n] = dup_lo(uu[j]);
    }
    if (t < 128) {
        float s = 0.f, s2 = 0.f;
#pragma unroll
        for (int d4 = 0; d4 < DH_ / 4; d4++) {
            const uint4 kk = *(const uint4*)&kb[t * DH_ + d4 * 4];
            const float k0 = rec(kk.x), k1 = rec(kk.y), k2 = rec(kk.z), k3 = rec(kk.w);
            s += k0 * k0 + k1 * k1 + k2 * k2 + k3 * k3;
            const uint4 qq = *(const uint4*)&qb[t * DH_ + d4 * 4];
            const float q0 = rec(qq.x), q1 = rec(qq.y), q2 = rec(qq.z), q3 = rec(qq.w);
            s2 += q0 * q0 + q1 * q1 + q2 * q2 + q3 * q3;
        }
        sdk[t] = s * diagc + kmaxv;     // kmax folded: kp arg = acc*nrm - sdk[n]
        sdq[t] = s2 * diagc;
    }
    __syncthreads();

    // adq[j][mtl]: qp dd for this wave's qds (wh=1 -> qd {0,2}; wh=0 -> qd {1,3})
    floatx4 adq[2][4];
#pragma unroll
    for (int j = 0; j < 2; j++)
#pragma unroll
        for (int mtl = 0; mtl < 4; mtl++) adq[j][mtl] = (floatx4){0.f, 0.f, 0.f, 0.f};

#pragma unroll
    for (int qd = 0; qd < 4; qd++) {
        // stage P quarter
        {
            const int col = t >> 4, ch2 = t & 15;
            const unsigned* src = P2 + (size_t)(qd * 64 + col) * DH_ + ch2 * 2;
            const unsigned u0 = src[0], u1 = src[1];
            *(uint4*)&sB[col * 136 + ch2 * 8] = make_uint4(u0, u0, u1, u1);
        }
        __syncthreads();
        // phase B: kp MFMAs (all 16 waves) + exp/split/pack + ksum partials
        floatx4 acc[2];
        acc[0] = (floatx4){0.f, 0.f, 0.f, 0.f};
        acc[1] = (floatx4){0.f, 0.f, 0.f, 0.f};
#pragma unroll
        for (int ks = 0; ks < 4; ks++) {
            const short8 af = *(const short8*)&sA[nq * 136 + ks * 32 + quad * 8];
            short8 bf[2];
#pragma unroll
            for (int ctl = 0; ctl < 2; ctl++)
                bf[ctl] = *(const short8*)&sB[((2 * wh + ctl) * 16 + l16) * 136 + ks * 32 + quad * 8];
#pragma unroll
            for (int ctl = 0; ctl < 2; ctl++)
                acc[ctl] = __builtin_amdgcn_mfma_f32_16x16x32_bf16(af, bf[ctl], acc[ctl], 0, 0, 0);
        }
        unsigned* kpT = (unsigned*)sBig;
        float kc[2];
#pragma unroll
        for (int ctl = 0; ctl < 2; ctl++) {
            float kcl = 0.f;
            unsigned pk[4];
#pragma unroll
            for (int i = 0; i < 4; i++) {
                const int n = wg * 16 + quad * 4 + i;
                const float kp = ratio * (__expf(acc[ctl][i] * nrm - sdk[n]) + 1e-4f);
                kcl += kp;
                pk[i] = split_pack_fast(kp);
            }
            *(uint4*)&kpT[((2 * wh + ctl) * 16 + l16) * 132 + wg * 16 + quad * 4] =
                make_uint4(pk[0], pk[1], pk[2], pk[3]);
            kc[ctl] = kcl;
        }
#pragma unroll
        for (int ctl = 0; ctl < 2; ctl++) {
            kc[ctl] += __shfl_xor(kc[ctl], 16, 64);
            kc[ctl] += __shfl_xor(kc[ctl], 32, 64);
        }
        if (quad == 0) {
            sksP[w * 32 + l16] = kc[0];
            sksP[w * 32 + 16 + l16] = kc[1];
        }
        __syncthreads();
        // phase C: one half does qp MFMAs (B from regs), other half does ctx MFMAs
        const int qown = (qd & 1) ^ 1;
        if (wh == qown) {
            const int aidx = qd >> 1;
#pragma unroll
            for (int mtl = 0; mtl < 4; mtl++)
#pragma unroll
                for (int ks = 0; ks < 4; ks++) {
                    const short8 af2 = *(const short8*)&sB[(mtl * 16 + l16) * 136 + ks * 32 + quad * 8];
                    adq[aidx][mtl] = __builtin_amdgcn_mfma_f32_16x16x32_bf16(af2, qf[ks], adq[aidx][mtl], 0, 0, 0);
                }
        } else {
            const int mt = wg & 3, dt = wg >> 2;
            floatx4 cacc = (floatx4){0.f, 0.f, 0.f, 0.f};
#pragma unroll
            for (int ks = 0; ks < 8; ks++) {
                const short8 a = *(const short8*)&sBig[(mt * 16 + l16) * 264 + ks * 32 + quad * 8];
                const short8 bvv = *(const short8*)&sV[(dt * 16 + l16) * 264 + ks * 32 + quad * 8];
                cacc = __builtin_amdgcn_mfma_f32_16x16x32_bf16(a, bvv, cacc, 0, 0, 0);
            }
            unsigned* ctxB = (unsigned*)sCtx;
            unsigned pk2[4];
#pragma unroll
            for (int i = 0; i < 4; i++) pk2[i] = (unsigned)bf16_rn(cacc[i]) * 0x10001u;
            *(uint4*)&ctxB[(dt * 16 + l16) * 260 + qd * 64 + mt * 16 + quad * 4] =
                make_uint4(pk2[0], pk2[1], pk2[2], pk2[3]);
        }
        if (t < 64) {
            float s = 0.f;
#pragma unroll
            for (int wg2 = 0; wg2 < 8; wg2++)
                s += sksP[((t >> 5) * 8 + wg2) * 32 + (t & 31)];
            sksum[qd * 64 + t] = s;
        }
        __syncthreads();
    }

    // row max over this wave's half of (qd,m); union across wh = full m range
    {
        float mxn = -INFINITY;
#pragma unroll
        for (int j = 0; j < 2; j++)
#pragma unroll
            for (int mtl = 0; mtl < 4; mtl++)
#pragma unroll
                for (int i = 0; i < 4; i++) mxn = fmaxf(mxn, adq[j][mtl][i]);
        mxn = fmaxf(mxn, __shfl_xor(mxn, 16, 64));
        mxn = fmaxf(mxn, __shfl_xor(mxn, 32, 64));
        if (quad == 0) smaxP[wh * 128 + nq] = mxn;
    }
    __syncthreads();
    const float dmq = sdq[nq] + fmaxf(smaxP[nq], smaxP[128 + nq]) * nrm;

    // o^T[d][n]: A = ctx^T from sCtx (dup), B = exp+split of adq straight from regs.
    floatx4 oT[2];
    oT[0] = (floatx4){0.f, 0.f, 0.f, 0.f};
    oT[1] = (floatx4){0.f, 0.f, 0.f, 0.f};
    float dp = 0.f;
#pragma unroll
    for (int j = 0; j < 2; j++) {
        const int qdo = 2 * j + (wh ^ 1);
#pragma unroll
        for (int mtl = 0; mtl < 4; mtl++) {
            unsigned pk[4];
#pragma unroll
            for (int i = 0; i < 4; i++) {
                const float qp = ratio * (__expf(adq[j][mtl][i] * nrm - dmq) + 1e-4f);
                dp += qp * sksum[qdo * 64 + mtl * 16 + quad * 4 + i];
                pk[i] = split_pack_fast(qp);
            }
            U8 tb; tb.u = make_uint4(pk[0], pk[1], pk[2], pk[3]);
#pragma unroll
            for (int dt = 0; dt < 2; dt++) {
                const short8 actx = *(const short8*)&sCtx[(dt * 16 + l16) * 520 + qdo * 128 + mtl * 32 + quad * 8];
                oT[dt] = __builtin_amdgcn_mfma_f32_16x16x32_bf16(actx, tb.s, oT[dt], 0, 0, 0);
            }
        }
    }
    dp += __shfl_xor(dp, 16, 64);
    dp += __shfl_xor(dp, 32, 64);
    if (quad == 0) sdenP[wh * 128 + nq] = dp;

    // cross-half o reduction through dead kpT space, then coalesced packed store
    float* oRed = (float*)sBig;
    if (wh == 1) {
#pragma unroll
        for (int dt = 0; dt < 2; dt++)
            *(floatx4*)&oRed[((wg * 2 + dt) * 64 + lane) * 4] = oT[dt];
    }
    __syncthreads();
    if (wh == 0) {
        const float inv = 1.0f / (sdenP[nq] + sdenP[128 + nq]);
#pragma unroll
        for (int dt = 0; dt < 2; dt++) {
            const floatx4 o2 = *(const floatx4*)&oRed[((wg * 2 + dt) * 64 + lane) * 4];
            const unsigned r0 = split_pack((oT[dt][0] + o2[0]) * inv);
            const unsigned r1 = split_pack((oT[dt][1] + o2[1]) * inv);
            const unsigned r2 = split_pack((oT[dt][2] + o2[2]) * inv);
            const unsigned r3 = split_pack((oT[dt][3] + o2[3]) * inv);
            *(uint4*)&outp[((size_t)b * S_ + nq) * D_ + hh * DH_ + dt * 16 + quad * 4] =
                make_uint4(r0, r1, r2, r3);
        }
    }
}

// ---------- classification head (packed input) ----------
__global__ void __launch_bounds__(256) k_head(
    const unsigned* __restrict__ hfin, const float* __restrict__ h1w, const float* __restrict__ h1b,
    const float* __restrict__ h2w, const float* __restrict__ h2b,
    const float* __restrict__ ow, const float* __restrict__ ob, float* __restrict__ outp)
{
    __shared__ float c0[D_];
    __shared__ float c1[2 * HID_];
    __shared__ float sred[4];
    const int t = threadIdx.x;
    const int b = blockIdx.x;
    c0[t] = rec(hfin[(size_t)b * S_ * D_ + t]);
    __syncthreads();
#pragma unroll
    for (int half = 0; half < 2; half++) {
        const int j = half * 256 + t;
        float a = h1b[j];
        const float* w = h1w + (size_t)j * D_;
        for (int d = 0; d < D_; d += 4) {
            const float4 w4 = *(const float4*)&w[d];
            const float4 x4 = *(const float4*)&c0[d];
            a += x4.x * w4.x + x4.y * w4.y + x4.z * w4.z + x4.w * w4.w;
        }
        c1[j] = (a >= 0.f) ? a : 0.2f * a;
    }
    __syncthreads();
    float a2 = h2b[t];
    const float* w2 = h2w + (size_t)t * (2 * HID_);
    for (int j = 0; j < 2 * HID_; j += 4) {
        const float4 w4 = *(const float4*)&w2[j];
        const float4 x4 = *(const float4*)&c1[j];
        a2 += x4.x * w4.x + x4.y * w4.y + x4.z * w4.z + x4.w * w4.w;
    }
    const float c2 = (a2 >= 0.f) ? a2 : 0.2f * a2;
    const float s = blk_sum(c2 * ow[t], sred);
    if (t == 0) outp[b] = s + ob[0];
}

extern "C" void kernel_launch(void* const* d_in, const int* in_sizes, int n_in,
                              void* d_out, int out_size, void* d_ws, size_t ws_size,
                              hipStream_t stream)
{
    const float* x     = (const float*)d_in[0];
    const int*   mask  = (const int*)d_in[1];
    const float* emb_w = (const float*)d_in[2];
    const float* emb_b = (const float*)d_in[3];
    const float* Wq    = (const float*)d_in[4];
    const float* bq    = (const float*)d_in[5];
    const float* Wk    = (const float*)d_in[6];
    const float* bk    = (const float*)d_in[7];
    const float* Wv    = (const float*)d_in[8];
    const float* bv    = (const float*)d_in[9];
    const float* Wo    = (const float*)d_in[10];
    const float* bo    = (const float*)d_in[11];
    const float* proj  = (const float*)d_in[12];
    const float* n1w   = (const float*)d_in[13];
    const float* n1b   = (const float*)d_in[14];
    const float* n2w   = (const float*)d_in[15];
    const float* n2b   = (const float*)d_in[16];
    const float* f1w   = (const float*)d_in[17];
    const float* f1b   = (const float*)d_in[18];
    const float* f2w   = (const float*)d_in[19];
    const float* f2b   = (const float*)d_in[20];
    const float* h1w   = (const float*)d_in[21];
    const float* h1b   = (const float*)d_in[22];
    const float* h2w   = (const float*)d_in[23];
    const float* h2b   = (const float*)d_in[24];
    const float* ow    = (const float*)d_in[25];
    const float* ob    = (const float*)d_in[26];

    const size_t BSD = (size_t)B_ * S_ * D_;
    unsigned* A = (unsigned*)d_ws;                 // packed activations
    unsigned* Q = A + BSD;
    unsigned* K = Q + BSD;
    unsigned* V = K + BSD;
    unsigned* T = K;                               // post-LN1 alias (K dead after attn)
    const size_t WMU = 65536;                      // ushorts per matrix plane (256x256)
    ushort* WH = (ushort*)(V + BSD);               // 6 x L x 65536 ushorts (h planes)
    ushort* WL = WH + 6 * L_ * WMU;                // 6 x L x 65536 ushorts (l planes)
    unsigned* P2 = (unsigned*)(WL + 6 * L_ * WMU); // compact split proj: L x 256 x 32 uints
    int* slots = (int*)(P2 + (size_t)L_ * M_ * DH_);

    k_wconvp<<<128, 256, 0, stream>>>(Wq,  WH + 0 * L_ * WMU, WL + 0 * L_ * WMU);
    k_wconvp<<<128, 256, 0, stream>>>(Wk,  WH + 1 * L_ * WMU, WL + 1 * L_ * WMU);
    k_wconvp<<<128, 256, 0, stream>>>(Wv,  WH + 2 * L_ * WMU, WL + 2 * L_ * WMU);
    k_wconvp<<<128, 256, 0, stream>>>(Wo,  WH + 3 * L_ * WMU, WL + 3 * L_ * WMU);
    k_wconvp<<<128, 256, 0, stream>>>(f1w, WH + 4 * L_ * WMU, WL + 4 * L_ * WMU);
    k_wconvp<<<128, 256, 0, stream>>>(f2w, WH + 5 * L_ * WMU, WL + 5 * L_ * WMU);
    k_wconv<<<32, 256, 0, stream>>>(proj, P2);
    k_reset<<<1, 64, 0, stream>>>(slots);

    const int GB = B_ * S_ / 64;               // 512 blocks per GEMM
    const int DB = B_ * H_ * S_ / 64 * 2;      // 8192 blocks for k_dmax
    const size_t ATTN_LDS = 142336;            // 139 KB dynamic LDS

    k_embed<<<B_ * S_ * D_ / 256, 256, 0, stream>>>(x, emb_w, emb_b, A);
    for (int l = 0; l < L_; l++) {
        const unsigned* P2l = P2 + (size_t)l * M_ * DH_;
        k_gemm<0><<<GB, 512, 0, stream>>>(A, WH + (0 * L_ + l) * WMU, WL + (0 * L_ + l) * WMU, bq + l * D_, nullptr, nullptr, nullptr, Q);
        k_gemm<0><<<GB, 512, 0, stream>>>(A, WH + (1 * L_ + l) * WMU, WL + (1 * L_ + l) * WMU, bk + l * D_, nullptr, nullptr, nullptr, K);
        k_gemm<1><<<GB, 512, 0, stream>>>(A, WH + (2 * L_ + l) * WMU, WL + (2 * L_ + l) * WMU, bv + l * D_, nullptr, nullptr, mask, V);
        k_dmax<<<DB, 256, 0, stream>>>(K, P2l, slots + l);
        k_attn2<<<B_ * H_, 1024, ATTN_LDS, stream>>>(Q, K, V, P2l, slots + l, A);
        k_gemm<2><<<GB, 512, 0, stream>>>(A, WH + (3 * L_ + l) * WMU, WL + (3 * L_ + l) * WMU, bo + l * D_, n1w + l * D_, n1b + l * D_, nullptr, T);
        k_gemm<3><<<GB, 512, 0, stream>>>(T, WH + (4 * L_ + l) * WMU, WL + (4 * L_ + l) * WMU, f1b + l * HID_, nullptr, nullptr, nullptr, Q);
        k_gemm<2><<<GB, 512, 0, stream>>>(Q, WH + (5 * L_ + l) * WMU, WL + (5 * L_ + l) * WMU, f2b + l * D_, n2w + l * D_, n2b + l * D_, nullptr, A);
    }
    k_head<<<B_, 256, 0, stream>>>(A, h1w, h1b, h2w, h2b, ow, ob, (float*)d_out);
}

// Round 6
// 1588.864 us; speedup vs baseline: 1.2791x; 1.0310x over previous
//
#include <hip/hip_runtime.h>
#include <math.h>

#define B_ 256
#define N_ 127
#define S_ 128
#define NDIM_ 3
#define D_ 256
#define H_ 8
#define DH_ 32
#define M_ 256
#define HID_ 256
#define L_ 4
#define LOG2E 1.44269504088896340736f

typedef __attribute__((ext_vector_type(8))) short short8;
typedef __attribute__((ext_vector_type(4))) float floatx4;

// ---------- bf16 split helpers ----------
__device__ __forceinline__ ushort bf16_rn(float x) {
    unsigned u = __float_as_uint(x);
    u = (u + 0x7fffu + ((u >> 16) & 1u)) >> 16;
    return (ushort)u;
}
__device__ __forceinline__ unsigned split_pack(float x) {
    const ushort h = bf16_rn(x);
    const float r = x - __uint_as_float(((unsigned)h) << 16);
    const ushort l = bf16_rn(r);
    return (unsigned)h | ((unsigned)l << 16);
}
// Fast 5-inst split (attn-internal kp/qp)
__device__ __forceinline__ unsigned split_pack_fast(float x) {
    const unsigned xu = __float_as_uint(x);
    const unsigned hb = xu & 0xffff0000u;
    const float r = x - __uint_as_float(hb);
    return (hb >> 16) | (__float_as_uint(r) & 0xffff0000u);
}
__device__ __forceinline__ unsigned dup_lo(unsigned u) {
    const unsigned h = u & 0xffffu;
    return h | (h << 16);
}
__device__ __forceinline__ unsigned dup_hi(unsigned u) {
    const unsigned l = u >> 16;
    return l | (l << 16);
}
__device__ __forceinline__ float rec(unsigned u) {
    return __uint_as_float(u << 16) + __uint_as_float(u & 0xffff0000u);
}
__device__ __forceinline__ unsigned hpair(unsigned u0, unsigned u1) {
    return (u0 & 0xffffu) | (u1 << 16);
}
__device__ __forceinline__ unsigned lpair(unsigned u0, unsigned u1) {
    return (u0 >> 16) | (u1 & 0xffff0000u);
}

// ---------- block reductions ----------
__device__ __forceinline__ float blk_sum(float v, float* sred) {
#pragma unroll
    for (int o = 32; o > 0; o >>= 1) v += __shfl_xor(v, o, 64);
    if ((threadIdx.x & 63) == 0) sred[threadIdx.x >> 6] = v;
    __syncthreads();
    v = sred[0] + sred[1] + sred[2] + sred[3];
    __syncthreads();
    return v;
}

// ---------- embedding (emits packed) ----------
__global__ void k_embed(const float* __restrict__ x, const float* __restrict__ ew,
                        const float* __restrict__ eb, unsigned* __restrict__ h) {
    const int idx = blockIdx.x * 256 + threadIdx.x;
    const int d = idx & (D_ - 1);
    const int n = (idx >> 8) & (S_ - 1);
    const int b = idx >> 15;
    float val = 0.f;
    if (n > 0) {
        const float* xr = x + ((size_t)b * N_ + (n - 1)) * NDIM_;
        val = eb[d] + xr[0] * ew[d * 3 + 0] + xr[1] * ew[d * 3 + 1] + xr[2] * ew[d * 3 + 2];
    }
    h[idx] = split_pack(val);
}

// ---------- fused prep: 6x weight-plane conv + proj conv + slot reset (1 dispatch) ----------
// blocks 0-767: wconvp for tensor blockIdx/128 (layout [kc][col][8] h/l planes)
// blocks 768-799: proj packed conv; block 800: kmax slot reset
__global__ void __launch_bounds__(256) k_prep(
    const float* __restrict__ Wq, const float* __restrict__ Wk, const float* __restrict__ Wv,
    const float* __restrict__ Wo, const float* __restrict__ f1w, const float* __restrict__ f2w,
    const float* __restrict__ proj, ushort* __restrict__ WH, ushort* __restrict__ WL,
    unsigned* __restrict__ P2, int* __restrict__ slots)
{
    const int bid = blockIdx.x;
    if (bid < 768) {
        const int tensor = bid / 128;
        const int tid = (bid & 127) * 256 + threadIdx.x;
        const float* src = tensor == 0 ? Wq : tensor == 1 ? Wk : tensor == 2 ? Wv
                         : tensor == 3 ? Wo : tensor == 4 ? f1w : f2w;
        ushort* dh = WH + (size_t)tensor * L_ * 65536;
        ushort* dl = WL + (size_t)tensor * L_ * 65536;
        const int l = tid >> 13;
        const int col = (tid >> 5) & 255, kc = tid & 31;
        const float* sp = src + ((size_t)l << 16) + col * 256 + kc * 8;
        float v[8];
        *(float4*)&v[0] = *(const float4*)sp;
        *(float4*)&v[4] = *(const float4*)(sp + 4);
        unsigned hu[4], lu[4];
#pragma unroll
        for (int i = 0; i < 4; i++) {
            const unsigned u0 = split_pack(v[2 * i]);
            const unsigned u1 = split_pack(v[2 * i + 1]);
            hu[i] = hpair(u0, u1);
            lu[i] = lpair(u0, u1);
        }
        const size_t off = ((size_t)l << 16) + ((size_t)(kc * 256 + col)) * 8;
        *(uint4*)&dh[off] = make_uint4(hu[0], hu[1], hu[2], hu[3]);
        *(uint4*)&dl[off] = make_uint4(lu[0], lu[1], lu[2], lu[3]);
    } else if (bid < 800) {
        const int idx = ((bid - 768) * 256 + threadIdx.x) * 4;
        const float4 w4 = *(const float4*)&proj[idx];
        const float v[4] = {w4.x, w4.y, w4.z, w4.w};
        unsigned u[4];
#pragma unroll
        for (int i = 0; i < 4; i++) u[i] = split_pack(v[i]);
        *(uint4*)&P2[idx] = make_uint4(u[0], u[1], u[2], u[3]);
    } else {
        if (threadIdx.x < 4) {
            const int i = __float_as_int(-INFINITY);
            slots[threadIdx.x] = (i >= 0) ? i : (i ^ 0x7fffffff);
        }
    }
}

// ---------- 3-product split MFMA GEMM, W direct-from-global ----------
template<int EPI>
__global__ void __launch_bounds__(512, 4) k_gemm(
    const unsigned* __restrict__ Ap, const ushort* __restrict__ WH,
    const ushort* __restrict__ WL,
    const float* __restrict__ bias, const float* __restrict__ g1,
    const float* __restrict__ g2, const int* __restrict__ mask,
    unsigned* __restrict__ out)
{
    __shared__ ushort sAh[2][2080];
    __shared__ ushort sAl[2][2080];
    __shared__ float sredA[64][4], sredB[64][4];
    const int t = threadIdx.x;
    const int w = t >> 6, lane = t & 63;
    const int quad = lane >> 4, l16 = lane & 15;
    const int rowbase = 32 * (w >> 2), colbase = 64 * (w & 3);
    const int colg = w & 3;
    const int row0 = blockIdx.x * 64;

    floatx4 acc[2][4];
#pragma unroll
    for (int rt = 0; rt < 2; rt++)
#pragma unroll
        for (int ct = 0; ct < 4; ct++) acc[rt][ct] = (floatx4){0.f, 0.f, 0.f, 0.f};

    const int arow = t >> 3, akq = t & 7;
    const unsigned* AG = Ap + (size_t)(row0 + arow) * D_ + akq * 4;
    const int aidx = (akq >> 1) * 520 + arow * 8 + (akq & 1) * 4;

    {
        const uint4 a4 = *(const uint4*)AG;
        *(uint2*)&sAh[0][aidx] = make_uint2(hpair(a4.x, a4.y), hpair(a4.z, a4.w));
        *(uint2*)&sAl[0][aidx] = make_uint2(lpair(a4.x, a4.y), lpair(a4.z, a4.w));
    }
    __syncthreads();

    for (int s = 0; s < 8; s++) {
        const int p = s & 1;
        uint4 a_n;
        if (s + 1 < 8) a_n = *(const uint4*)(AG + (s + 1) * 32);
        const size_t wbase = ((size_t)((s * 4 + quad) * 256 + colbase + l16)) * 8;
        const ushort* WHf = WH + wbase;
        const ushort* WLf = WL + wbase;
        short8 ah[2], al[2], wh[4], wl[4];
#pragma unroll
        for (int ct = 0; ct < 4; ct++) {
            wh[ct] = *(const short8*)&WHf[ct * 128];
            wl[ct] = *(const short8*)&WLf[ct * 128];
        }
#pragma unroll
        for (int rt = 0; rt < 2; rt++) {
            const int ai = quad * 520 + (rowbase + 16 * rt + l16) * 8;
            ah[rt] = *(const short8*)&sAh[p][ai];
            al[rt] = *(const short8*)&sAl[p][ai];
        }
#pragma unroll
        for (int rt = 0; rt < 2; rt++)
#pragma unroll
            for (int ct = 0; ct < 4; ct++) {
                acc[rt][ct] = __builtin_amdgcn_mfma_f32_16x16x32_bf16(ah[rt], wh[ct], acc[rt][ct], 0, 0, 0);
                acc[rt][ct] = __builtin_amdgcn_mfma_f32_16x16x32_bf16(ah[rt], wl[ct], acc[rt][ct], 0, 0, 0);
                acc[rt][ct] = __builtin_amdgcn_mfma_f32_16x16x32_bf16(al[rt], wh[ct], acc[rt][ct], 0, 0, 0);
            }
        if (s + 1 < 8) {
            *(uint2*)&sAh[p ^ 1][aidx] = make_uint2(hpair(a_n.x, a_n.y), hpair(a_n.z, a_n.w));
            *(uint2*)&sAl[p ^ 1][aidx] = make_uint2(lpair(a_n.x, a_n.y), lpair(a_n.z, a_n.w));
        }
        __syncthreads();
    }

    int colv[4]; float bv[4];
#pragma unroll
    for (int ct = 0; ct < 4; ct++) { colv[ct] = colbase + 16 * ct + l16; bv[ct] = bias[colv[ct]]; }

    if (EPI <= 1) {
        const int b = row0 >> 7;
#pragma unroll
        for (int rt = 0; rt < 2; rt++)
#pragma unroll
        for (int i = 0; i < 4; i++) {
            const int rl = rowbase + 16 * rt + quad * 4 + i;
            const int n = (row0 + rl) & (S_ - 1);
            float keep = 1.f;
            if (EPI == 1) keep = (n == 0) ? 1.f : (mask[b * N_ + n - 1] ? 0.f : 1.f);
#pragma unroll
            for (int ct = 0; ct < 4; ct++) {
                float c = acc[rt][ct][i] + bv[ct];
                if (EPI == 1) c *= keep;
                const int col = colv[ct];
                out[(((size_t)b * H_ + (col >> 5)) * S_ + n) * DH_ + (col & 31)] = split_pack(c);
            }
        }
    } else if (EPI == 2) {
        float gv[4], bbv[4];
#pragma unroll
        for (int ct = 0; ct < 4; ct++) { gv[ct] = g1[colv[ct]]; bbv[ct] = g2[colv[ct]]; }
#pragma unroll
        for (int rt = 0; rt < 2; rt++)
#pragma unroll
        for (int i = 0; i < 4; i++) {
            const int rl = rowbase + 16 * rt + quad * 4 + i;
            float s = 0.f, s2 = 0.f;
#pragma unroll
            for (int ct = 0; ct < 4; ct++) {
                const float c = acc[rt][ct][i] + bv[ct];
                s += c; s2 += c * c;
            }
#pragma unroll
            for (int o = 8; o > 0; o >>= 1) { s += __shfl_xor(s, o, 64); s2 += __shfl_xor(s2, o, 64); }
            if (l16 == 0) { sredA[rl][colg] = s; sredB[rl][colg] = s2; }
        }
        __syncthreads();
#pragma unroll
        for (int rt = 0; rt < 2; rt++)
#pragma unroll
        for (int i = 0; i < 4; i++) {
            const int rl = rowbase + 16 * rt + quad * 4 + i;
            const float s = sredA[rl][0] + sredA[rl][1] + sredA[rl][2] + sredA[rl][3];
            const float s2 = sredB[rl][0] + sredB[rl][1] + sredB[rl][2] + sredB[rl][3];
            const float mu = s * (1.f / D_);
            const float rs = rsqrtf(s2 * (1.f / D_) - mu * mu + 1e-5f);
#pragma unroll
            for (int ct = 0; ct < 4; ct++) {
                const float c = acc[rt][ct][i] + bv[ct];
                out[(size_t)(row0 + rl) * D_ + colv[ct]] = split_pack((c - mu) * rs * gv[ct] + bbv[ct]);
            }
        }
    } else {
#pragma unroll
        for (int rt = 0; rt < 2; rt++)
#pragma unroll
        for (int i = 0; i < 4; i++) {
            const int rl = rowbase + 16 * rt + quad * 4 + i;
#pragma unroll
            for (int ct = 0; ct < 4; ct++) {
                const float c = acc[rt][ct][i] + bv[ct];
                out[(size_t)(row0 + rl) * D_ + colv[ct]] = split_pack((c >= 0.f) ? c : 0.2f * c);
            }
        }
    }
}

// ---------- fused Q/K/V GEMM: 3 gemms in one dispatch (grid 1536) ----------
// which = blockIdx>>9 selects {W,bias,out}; V (which==2) applies the keep mask.
// Body identical to k_gemm; arithmetic bit-identical to 3 separate dispatches.
__global__ void __launch_bounds__(512, 4) k_gemm_qkv(
    const unsigned* __restrict__ Ap, const ushort* __restrict__ WHb,
    const ushort* __restrict__ WLb, const int l,
    const float* __restrict__ bq, const float* __restrict__ bk, const float* __restrict__ bv_,
    const int* __restrict__ mask,
    unsigned* __restrict__ Qo, unsigned* __restrict__ Ko, unsigned* __restrict__ Vo)
{
    __shared__ ushort sAh[2][2080];
    __shared__ ushort sAl[2][2080];
    const int t = threadIdx.x;
    const int w = t >> 6, lane = t & 63;
    const int quad = lane >> 4, l16 = lane & 15;
    const int rowbase = 32 * (w >> 2), colbase = 64 * (w & 3);
    const int which = blockIdx.x >> 9;
    const int row0 = (blockIdx.x & 511) * 64;
    const ushort* WH = WHb + ((size_t)(which * L_ + l)) * 65536;
    const ushort* WL = WLb + ((size_t)(which * L_ + l)) * 65536;
    const float* bias = which == 0 ? bq : which == 1 ? bk : bv_;
    unsigned* out = which == 0 ? Qo : which == 1 ? Ko : Vo;

    floatx4 acc[2][4];
#pragma unroll
    for (int rt = 0; rt < 2; rt++)
#pragma unroll
        for (int ct = 0; ct < 4; ct++) acc[rt][ct] = (floatx4){0.f, 0.f, 0.f, 0.f};

    const int arow = t >> 3, akq = t & 7;
    const unsigned* AG = Ap + (size_t)(row0 + arow) * D_ + akq * 4;
    const int aidx = (akq >> 1) * 520 + arow * 8 + (akq & 1) * 4;

    {
        const uint4 a4 = *(const uint4*)AG;
        *(uint2*)&sAh[0][aidx] = make_uint2(hpair(a4.x, a4.y), hpair(a4.z, a4.w));
        *(uint2*)&sAl[0][aidx] = make_uint2(lpair(a4.x, a4.y), lpair(a4.z, a4.w));
    }
    __syncthreads();

    for (int s = 0; s < 8; s++) {
        const int p = s & 1;
        uint4 a_n;
        if (s + 1 < 8) a_n = *(const uint4*)(AG + (s + 1) * 32);
        const size_t wbase = ((size_t)((s * 4 + quad) * 256 + colbase + l16)) * 8;
        const ushort* WHf = WH + wbase;
        const ushort* WLf = WL + wbase;
        short8 ah[2], al[2], wh[4], wl[4];
#pragma unroll
        for (int ct = 0; ct < 4; ct++) {
            wh[ct] = *(const short8*)&WHf[ct * 128];
            wl[ct] = *(const short8*)&WLf[ct * 128];
        }
#pragma unroll
        for (int rt = 0; rt < 2; rt++) {
            const int ai = quad * 520 + (rowbase + 16 * rt + l16) * 8;
            ah[rt] = *(const short8*)&sAh[p][ai];
            al[rt] = *(const short8*)&sAl[p][ai];
        }
#pragma unroll
        for (int rt = 0; rt < 2; rt++)
#pragma unroll
            for (int ct = 0; ct < 4; ct++) {
                acc[rt][ct] = __builtin_amdgcn_mfma_f32_16x16x32_bf16(ah[rt], wh[ct], acc[rt][ct], 0, 0, 0);
                acc[rt][ct] = __builtin_amdgcn_mfma_f32_16x16x32_bf16(ah[rt], wl[ct], acc[rt][ct], 0, 0, 0);
                acc[rt][ct] = __builtin_amdgcn_mfma_f32_16x16x32_bf16(al[rt], wh[ct], acc[rt][ct], 0, 0, 0);
            }
        if (s + 1 < 8) {
            *(uint2*)&sAh[p ^ 1][aidx] = make_uint2(hpair(a_n.x, a_n.y), hpair(a_n.z, a_n.w));
            *(uint2*)&sAl[p ^ 1][aidx] = make_uint2(lpair(a_n.x, a_n.y), lpair(a_n.z, a_n.w));
        }
        __syncthreads();
    }

    int colv[4]; float bv[4];
#pragma unroll
    for (int ct = 0; ct < 4; ct++) { colv[ct] = colbase + 16 * ct + l16; bv[ct] = bias[colv[ct]]; }

    const int b = row0 >> 7;
#pragma unroll
    for (int rt = 0; rt < 2; rt++)
#pragma unroll
    for (int i = 0; i < 4; i++) {
        const int rl = rowbase + 16 * rt + quad * 4 + i;
        const int n = (row0 + rl) & (S_ - 1);
        float keep = 1.f;
        if (which == 2) keep = (n == 0) ? 1.f : (mask[b * N_ + n - 1] ? 0.f : 1.f);
#pragma unroll
        for (int ct = 0; ct < 4; ct++) {
            float c = acc[rt][ct][i] + bv[ct];
            c *= keep;
            const int col = colv[ct];
            out[(((size_t)b * H_ + (col >> 5)) * S_ + n) * DH_ + (col & 31)] = split_pack(c);
        }
    }
}

// ---------- MFMA global k-max (packed K input) ----------
__global__ void __launch_bounds__(256) k_dmax(
    const unsigned* __restrict__ kg, const unsigned* __restrict__ P2, int* __restrict__ slot)
{
    __shared__ __align__(16) ushort A2s[64 * 136];
    __shared__ __align__(16) ushort Ps[128 * 136];
    __shared__ float sred[4];
    const int t = threadIdx.x;
    const size_t row0 = (size_t)(blockIdx.x >> 1) * 64;
    const int m0 = (blockIdx.x & 1) * 128;
    {
        const int row = t >> 2, kq = (t & 3) * 8;
        const unsigned* src = kg + (row0 + row) * DH_ + kq;
        const uint4 f0 = *(const uint4*)src;
        const uint4 f1 = *(const uint4*)(src + 4);
        const unsigned uu[8] = {f0.x, f0.y, f0.z, f0.w, f1.x, f1.y, f1.z, f1.w};
#pragma unroll
        for (int i = 0; i < 4; i++) {
            *(uint4*)&A2s[row * 136 + ((t & 3) * 4 + i) * 8] =
                make_uint4(dup_lo(uu[2 * i]), dup_hi(uu[2 * i]), dup_lo(uu[2 * i + 1]), dup_hi(uu[2 * i + 1]));
        }
    }
    {
        const int col = t >> 1;
        const unsigned* src = P2 + (m0 + col) * DH_ + (t & 1) * 16;
#pragma unroll
        for (int i = 0; i < 8; i++) {
            const unsigned u0 = src[2 * i], u1 = src[2 * i + 1];
            *(uint4*)&Ps[col * 136 + ((t & 1) * 8 + i) * 8] = make_uint4(u0, u0, u1, u1);
        }
    }
    __syncthreads();
    const int w = t >> 6, lane = t & 63, quad = lane >> 4, l16 = lane & 15;
    floatx4 acc[4][2];
#pragma unroll
    for (int rt = 0; rt < 4; rt++)
#pragma unroll
        for (int ct = 0; ct < 2; ct++) acc[rt][ct] = (floatx4){0.f, 0.f, 0.f, 0.f};
#pragma unroll
    for (int kk = 0; kk < 4; kk++) {
        short8 af[4], bf[2];
#pragma unroll
        for (int rt = 0; rt < 4; rt++)
            af[rt] = *(const short8*)&A2s[(rt * 16 + l16) * 136 + (kk * 4 + quad) * 8];
#pragma unroll
        for (int ct = 0; ct < 2; ct++)
            bf[ct] = *(const short8*)&Ps[((w * 2 + ct) * 16 + l16) * 136 + (kk * 4 + quad) * 8];
#pragma unroll
        for (int rt = 0; rt < 4; rt++)
#pragma unroll
            for (int ct = 0; ct < 2; ct++)
                acc[rt][ct] = __builtin_amdgcn_mfma_f32_16x16x32_bf16(af[rt], bf[ct], acc[rt][ct], 0, 0, 0);
    }
    float mx = -INFINITY;
#pragma unroll
    for (int rt = 0; rt < 4; rt++)
#pragma unroll
        for (int ct = 0; ct < 2; ct++)
#pragma unroll
            for (int i = 0; i < 4; i++) mx = fmaxf(mx, acc[rt][ct][i]);
#pragma unroll
    for (int o = 32; o > 0; o >>= 1) mx = fmaxf(mx, __shfl_xor(mx, o, 64));
    if (lane == 0) sred[w] = mx;
    __syncthreads();
    if (t == 0) {
        const float m4 = fmaxf(fmaxf(sred[0], sred[1]), fmaxf(sred[2], sred[3]))
                       * 0.42044820762685725f;
        const int i = __float_as_int(m4);
        atomicMax(slot, (i >= 0) ? i : (i ^ 0x7fffffff));
    }
}

// ---------- full-MFMA performer attention v3 (fast exp + fast split), 1024 threads ----------
__global__ void __launch_bounds__(1024) k_attn2(
    const unsigned* __restrict__ qg, const unsigned* __restrict__ kg, const unsigned* __restrict__ vg,
    const unsigned* __restrict__ P2, const int* __restrict__ slot,
    unsigned* __restrict__ outp)
{
    extern __shared__ char smem[];
    ushort* sA    = (ushort*)(smem);            // [128][136]: K-split
    ushort* sB    = (ushort*)(smem + 34816);    // [64][136]: P-quarter {h,l,h,l}
    ushort* sBig  = (ushort*)(smem + 52224);    // kpT [64][264]; later oRed f32[4096]
    ushort* sV    = (ushort*)(smem + 86016);    // [32][264]: v dup
    ushort* sCtx  = (ushort*)(smem + 102912);   // [32][520]: ctx dup
    float* sdk    = (float*)(smem + 136192);    // [128]  (includes +kmax fold)
    float* sdq    = (float*)(smem + 136704);    // [128]
    float* smaxP  = (float*)(smem + 137216);    // [2][128]
    float* sdenP  = (float*)(smem + 138240);    // [2][128]
    float* sksum  = (float*)(smem + 139264);    // [256]
    float* sksP   = (float*)(smem + 140288);    // [16][32]

    const int bh = blockIdx.x;
    const int b = bh >> 3, hh = bh & 7;
    const int t = threadIdx.x;
    const int w = t >> 6, lane = t & 63, quad = lane >> 4, l16 = lane & 15;
    const int wg = w & 7, wh = w >> 3;
    const int nq = wg * 16 + l16;
    const unsigned* kb = kg + (size_t)bh * S_ * DH_;
    const unsigned* qb = qg + (size_t)bh * S_ * DH_;
    const unsigned* vb = vg + (size_t)bh * S_ * DH_;
    const float nrm = 0.42044820762685725f;
    const float diagc = 0.5f * nrm * nrm;
    const float ratio = 0.0625f;

    union U8 { uint4 u; short8 s; };

    float kmaxv;
    { const int iv = *slot; kmaxv = __int_as_float((iv >= 0) ? iv : (iv ^ 0x7fffffff)); }

    short8 qf[4];
    {
        const unsigned* qrow = qb + (size_t)nq * DH_ + quad * 2;
#pragma unroll
        for (int ks = 0; ks < 4; ks++) {
            const uint2 qv = *(const uint2*)(qrow + ks * 8);
            U8 tmp; tmp.u = make_uint4(dup_lo(qv.x), dup_hi(qv.x), dup_lo(qv.y), dup_hi(qv.y));
            qf[ks] = tmp.s;
        }
    }

    if (t < 512) {
        const int row = t >> 2, seg = t & 3;
        const unsigned* src = kb + row * DH_ + seg * 8;
        const uint4 f0 = *(const uint4*)&src[0];
        const uint4 f1 = *(const uint4*)&src[4];
        const unsigned uu[8] = {f0.x, f0.y, f0.z, f0.w, f1.x, f1.y, f1.z, f1.w};
#pragma unroll
        for (int p = 0; p < 4; p++) {
            *(uint4*)&sA[row * 136 + seg * 32 + p * 8] =
                make_uint4(dup_lo(uu[2 * p]), dup_hi(uu[2 * p]), dup_lo(uu[2 * p + 1]), dup_hi(uu[2 * p + 1]));
        }
    } else {
        const int tt2 = t - 512;
        const int n = tt2 & 127, d0 = (tt2 >> 7) * 8;
        const unsigned* src = vb + n * DH_ + d0;
        const uint4 f0 = *(const uint4*)&src[0];
        const uint4 f1 = *(const uint4*)&src[4];
        const unsigned uu[8] = {f0.x, f0.y, f0.z, f0.w, f1.x, f1.y, f1.z, f1.w};
        unsigned* dst = (unsigned*)sV;
#pragma unroll
        for (int j = 0; j < 8; j++)
            dst[(d0 + j) * 132 + n] = dup_lo(uu[j]);
    }
    if (t < 128) {
        float s = 0.f, s2 = 0.f;
#pragma unroll
        for (int d4 = 0; d4 < DH_ / 4; d4++) {
            const uint4 kk = *(const uint4*)&kb[t * DH_ + d4 * 4];
            const float k0 = rec(kk.x), k1 = rec(kk.y), k2 = rec(kk.z), k3 = rec(kk.w);
            s += k0 * k0 + k1 * k1 + k2 * k2 + k3 * k3;
            const uint4 qq = *(const uint4*)&qb[t * DH_ + d4 * 4];
            const float q0 = rec(qq.x), q1 = rec(qq.y), q2 = rec(qq.z), q3 = rec(qq.w);
            s2 += q0 * q0 + q1 * q1 + q2 * q2 + q3 * q3;
        }
        sdk[t] = s * diagc + kmaxv;
        sdq[t] = s2 * diagc;
    }
    __syncthreads();

    floatx4 adq[2][4];
#pragma unroll
    for (int j = 0; j < 2; j++)
#pragma unroll
        for (int mtl = 0; mtl < 4; mtl++) adq[j][mtl] = (floatx4){0.f, 0.f, 0.f, 0.f};

#pragma unroll
    for (int qd = 0; qd < 4; qd++) {
        {
            const int col = t >> 4, ch2 = t & 15;
            const unsigned* src = P2 + (size_t)(qd * 64 + col) * DH_ + ch2 * 2;
            const unsigned u0 = src[0], u1 = src[1];
            *(uint4*)&sB[col * 136 + ch2 * 8] = make_uint4(u0, u0, u1, u1);
        }
        __syncthreads();
        floatx4 acc[2];
        acc[0] = (floatx4){0.f, 0.f, 0.f, 0.f};
        acc[1] = (floatx4){0.f, 0.f, 0.f, 0.f};
#pragma unroll
        for (int ks = 0; ks < 4; ks++) {
            const short8 af = *(const short8*)&sA[nq * 136 + ks * 32 + quad * 8];
            short8 bf[2];
#pragma unroll
            for (int ctl = 0; ctl < 2; ctl++)
                bf[ctl] = *(const short8*)&sB[((2 * wh + ctl) * 16 + l16) * 136 + ks * 32 + quad * 8];
#pragma unroll
            for (int ctl = 0; ctl < 2; ctl++)
                acc[ctl] = __builtin_amdgcn_mfma_f32_16x16x32_bf16(af, bf[ctl], acc[ctl], 0, 0, 0);
        }
        unsigned* kpT = (unsigned*)sBig;
        float kc[2];
#pragma unroll
        for (int ctl = 0; ctl < 2; ctl++) {
            float kcl = 0.f;
            unsigned pk[4];
#pragma unroll
            for (int i = 0; i < 4; i++) {
                const int n = wg * 16 + quad * 4 + i;
                const float kp = ratio * (__expf(acc[ctl][i] * nrm - sdk[n]) + 1e-4f);
                kcl += kp;
                pk[i] = split_pack_fast(kp);
            }
            *(uint4*)&kpT[((2 * wh + ctl) * 16 + l16) * 132 + wg * 16 + quad * 4] =
                make_uint4(pk[0], pk[1], pk[2], pk[3]);
            kc[ctl] = kcl;
        }
#pragma unroll
        for (int ctl = 0; ctl < 2; ctl++) {
            kc[ctl] += __shfl_xor(kc[ctl], 16, 64);
            kc[ctl] += __shfl_xor(kc[ctl], 32, 64);
        }
        if (quad == 0) {
            sksP[w * 32 + l16] = kc[0];
            sksP[w * 32 + 16 + l16] = kc[1];
        }
        __syncthreads();
        const int qown = (qd & 1) ^ 1;
        if (wh == qown) {
            const int aidx2 = qd >> 1;
#pragma unroll
            for (int mtl = 0; mtl < 4; mtl++)
#pragma unroll
                for (int ks = 0; ks < 4; ks++) {
                    const short8 af2 = *(const short8*)&sB[(mtl * 16 + l16) * 136 + ks * 32 + quad * 8];
                    adq[aidx2][mtl] = __builtin_amdgcn_mfma_f32_16x16x32_bf16(af2, qf[ks], adq[aidx2][mtl], 0, 0, 0);
                }
        } else {
            const int mt = wg & 3, dt = wg >> 2;
            floatx4 cacc = (floatx4){0.f, 0.f, 0.f, 0.f};
#pragma unroll
            for (int ks = 0; ks < 8; ks++) {
                const short8 a = *(const short8*)&sBig[(mt * 16 + l16) * 264 + ks * 32 + quad * 8];
                const short8 bvv = *(const short8*)&sV[(dt * 16 + l16) * 264 + ks * 32 + quad * 8];
                cacc = __builtin_amdgcn_mfma_f32_16x16x32_bf16(a, bvv, cacc, 0, 0, 0);
            }
            unsigned* ctxB = (unsigned*)sCtx;
            unsigned pk2[4];
#pragma unroll
            for (int i = 0; i < 4; i++) pk2[i] = (unsigned)bf16_rn(cacc[i]) * 0x10001u;
            *(uint4*)&ctxB[(dt * 16 + l16) * 260 + qd * 64 + mt * 16 + quad * 4] =
                make_uint4(pk2[0], pk2[1], pk2[2], pk2[3]);
        }
        if (t < 64) {
            float s = 0.f;
#pragma unroll
            for (int wg2 = 0; wg2 < 8; wg2++)
                s += sksP[((t >> 5) * 8 + wg2) * 32 + (t & 31)];
            sksum[qd * 64 + t] = s;
        }
        __syncthreads();
    }

    {
        float mxn = -INFINITY;
#pragma unroll
        for (int j = 0; j < 2; j++)
#pragma unroll
            for (int mtl = 0; mtl < 4; mtl++)
#pragma unroll
                for (int i = 0; i < 4; i++) mxn = fmaxf(mxn, adq[j][mtl][i]);
        mxn = fmaxf(mxn, __shfl_xor(mxn, 16, 64));
        mxn = fmaxf(mxn, __shfl_xor(mxn, 32, 64));
        if (quad == 0) smaxP[wh * 128 + nq] = mxn;
    }
    __syncthreads();
    const float dmq = sdq[nq] + fmaxf(smaxP[nq], smaxP[128 + nq]) * nrm;

    floatx4 oT[2];
    oT[0] = (floatx4){0.f, 0.f, 0.f, 0.f};
    oT[1] = (floatx4){0.f, 0.f, 0.f, 0.f};
    float dp = 0.f;
#pragma unroll
    for (int j = 0; j < 2; j++) {
        const int qdo = 2 * j + (wh ^ 1);
#pragma unroll
        for (int mtl = 0; mtl < 4; mtl++) {
            unsigned pk[4];
#pragma unroll
            for (int i = 0; i < 4; i++) {
                const float qp = ratio * (__expf(adq[j][mtl][i] * nrm - dmq) + 1e-4f);
                dp += qp * sksum[qdo * 64 + mtl * 16 + quad * 4 + i];
                pk[i] = split_pack_fast(qp);
            }
            U8 tb; tb.u = make_uint4(pk[0], pk[1], pk[2], pk[3]);
#pragma unroll
            for (int dt = 0; dt < 2; dt++) {
                const short8 actx = *(const short8*)&sCtx[(dt * 16 + l16) * 520 + qdo * 128 + mtl * 32 + quad * 8];
                oT[dt] = __builtin_amdgcn_mfma_f32_16x16x32_bf16(actx, tb.s, oT[dt], 0, 0, 0);
            }
        }
    }
    dp += __shfl_xor(dp, 16, 64);
    dp += __shfl_xor(dp, 32, 64);
    if (quad == 0) sdenP[wh * 128 + nq] = dp;

    float* oRed = (float*)sBig;
    if (wh == 1) {
#pragma unroll
        for (int dt = 0; dt < 2; dt++)
            *(floatx4*)&oRed[((wg * 2 + dt) * 64 + lane) * 4] = oT[dt];
    }
    __syncthreads();
    if (wh == 0) {
        const float inv = 1.0f / (sdenP[nq] + sdenP[128 + nq]);
#pragma unroll
        for (int dt = 0; dt < 2; dt++) {
            const floatx4 o2 = *(const floatx4*)&oRed[((wg * 2 + dt) * 64 + lane) * 4];
            const unsigned r0 = split_pack((oT[dt][0] + o2[0]) * inv);
            const unsigned r1 = split_pack((oT[dt][1] + o2[1]) * inv);
            const unsigned r2 = split_pack((oT[dt][2] + o2[2]) * inv);
            const unsigned r3 = split_pack((oT[dt][3] + o2[3]) * inv);
            *(uint4*)&outp[((size_t)b * S_ + nq) * D_ + hh * DH_ + dt * 16 + quad * 4] =
                make_uint4(r0, r1, r2, r3);
        }
    }
}

// ---------- classification head (packed input) ----------
__global__ void __launch_bounds__(256) k_head(
    const unsigned* __restrict__ hfin, const float* __restrict__ h1w, const float* __restrict__ h1b,
    const float* __restrict__ h2w, const float* __restrict__ h2b,
    const float* __restrict__ ow, const float* __restrict__ ob, float* __restrict__ outp)
{
    __shared__ float c0[D_];
    __shared__ float c1[2 * HID_];
    __shared__ float sred[4];
    const int t = threadIdx.x;
    const int b = blockIdx.x;
    c0[t] = rec(hfin[(size_t)b * S_ * D_ + t]);
    __syncthreads();
#pragma unroll
    for (int half = 0; half < 2; half++) {
        const int j = half * 256 + t;
        float a = h1b[j];
        const float* w = h1w + (size_t)j * D_;
        for (int d = 0; d < D_; d += 4) {
            const float4 w4 = *(const float4*)&w[d];
            const float4 x4 = *(const float4*)&c0[d];
            a += x4.x * w4.x + x4.y * w4.y + x4.z * w4.z + x4.w * w4.w;
        }
        c1[j] = (a >= 0.f) ? a : 0.2f * a;
    }
    __syncthreads();
    float a2 = h2b[t];
    const float* w2 = h2w + (size_t)t * (2 * HID_);
    for (int j = 0; j < 2 * HID_; j += 4) {
        const float4 w4 = *(const float4*)&w2[j];
        const float4 x4 = *(const float4*)&c1[j];
        a2 += x4.x * w4.x + x4.y * w4.y + x4.z * w4.z + x4.w * w4.w;
    }
    const float c2 = (a2 >= 0.f) ? a2 : 0.2f * a2;
    const float s = blk_sum(c2 * ow[t], sred);
    if (t == 0) outp[b] = s + ob[0];
}

extern "C" void kernel_launch(void* const* d_in, const int* in_sizes, int n_in,
                              void* d_out, int out_size, void* d_ws, size_t ws_size,
                              hipStream_t stream)
{
    const float* x     = (const float*)d_in[0];
    const int*   mask  = (const int*)d_in[1];
    const float* emb_w = (const float*)d_in[2];
    const float* emb_b = (const float*)d_in[3];
    const float* Wq    = (const float*)d_in[4];
    const float* bq    = (const float*)d_in[5];
    const float* Wk    = (const float*)d_in[6];
    const float* bk    = (const float*)d_in[7];
    const float* Wv    = (const float*)d_in[8];
    const float* bv    = (const float*)d_in[9];
    const float* Wo    = (const float*)d_in[10];
    const float* bo    = (const float*)d_in[11];
    const float* proj  = (const float*)d_in[12];
    const float* n1w   = (const float*)d_in[13];
    const float* n1b   = (const float*)d_in[14];
    const float* n2w   = (const float*)d_in[15];
    const float* n2b   = (const float*)d_in[16];
    const float* f1w   = (const float*)d_in[17];
    const float* f1b   = (const float*)d_in[18];
    const float* f2w   = (const float*)d_in[19];
    const float* f2b   = (const float*)d_in[20];
    const float* h1w   = (const float*)d_in[21];
    const float* h1b   = (const float*)d_in[22];
    const float* h2w   = (const float*)d_in[23];
    const float* h2b   = (const float*)d_in[24];
    const float* ow    = (const float*)d_in[25];
    const float* ob    = (const float*)d_in[26];

    const size_t BSD = (size_t)B_ * S_ * D_;
    unsigned* A = (unsigned*)d_ws;                 // packed activations
    unsigned* Q = A + BSD;
    unsigned* K = Q + BSD;
    unsigned* V = K + BSD;
    unsigned* T = K;                               // post-LN1 alias (K dead after attn)
    const size_t WMU = 65536;                      // ushorts per matrix plane (256x256)
    ushort* WH = (ushort*)(V + BSD);               // 6 x L x 65536 ushorts (h planes)
    ushort* WL = WH + 6 * L_ * WMU;                // 6 x L x 65536 ushorts (l planes)
    unsigned* P2 = (unsigned*)(WL + 6 * L_ * WMU); // compact split proj: L x 256 x 32 uints
    int* slots = (int*)(P2 + (size_t)L_ * M_ * DH_);

    k_prep<<<801, 256, 0, stream>>>(Wq, Wk, Wv, Wo, f1w, f2w, proj, WH, WL, P2, slots);

    const int GB = B_ * S_ / 64;               // 512 blocks per GEMM
    const int DB = B_ * H_ * S_ / 64 * 2;      // 8192 blocks for k_dmax
    const size_t ATTN_LDS = 142336;            // 139 KB dynamic LDS

    k_embed<<<B_ * S_ * D_ / 256, 256, 0, stream>>>(x, emb_w, emb_b, A);
    for (int l = 0; l < L_; l++) {
        const unsigned* P2l = P2 + (size_t)l * M_ * DH_;
        k_gemm_qkv<<<3 * GB, 512, 0, stream>>>(A, WH, WL, l, bq + l * D_, bk + l * D_, bv + l * D_, mask, Q, K, V);
        k_dmax<<<DB, 256, 0, stream>>>(K, P2l, slots + l);
        k_attn2<<<B_ * H_, 1024, ATTN_LDS, stream>>>(Q, K, V, P2l, slots + l, A);
        k_gemm<2><<<GB, 512, 0, stream>>>(A, WH + (3 * L_ + l) * WMU, WL + (3 * L_ + l) * WMU, bo + l * D_, n1w + l * D_, n1b + l * D_, nullptr, T);
        k_gemm<3><<<GB, 512, 0, stream>>>(T, WH + (4 * L_ + l) * WMU, WL + (4 * L_ + l) * WMU, f1b + l * HID_, nullptr, nullptr, nullptr, Q);
        k_gemm<2><<<GB, 512, 0, stream>>>(Q, WH + (5 * L_ + l) * WMU, WL + (5 * L_ + l) * WMU, f2b + l * D_, n2w + l * D_, n2b + l * D_, nullptr, A);
    }
    k_head<<<B_, 256, 0, stream>>>(A, h1w, h1b, h2w, h2b, ow, ob, (float*)d_out);
}

// Round 8
// 1501.010 us; speedup vs baseline: 1.3540x; 1.0585x over previous
//
#include <hip/hip_runtime.h>
#include <math.h>

#define B_ 256
#define N_ 127
#define S_ 128
#define NDIM_ 3
#define D_ 256
#define H_ 8
#define DH_ 32
#define M_ 256
#define HID_ 256
#define L_ 4
#define LOG2E 1.44269504088896340736f

typedef __attribute__((ext_vector_type(8))) short short8;
typedef __attribute__((ext_vector_type(4))) float floatx4;

// ---------- bf16 split helpers ----------
__device__ __forceinline__ ushort bf16_rn(float x) {
    unsigned u = __float_as_uint(x);
    u = (u + 0x7fffu + ((u >> 16) & 1u)) >> 16;
    return (ushort)u;
}
__device__ __forceinline__ unsigned split_pack(float x) {
    const ushort h = bf16_rn(x);
    const float r = x - __uint_as_float(((unsigned)h) << 16);
    const ushort l = bf16_rn(r);
    return (unsigned)h | ((unsigned)l << 16);
}
// Fast 5-inst split (attn-internal kp/qp)
__device__ __forceinline__ unsigned split_pack_fast(float x) {
    const unsigned xu = __float_as_uint(x);
    const unsigned hb = xu & 0xffff0000u;
    const float r = x - __uint_as_float(hb);
    return (hb >> 16) | (__float_as_uint(r) & 0xffff0000u);
}
__device__ __forceinline__ unsigned dup_lo(unsigned u) {
    const unsigned h = u & 0xffffu;
    return h | (h << 16);
}
__device__ __forceinline__ unsigned dup_hi(unsigned u) {
    const unsigned l = u >> 16;
    return l | (l << 16);
}
__device__ __forceinline__ float rec(unsigned u) {
    return __uint_as_float(u << 16) + __uint_as_float(u & 0xffff0000u);
}
__device__ __forceinline__ unsigned hpair(unsigned u0, unsigned u1) {
    return (u0 & 0xffffu) | (u1 << 16);
}
__device__ __forceinline__ unsigned lpair(unsigned u0, unsigned u1) {
    return (u0 >> 16) | (u1 & 0xffff0000u);
}

// ---------- block reductions ----------
__device__ __forceinline__ float blk_sum(float v, float* sred) {
#pragma unroll
    for (int o = 32; o > 0; o >>= 1) v += __shfl_xor(v, o, 64);
    if ((threadIdx.x & 63) == 0) sred[threadIdx.x >> 6] = v;
    __syncthreads();
    v = sred[0] + sred[1] + sred[2] + sred[3];
    __syncthreads();
    return v;
}

// ---------- fused prep: weight planes + proj conv + slot reset + embedding ----------
// blocks 0-767: wconvp; 768-799: proj conv; 800: reset; 801+: embedding (x4 vec)
__global__ void __launch_bounds__(256) k_prep(
    const float* __restrict__ Wq, const float* __restrict__ Wk, const float* __restrict__ Wv,
    const float* __restrict__ Wo, const float* __restrict__ f1w, const float* __restrict__ f2w,
    const float* __restrict__ proj, ushort* __restrict__ WH, ushort* __restrict__ WL,
    unsigned* __restrict__ P2, int* __restrict__ slots,
    const float* __restrict__ x, const float* __restrict__ ew, const float* __restrict__ eb,
    unsigned* __restrict__ Aout)
{
    const int bid = blockIdx.x;
    if (bid < 768) {
        const int tensor = bid / 128;
        const int tid = (bid & 127) * 256 + threadIdx.x;
        const float* src = tensor == 0 ? Wq : tensor == 1 ? Wk : tensor == 2 ? Wv
                         : tensor == 3 ? Wo : tensor == 4 ? f1w : f2w;
        ushort* dh = WH + (size_t)tensor * L_ * 65536;
        ushort* dl = WL + (size_t)tensor * L_ * 65536;
        const int l = tid >> 13;
        const int col = (tid >> 5) & 255, kc = tid & 31;
        const float* sp = src + ((size_t)l << 16) + col * 256 + kc * 8;
        float v[8];
        *(float4*)&v[0] = *(const float4*)sp;
        *(float4*)&v[4] = *(const float4*)(sp + 4);
        unsigned hu[4], lu[4];
#pragma unroll
        for (int i = 0; i < 4; i++) {
            const unsigned u0 = split_pack(v[2 * i]);
            const unsigned u1 = split_pack(v[2 * i + 1]);
            hu[i] = hpair(u0, u1);
            lu[i] = lpair(u0, u1);
        }
        const size_t off = ((size_t)l << 16) + ((size_t)(kc * 256 + col)) * 8;
        *(uint4*)&dh[off] = make_uint4(hu[0], hu[1], hu[2], hu[3]);
        *(uint4*)&dl[off] = make_uint4(lu[0], lu[1], lu[2], lu[3]);
    } else if (bid < 800) {
        const int idx = ((bid - 768) * 256 + threadIdx.x) * 4;
        const float4 w4 = *(const float4*)&proj[idx];
        const float v[4] = {w4.x, w4.y, w4.z, w4.w};
        unsigned u[4];
#pragma unroll
        for (int i = 0; i < 4; i++) u[i] = split_pack(v[i]);
        *(uint4*)&P2[idx] = make_uint4(u[0], u[1], u[2], u[3]);
    } else if (bid == 800) {
        if (threadIdx.x < 4) {
            const int i = __float_as_int(-INFINITY);
            slots[threadIdx.x] = (i >= 0) ? i : (i ^ 0x7fffffff);
        }
    } else {
        // embedding: 8192 blocks x 256 threads x 4 d's
        const int idx4 = (bid - 801) * 256 + threadIdx.x;
        const int d0 = (idx4 & 63) * 4;
        const int n = (idx4 >> 6) & (S_ - 1);
        const int b = idx4 >> 13;
        unsigned r[4] = {0u, 0u, 0u, 0u};
        if (n > 0) {
            const float* xr = x + ((size_t)b * N_ + (n - 1)) * NDIM_;
            const float x0 = xr[0], x1 = xr[1], x2 = xr[2];
#pragma unroll
            for (int j = 0; j < 4; j++) {
                const int d = d0 + j;
                const float val = eb[d] + x0 * ew[d * 3 + 0] + x1 * ew[d * 3 + 1] + x2 * ew[d * 3 + 2];
                r[j] = split_pack(val);
            }
        }
        *(uint4*)&Aout[(size_t)idx4 * 4] = make_uint4(r[0], r[1], r[2], r[3]);
    }
}

// ---------- 3-product split MFMA GEMM, W direct-from-global ----------
template<int EPI>
__global__ void __launch_bounds__(512, 4) k_gemm(
    const unsigned* __restrict__ Ap, const ushort* __restrict__ WH,
    const ushort* __restrict__ WL,
    const float* __restrict__ bias, const float* __restrict__ g1,
    const float* __restrict__ g2, const int* __restrict__ mask,
    unsigned* __restrict__ out)
{
    __shared__ ushort sAh[2][2080];
    __shared__ ushort sAl[2][2080];
    __shared__ float sredA[64][4], sredB[64][4];
    const int t = threadIdx.x;
    const int w = t >> 6, lane = t & 63;
    const int quad = lane >> 4, l16 = lane & 15;
    const int rowbase = 32 * (w >> 2), colbase = 64 * (w & 3);
    const int colg = w & 3;
    const int row0 = blockIdx.x * 64;

    floatx4 acc[2][4];
#pragma unroll
    for (int rt = 0; rt < 2; rt++)
#pragma unroll
        for (int ct = 0; ct < 4; ct++) acc[rt][ct] = (floatx4){0.f, 0.f, 0.f, 0.f};

    const int arow = t >> 3, akq = t & 7;
    const unsigned* AG = Ap + (size_t)(row0 + arow) * D_ + akq * 4;
    const int aidx = (akq >> 1) * 520 + arow * 8 + (akq & 1) * 4;

    {
        const uint4 a4 = *(const uint4*)AG;
        *(uint2*)&sAh[0][aidx] = make_uint2(hpair(a4.x, a4.y), hpair(a4.z, a4.w));
        *(uint2*)&sAl[0][aidx] = make_uint2(lpair(a4.x, a4.y), lpair(a4.z, a4.w));
    }
    __syncthreads();

    for (int s = 0; s < 8; s++) {
        const int p = s & 1;
        uint4 a_n;
        if (s + 1 < 8) a_n = *(const uint4*)(AG + (s + 1) * 32);
        const size_t wbase = ((size_t)((s * 4 + quad) * 256 + colbase + l16)) * 8;
        const ushort* WHf = WH + wbase;
        const ushort* WLf = WL + wbase;
        short8 ah[2], al[2], wh[4], wl[4];
#pragma unroll
        for (int ct = 0; ct < 4; ct++) {
            wh[ct] = *(const short8*)&WHf[ct * 128];
            wl[ct] = *(const short8*)&WLf[ct * 128];
        }
#pragma unroll
        for (int rt = 0; rt < 2; rt++) {
            const int ai = quad * 520 + (rowbase + 16 * rt + l16) * 8;
            ah[rt] = *(const short8*)&sAh[p][ai];
            al[rt] = *(const short8*)&sAl[p][ai];
        }
#pragma unroll
        for (int rt = 0; rt < 2; rt++)
#pragma unroll
            for (int ct = 0; ct < 4; ct++) {
                acc[rt][ct] = __builtin_amdgcn_mfma_f32_16x16x32_bf16(ah[rt], wh[ct], acc[rt][ct], 0, 0, 0);
                acc[rt][ct] = __builtin_amdgcn_mfma_f32_16x16x32_bf16(ah[rt], wl[ct], acc[rt][ct], 0, 0, 0);
                acc[rt][ct] = __builtin_amdgcn_mfma_f32_16x16x32_bf16(al[rt], wh[ct], acc[rt][ct], 0, 0, 0);
            }
        if (s + 1 < 8) {
            *(uint2*)&sAh[p ^ 1][aidx] = make_uint2(hpair(a_n.x, a_n.y), hpair(a_n.z, a_n.w));
            *(uint2*)&sAl[p ^ 1][aidx] = make_uint2(lpair(a_n.x, a_n.y), lpair(a_n.z, a_n.w));
        }
        __syncthreads();
    }

    int colv[4]; float bv[4];
#pragma unroll
    for (int ct = 0; ct < 4; ct++) { colv[ct] = colbase + 16 * ct + l16; bv[ct] = bias[colv[ct]]; }

    if (EPI <= 1) {
        const int b = row0 >> 7;
#pragma unroll
        for (int rt = 0; rt < 2; rt++)
#pragma unroll
        for (int i = 0; i < 4; i++) {
            const int rl = rowbase + 16 * rt + quad * 4 + i;
            const int n = (row0 + rl) & (S_ - 1);
            float keep = 1.f;
            if (EPI == 1) keep = (n == 0) ? 1.f : (mask[b * N_ + n - 1] ? 0.f : 1.f);
#pragma unroll
            for (int ct = 0; ct < 4; ct++) {
                float c = acc[rt][ct][i] + bv[ct];
                if (EPI == 1) c *= keep;
                const int col = colv[ct];
                out[(((size_t)b * H_ + (col >> 5)) * S_ + n) * DH_ + (col & 31)] = split_pack(c);
            }
        }
    } else if (EPI == 2) {
        float gv[4], bbv[4];
#pragma unroll
        for (int ct = 0; ct < 4; ct++) { gv[ct] = g1[colv[ct]]; bbv[ct] = g2[colv[ct]]; }
#pragma unroll
        for (int rt = 0; rt < 2; rt++)
#pragma unroll
        for (int i = 0; i < 4; i++) {
            const int rl = rowbase + 16 * rt + quad * 4 + i;
            float s = 0.f, s2 = 0.f;
#pragma unroll
            for (int ct = 0; ct < 4; ct++) {
                const float c = acc[rt][ct][i] + bv[ct];
                s += c; s2 += c * c;
            }
#pragma unroll
            for (int o = 8; o > 0; o >>= 1) { s += __shfl_xor(s, o, 64); s2 += __shfl_xor(s2, o, 64); }
            if (l16 == 0) { sredA[rl][colg] = s; sredB[rl][colg] = s2; }
        }
        __syncthreads();
#pragma unroll
        for (int rt = 0; rt < 2; rt++)
#pragma unroll
        for (int i = 0; i < 4; i++) {
            const int rl = rowbase + 16 * rt + quad * 4 + i;
            const float s = sredA[rl][0] + sredA[rl][1] + sredA[rl][2] + sredA[rl][3];
            const float s2 = sredB[rl][0] + sredB[rl][1] + sredB[rl][2] + sredB[rl][3];
            const float mu = s * (1.f / D_);
            const float rs = rsqrtf(s2 * (1.f / D_) - mu * mu + 1e-5f);
#pragma unroll
            for (int ct = 0; ct < 4; ct++) {
                const float c = acc[rt][ct][i] + bv[ct];
                out[(size_t)(row0 + rl) * D_ + colv[ct]] = split_pack((c - mu) * rs * gv[ct] + bbv[ct]);
            }
        }
    } else {
#pragma unroll
        for (int rt = 0; rt < 2; rt++)
#pragma unroll
        for (int i = 0; i < 4; i++) {
            const int rl = rowbase + 16 * rt + quad * 4 + i;
#pragma unroll
            for (int ct = 0; ct < 4; ct++) {
                const float c = acc[rt][ct][i] + bv[ct];
                out[(size_t)(row0 + rl) * D_ + colv[ct]] = split_pack((c >= 0.f) ? c : 0.2f * c);
            }
        }
    }
}

// ---------- fused Q/K/V GEMM (grid 1536) ----------
__global__ void __launch_bounds__(512, 4) k_gemm_qkv(
    const unsigned* __restrict__ Ap, const ushort* __restrict__ WHb,
    const ushort* __restrict__ WLb, const int l,
    const float* __restrict__ bq, const float* __restrict__ bk, const float* __restrict__ bv_,
    const int* __restrict__ mask,
    unsigned* __restrict__ Qo, unsigned* __restrict__ Ko, unsigned* __restrict__ Vo)
{
    __shared__ ushort sAh[2][2080];
    __shared__ ushort sAl[2][2080];
    const int t = threadIdx.x;
    const int w = t >> 6, lane = t & 63;
    const int quad = lane >> 4, l16 = lane & 15;
    const int rowbase = 32 * (w >> 2), colbase = 64 * (w & 3);
    const int which = blockIdx.x >> 9;
    const int row0 = (blockIdx.x & 511) * 64;
    const ushort* WH = WHb + ((size_t)(which * L_ + l)) * 65536;
    const ushort* WL = WLb + ((size_t)(which * L_ + l)) * 65536;
    const float* bias = which == 0 ? bq : which == 1 ? bk : bv_;
    unsigned* out = which == 0 ? Qo : which == 1 ? Ko : Vo;

    floatx4 acc[2][4];
#pragma unroll
    for (int rt = 0; rt < 2; rt++)
#pragma unroll
        for (int ct = 0; ct < 4; ct++) acc[rt][ct] = (floatx4){0.f, 0.f, 0.f, 0.f};

    const int arow = t >> 3, akq = t & 7;
    const unsigned* AG = Ap + (size_t)(row0 + arow) * D_ + akq * 4;
    const int aidx = (akq >> 1) * 520 + arow * 8 + (akq & 1) * 4;

    {
        const uint4 a4 = *(const uint4*)AG;
        *(uint2*)&sAh[0][aidx] = make_uint2(hpair(a4.x, a4.y), hpair(a4.z, a4.w));
        *(uint2*)&sAl[0][aidx] = make_uint2(lpair(a4.x, a4.y), lpair(a4.z, a4.w));
    }
    __syncthreads();

    for (int s = 0; s < 8; s++) {
        const int p = s & 1;
        uint4 a_n;
        if (s + 1 < 8) a_n = *(const uint4*)(AG + (s + 1) * 32);
        const size_t wbase = ((size_t)((s * 4 + quad) * 256 + colbase + l16)) * 8;
        const ushort* WHf = WH + wbase;
        const ushort* WLf = WL + wbase;
        short8 ah[2], al[2], wh[4], wl[4];
#pragma unroll
        for (int ct = 0; ct < 4; ct++) {
            wh[ct] = *(const short8*)&WHf[ct * 128];
            wl[ct] = *(const short8*)&WLf[ct * 128];
        }
#pragma unroll
        for (int rt = 0; rt < 2; rt++) {
            const int ai = quad * 520 + (rowbase + 16 * rt + l16) * 8;
            ah[rt] = *(const short8*)&sAh[p][ai];
            al[rt] = *(const short8*)&sAl[p][ai];
        }
#pragma unroll
        for (int rt = 0; rt < 2; rt++)
#pragma unroll
            for (int ct = 0; ct < 4; ct++) {
                acc[rt][ct] = __builtin_amdgcn_mfma_f32_16x16x32_bf16(ah[rt], wh[ct], acc[rt][ct], 0, 0, 0);
                acc[rt][ct] = __builtin_amdgcn_mfma_f32_16x16x32_bf16(ah[rt], wl[ct], acc[rt][ct], 0, 0, 0);
                acc[rt][ct] = __builtin_amdgcn_mfma_f32_16x16x32_bf16(al[rt], wh[ct], acc[rt][ct], 0, 0, 0);
            }
        if (s + 1 < 8) {
            *(uint2*)&sAh[p ^ 1][aidx] = make_uint2(hpair(a_n.x, a_n.y), hpair(a_n.z, a_n.w));
            *(uint2*)&sAl[p ^ 1][aidx] = make_uint2(lpair(a_n.x, a_n.y), lpair(a_n.z, a_n.w));
        }
        __syncthreads();
    }

    int colv[4]; float bv[4];
#pragma unroll
    for (int ct = 0; ct < 4; ct++) { colv[ct] = colbase + 16 * ct + l16; bv[ct] = bias[colv[ct]]; }

    const int b = row0 >> 7;
#pragma unroll
    for (int rt = 0; rt < 2; rt++)
#pragma unroll
    for (int i = 0; i < 4; i++) {
        const int rl = rowbase + 16 * rt + quad * 4 + i;
        const int n = (row0 + rl) & (S_ - 1);
        float keep = 1.f;
        if (which == 2) keep = (n == 0) ? 1.f : (mask[b * N_ + n - 1] ? 0.f : 1.f);
#pragma unroll
        for (int ct = 0; ct < 4; ct++) {
            float c = acc[rt][ct][i] + bv[ct];
            c *= keep;
            const int col = colv[ct];
            out[(((size_t)b * H_ + (col >> 5)) * S_ + n) * DH_ + (col & 31)] = split_pack(c);
        }
    }
}

// ---------- lite MFMA global k-max (h-plane only) ----------
// The max feeds exp(dd - mx) as a GLOBAL scalar shift: o is exactly invariant
// to small shifts in mx (numerator/denominator scale identically; eps term
// contributes ~1e-6). So single-bf16 (h*h) dd suffices: 8 MFMAs vs 32.
__global__ void __launch_bounds__(256) k_dmax(
    const unsigned* __restrict__ kg, const unsigned* __restrict__ P2, int* __restrict__ slot)
{
    __shared__ __align__(16) ushort A2s[64 * 40];
    __shared__ __align__(16) ushort Ps[128 * 40];
    __shared__ float sred[4];
    const int t = threadIdx.x;
    const size_t row0 = (size_t)(blockIdx.x >> 1) * 64;
    const int m0 = (blockIdx.x & 1) * 128;
    {
        const int row = t >> 2, seg = t & 3;
        const unsigned* src = kg + (row0 + row) * DH_ + seg * 8;
        const uint4 f0 = *(const uint4*)src;
        const uint4 f1 = *(const uint4*)(src + 4);
        *(uint4*)&A2s[row * 40 + seg * 8] =
            make_uint4(hpair(f0.x, f0.y), hpair(f0.z, f0.w), hpair(f1.x, f1.y), hpair(f1.z, f1.w));
    }
    {
        const int col = t >> 1, half = t & 1;
        const unsigned* src = P2 + (m0 + col) * DH_ + half * 16;
        const uint4 g0 = *(const uint4*)src;
        const uint4 g1 = *(const uint4*)(src + 4);
        const uint4 g2 = *(const uint4*)(src + 8);
        const uint4 g3 = *(const uint4*)(src + 12);
        *(uint4*)&Ps[col * 40 + half * 16] =
            make_uint4(hpair(g0.x, g0.y), hpair(g0.z, g0.w), hpair(g1.x, g1.y), hpair(g1.z, g1.w));
        *(uint4*)&Ps[col * 40 + half * 16 + 8] =
            make_uint4(hpair(g2.x, g2.y), hpair(g2.z, g2.w), hpair(g3.x, g3.y), hpair(g3.z, g3.w));
    }
    __syncthreads();
    const int w = t >> 6, lane = t & 63, quad = lane >> 4, l16 = lane & 15;
    floatx4 acc[4][2];
#pragma unroll
    for (int rt = 0; rt < 4; rt++)
#pragma unroll
        for (int ct = 0; ct < 2; ct++) acc[rt][ct] = (floatx4){0.f, 0.f, 0.f, 0.f};
    short8 af[4], bf[2];
#pragma unroll
    for (int rt = 0; rt < 4; rt++)
        af[rt] = *(const short8*)&A2s[(rt * 16 + l16) * 40 + quad * 8];
#pragma unroll
    for (int ct = 0; ct < 2; ct++)
        bf[ct] = *(const short8*)&Ps[((w * 2 + ct) * 16 + l16) * 40 + quad * 8];
#pragma unroll
    for (int rt = 0; rt < 4; rt++)
#pragma unroll
        for (int ct = 0; ct < 2; ct++)
            acc[rt][ct] = __builtin_amdgcn_mfma_f32_16x16x32_bf16(af[rt], bf[ct], acc[rt][ct], 0, 0, 0);
    float mx = -INFINITY;
#pragma unroll
    for (int rt = 0; rt < 4; rt++)
#pragma unroll
        for (int ct = 0; ct < 2; ct++)
#pragma unroll
            for (int i = 0; i < 4; i++) mx = fmaxf(mx, acc[rt][ct][i]);
#pragma unroll
    for (int o = 32; o > 0; o >>= 1) mx = fmaxf(mx, __shfl_xor(mx, o, 64));
    if (lane == 0) sred[w] = mx;
    __syncthreads();
    if (t == 0) {
        const float m4 = fmaxf(fmaxf(sred[0], sred[1]), fmaxf(sred[2], sred[3]))
                       * 0.42044820762685725f;
        const int i = __float_as_int(m4);
        atomicMax(slot, (i >= 0) ? i : (i ^ 0x7fffffff));
    }
}

// ---------- full-MFMA performer attention v4 (3-product kp/qp, h/l planes) ----------
__global__ void __launch_bounds__(1024) k_attn2(
    const unsigned* __restrict__ qg, const unsigned* __restrict__ kg, const unsigned* __restrict__ vg,
    const unsigned* __restrict__ P2, const int* __restrict__ slot,
    unsigned* __restrict__ outp)
{
    extern __shared__ char smem[];
    ushort* sAh   = (ushort*)(smem);            // [128][40] K h-plane
    ushort* sAl   = (ushort*)(smem + 10240);    // [128][40] K l-plane
    ushort* sBh   = (ushort*)(smem + 20480);    // [64][40] P-quarter h
    ushort* sBl   = (ushort*)(smem + 25600);    // [64][40] P-quarter l
    ushort* sBig  = (ushort*)(smem + 30720);    // kpT [64][264]; later oRed f32[4096]
    ushort* sV    = (ushort*)(smem + 64512);    // [32][264] v dup
    ushort* sCtx  = (ushort*)(smem + 81408);    // [32][520] ctx dup
    float* sdk    = (float*)(smem + 114688);    // [128] (+kmax fold)
    float* sdq    = (float*)(smem + 115200);    // [128]
    float* smaxP  = (float*)(smem + 115712);    // [2][128]
    float* sdenP  = (float*)(smem + 116736);    // [2][128]
    float* sksum  = (float*)(smem + 117760);    // [256]
    float* sksP   = (float*)(smem + 118784);    // [16][32]

    const int bh = blockIdx.x;
    const int b = bh >> 3, hh = bh & 7;
    const int t = threadIdx.x;
    const int w = t >> 6, lane = t & 63, quad = lane >> 4, l16 = lane & 15;
    const int wg = w & 7, wh = w >> 3;
    const int nq = wg * 16 + l16;
    const unsigned* kb = kg + (size_t)bh * S_ * DH_;
    const unsigned* qb = qg + (size_t)bh * S_ * DH_;
    const unsigned* vb = vg + (size_t)bh * S_ * DH_;
    const float nrm = 0.42044820762685725f;
    const float diagc = 0.5f * nrm * nrm;
    const float ratio = 0.0625f;

    union U8 { uint4 u; short8 s; };

    float kmaxv;
    { const int iv = *slot; kmaxv = __int_as_float((iv >= 0) ? iv : (iv ^ 0x7fffffff)); }

    // Q h/l fragments (8 d's for this quad)
    short8 qfh, qfl;
    {
        const unsigned* qrow = qb + (size_t)nq * DH_ + quad * 8;
        const uint4 q0 = *(const uint4*)qrow;
        const uint4 q1 = *(const uint4*)(qrow + 4);
        U8 th; th.u = make_uint4(hpair(q0.x, q0.y), hpair(q0.z, q0.w), hpair(q1.x, q1.y), hpair(q1.z, q1.w));
        U8 tl; tl.u = make_uint4(lpair(q0.x, q0.y), lpair(q0.z, q0.w), lpair(q1.x, q1.y), lpair(q1.z, q1.w));
        qfh = th.s; qfl = tl.s;
    }

    if (t < 512) {
        const int row = t >> 2, seg = t & 3;
        const unsigned* src = kb + row * DH_ + seg * 8;
        const uint4 f0 = *(const uint4*)&src[0];
        const uint4 f1 = *(const uint4*)&src[4];
        *(uint4*)&sAh[row * 40 + seg * 8] =
            make_uint4(hpair(f0.x, f0.y), hpair(f0.z, f0.w), hpair(f1.x, f1.y), hpair(f1.z, f1.w));
        *(uint4*)&sAl[row * 40 + seg * 8] =
            make_uint4(lpair(f0.x, f0.y), lpair(f0.z, f0.w), lpair(f1.x, f1.y), lpair(f1.z, f1.w));
    } else {
        const int tt2 = t - 512;
        const int n = tt2 & 127, d0 = (tt2 >> 7) * 8;
        const unsigned* src = vb + n * DH_ + d0;
        const uint4 f0 = *(const uint4*)&src[0];
        const uint4 f1 = *(const uint4*)&src[4];
        const unsigned uu[8] = {f0.x, f0.y, f0.z, f0.w, f1.x, f1.y, f1.z, f1.w};
        unsigned* dst = (unsigned*)sV;
#pragma unroll
        for (int j = 0; j < 8; j++)
            dst[(d0 + j) * 132 + n] = dup_lo(uu[j]);
    }
    if (t < 128) {
        float s = 0.f, s2 = 0.f;
#pragma unroll
        for (int d4 = 0; d4 < DH_ / 4; d4++) {
            const uint4 kk = *(const uint4*)&kb[t * DH_ + d4 * 4];
            const float k0 = rec(kk.x), k1 = rec(kk.y), k2 = rec(kk.z), k3 = rec(kk.w);
            s += k0 * k0 + k1 * k1 + k2 * k2 + k3 * k3;
            const uint4 qq = *(const uint4*)&qb[t * DH_ + d4 * 4];
            const float q0 = rec(qq.x), q1 = rec(qq.y), q2 = rec(qq.z), q3 = rec(qq.w);
            s2 += q0 * q0 + q1 * q1 + q2 * q2 + q3 * q3;
        }
        sdk[t] = s * diagc + kmaxv;
        sdq[t] = s2 * diagc;
    }
    __syncthreads();

    floatx4 adq[2][4];
#pragma unroll
    for (int j = 0; j < 2; j++)
#pragma unroll
        for (int mtl = 0; mtl < 4; mtl++) adq[j][mtl] = (floatx4){0.f, 0.f, 0.f, 0.f};

#pragma unroll
    for (int qd = 0; qd < 4; qd++) {
        // stage P quarter into h/l planes (2 d's per thread)
        {
            const int col = t >> 4, ch2 = t & 15;
            const unsigned* src = P2 + (size_t)(qd * 64 + col) * DH_ + ch2 * 2;
            const unsigned u0 = src[0], u1 = src[1];
            ((unsigned*)sBh)[col * 20 + ch2] = hpair(u0, u1);
            ((unsigned*)sBl)[col * 20 + ch2] = lpair(u0, u1);
        }
        __syncthreads();
        // phase B: kp MFMAs (3-product) + exp/pack + ksum partials
        floatx4 acc[2];
        acc[0] = (floatx4){0.f, 0.f, 0.f, 0.f};
        acc[1] = (floatx4){0.f, 0.f, 0.f, 0.f};
        {
            const short8 afh = *(const short8*)&sAh[nq * 40 + quad * 8];
            const short8 afl = *(const short8*)&sAl[nq * 40 + quad * 8];
#pragma unroll
            for (int ctl = 0; ctl < 2; ctl++) {
                const int mrow = ((2 * wh + ctl) * 16 + l16) * 40 + quad * 8;
                const short8 bfh = *(const short8*)&sBh[mrow];
                const short8 bfl = *(const short8*)&sBl[mrow];
                acc[ctl] = __builtin_amdgcn_mfma_f32_16x16x32_bf16(afh, bfh, acc[ctl], 0, 0, 0);
                acc[ctl] = __builtin_amdgcn_mfma_f32_16x16x32_bf16(afh, bfl, acc[ctl], 0, 0, 0);
                acc[ctl] = __builtin_amdgcn_mfma_f32_16x16x32_bf16(afl, bfh, acc[ctl], 0, 0, 0);
            }
        }
        unsigned* kpT = (unsigned*)sBig;
        float kc[2];
#pragma unroll
        for (int ctl = 0; ctl < 2; ctl++) {
            float kcl = 0.f;
            unsigned pk[4];
#pragma unroll
            for (int i = 0; i < 4; i++) {
                const int n = wg * 16 + quad * 4 + i;
                const float kp = ratio * (__expf(acc[ctl][i] * nrm - sdk[n]) + 1e-4f);
                kcl += kp;
                pk[i] = split_pack_fast(kp);
            }
            *(uint4*)&kpT[((2 * wh + ctl) * 16 + l16) * 132 + wg * 16 + quad * 4] =
                make_uint4(pk[0], pk[1], pk[2], pk[3]);
            kc[ctl] = kcl;
        }
#pragma unroll
        for (int ctl = 0; ctl < 2; ctl++) {
            kc[ctl] += __shfl_xor(kc[ctl], 16, 64);
            kc[ctl] += __shfl_xor(kc[ctl], 32, 64);
        }
        if (quad == 0) {
            sksP[w * 32 + l16] = kc[0];
            sksP[w * 32 + 16 + l16] = kc[1];
        }
        __syncthreads();
        // phase C: one half qp MFMAs (3-product, B from regs), other half ctx
        const int qown = (qd & 1) ^ 1;
        if (wh == qown) {
            const int aidx2 = qd >> 1;
#pragma unroll
            for (int mtl = 0; mtl < 4; mtl++) {
                const int prow = (mtl * 16 + l16) * 40 + quad * 8;
                const short8 aPh = *(const short8*)&sBh[prow];
                const short8 aPl = *(const short8*)&sBl[prow];
                adq[aidx2][mtl] = __builtin_amdgcn_mfma_f32_16x16x32_bf16(aPh, qfh, adq[aidx2][mtl], 0, 0, 0);
                adq[aidx2][mtl] = __builtin_amdgcn_mfma_f32_16x16x32_bf16(aPh, qfl, adq[aidx2][mtl], 0, 0, 0);
                adq[aidx2][mtl] = __builtin_amdgcn_mfma_f32_16x16x32_bf16(aPl, qfh, adq[aidx2][mtl], 0, 0, 0);
            }
        } else {
            const int mt = wg & 3, dt = wg >> 2;
            floatx4 cacc = (floatx4){0.f, 0.f, 0.f, 0.f};
#pragma unroll
            for (int ks = 0; ks < 8; ks++) {
                const short8 a = *(const short8*)&sBig[(mt * 16 + l16) * 264 + ks * 32 + quad * 8];
                const short8 bvv = *(const short8*)&sV[(dt * 16 + l16) * 264 + ks * 32 + quad * 8];
                cacc = __builtin_amdgcn_mfma_f32_16x16x32_bf16(a, bvv, cacc, 0, 0, 0);
            }
            unsigned* ctxB = (unsigned*)sCtx;
            unsigned pk2[4];
#pragma unroll
            for (int i = 0; i < 4; i++) pk2[i] = (unsigned)bf16_rn(cacc[i]) * 0x10001u;
            *(uint4*)&ctxB[(dt * 16 + l16) * 260 + qd * 64 + mt * 16 + quad * 4] =
                make_uint4(pk2[0], pk2[1], pk2[2], pk2[3]);
        }
        if (t < 64) {
            float s = 0.f;
#pragma unroll
            for (int wg2 = 0; wg2 < 8; wg2++)
                s += sksP[((t >> 5) * 8 + wg2) * 32 + (t & 31)];
            sksum[qd * 64 + t] = s;
        }
        __syncthreads();
    }

    {
        float mxn = -INFINITY;
#pragma unroll
        for (int j = 0; j < 2; j++)
#pragma unroll
            for (int mtl = 0; mtl < 4; mtl++)
#pragma unroll
                for (int i = 0; i < 4; i++) mxn = fmaxf(mxn, adq[j][mtl][i]);
        mxn = fmaxf(mxn, __shfl_xor(mxn, 16, 64));
        mxn = fmaxf(mxn, __shfl_xor(mxn, 32, 64));
        if (quad == 0) smaxP[wh * 128 + nq] = mxn;
    }
    __syncthreads();
    const float dmq = sdq[nq] + fmaxf(smaxP[nq], smaxP[128 + nq]) * nrm;

    floatx4 oT[2];
    oT[0] = (floatx4){0.f, 0.f, 0.f, 0.f};
    oT[1] = (floatx4){0.f, 0.f, 0.f, 0.f};
    float dp = 0.f;
#pragma unroll
    for (int j = 0; j < 2; j++) {
        const int qdo = 2 * j + (wh ^ 1);
#pragma unroll
        for (int mtl = 0; mtl < 4; mtl++) {
            unsigned pk[4];
#pragma unroll
            for (int i = 0; i < 4; i++) {
                const float qp = ratio * (__expf(adq[j][mtl][i] * nrm - dmq) + 1e-4f);
                dp += qp * sksum[qdo * 64 + mtl * 16 + quad * 4 + i];
                pk[i] = split_pack_fast(qp);
            }
            U8 tb; tb.u = make_uint4(pk[0], pk[1], pk[2], pk[3]);
#pragma unroll
            for (int dt = 0; dt < 2; dt++) {
                const short8 actx = *(const short8*)&sCtx[(dt * 16 + l16) * 520 + qdo * 128 + mtl * 32 + quad * 8];
                oT[dt] = __builtin_amdgcn_mfma_f32_16x16x32_bf16(actx, tb.s, oT[dt], 0, 0, 0);
            }
        }
    }
    dp += __shfl_xor(dp, 16, 64);
    dp += __shfl_xor(dp, 32, 64);
    if (quad == 0) sdenP[wh * 128 + nq] = dp;

    float* oRed = (float*)sBig;
    if (wh == 1) {
#pragma unroll
        for (int dt = 0; dt < 2; dt++)
            *(floatx4*)&oRed[((wg * 2 + dt) * 64 + lane) * 4] = oT[dt];
    }
    __syncthreads();
    if (wh == 0) {
        const float inv = 1.0f / (sdenP[nq] + sdenP[128 + nq]);
#pragma unroll
        for (int dt = 0; dt < 2; dt++) {
            const floatx4 o2 = *(const floatx4*)&oRed[((wg * 2 + dt) * 64 + lane) * 4];
            const unsigned r0 = split_pack((oT[dt][0] + o2[0]) * inv);
            const unsigned r1 = split_pack((oT[dt][1] + o2[1]) * inv);
            const unsigned r2 = split_pack((oT[dt][2] + o2[2]) * inv);
            const unsigned r3 = split_pack((oT[dt][3] + o2[3]) * inv);
            *(uint4*)&outp[((size_t)b * S_ + nq) * D_ + hh * DH_ + dt * 16 + quad * 4] =
                make_uint4(r0, r1, r2, r3);
        }
    }
}

// ---------- classification head (packed input) ----------
__global__ void __launch_bounds__(256) k_head(
    const unsigned* __restrict__ hfin, const float* __restrict__ h1w, const float* __restrict__ h1b,
    const float* __restrict__ h2w, const float* __restrict__ h2b,
    const float* __restrict__ ow, const float* __restrict__ ob, float* __restrict__ outp)
{
    __shared__ float c0[D_];
    __shared__ float c1[2 * HID_];
    __shared__ float sred[4];
    const int t = threadIdx.x;
    const int b = blockIdx.x;
    c0[t] = rec(hfin[(size_t)b * S_ * D_ + t]);
    __syncthreads();
#pragma unroll
    for (int half = 0; half < 2; half++) {
        const int j = half * 256 + t;
        float a = h1b[j];
        const float* w = h1w + (size_t)j * D_;
        for (int d = 0; d < D_; d += 4) {
            const float4 w4 = *(const float4*)&w[d];
            const float4 x4 = *(const float4*)&c0[d];
            a += x4.x * w4.x + x4.y * w4.y + x4.z * w4.z + x4.w * w4.w;
        }
        c1[j] = (a >= 0.f) ? a : 0.2f * a;
    }
    __syncthreads();
    float a2 = h2b[t];
    const float* w2 = h2w + (size_t)t * (2 * HID_);
    for (int j = 0; j < 2 * HID_; j += 4) {
        const float4 w4 = *(const float4*)&w2[j];
        const float4 x4 = *(const float4*)&c1[j];
        a2 += x4.x * w4.x + x4.y * w4.y + x4.z * w4.z + x4.w * w4.w;
    }
    const float c2 = (a2 >= 0.f) ? a2 : 0.2f * a2;
    const float s = blk_sum(c2 * ow[t], sred);
    if (t == 0) outp[b] = s + ob[0];
}

extern "C" void kernel_launch(void* const* d_in, const int* in_sizes, int n_in,
                              void* d_out, int out_size, void* d_ws, size_t ws_size,
                              hipStream_t stream)
{
    const float* x     = (const float*)d_in[0];
    const int*   mask  = (const int*)d_in[1];
    const float* emb_w = (const float*)d_in[2];
    const float* emb_b = (const float*)d_in[3];
    const float* Wq    = (const float*)d_in[4];
    const float* bq    = (const float*)d_in[5];
    const float* Wk    = (const float*)d_in[6];
    const float* bk    = (const float*)d_in[7];
    const float* Wv    = (const float*)d_in[8];
    const float* bv    = (const float*)d_in[9];
    const float* Wo    = (const float*)d_in[10];
    const float* bo    = (const float*)d_in[11];
    const float* proj  = (const float*)d_in[12];
    const float* n1w   = (const float*)d_in[13];
    const float* n1b   = (const float*)d_in[14];
    const float* n2w   = (const float*)d_in[15];
    const float* n2b   = (const float*)d_in[16];
    const float* f1w   = (const float*)d_in[17];
    const float* f1b   = (const float*)d_in[18];
    const float* f2w   = (const float*)d_in[19];
    const float* f2b   = (const float*)d_in[20];
    const float* h1w   = (const float*)d_in[21];
    const float* h1b   = (const float*)d_in[22];
    const float* h2w   = (const float*)d_in[23];
    const float* h2b   = (const float*)d_in[24];
    const float* ow    = (const float*)d_in[25];
    const float* ob    = (const float*)d_in[26];

    const size_t BSD = (size_t)B_ * S_ * D_;
    unsigned* A = (unsigned*)d_ws;                 // packed activations
    unsigned* Q = A + BSD;
    unsigned* K = Q + BSD;
    unsigned* V = K + BSD;
    unsigned* T = K;                               // post-LN1 alias (K dead after attn)
    const size_t WMU = 65536;                      // ushorts per matrix plane (256x256)
    ushort* WH = (ushort*)(V + BSD);               // 6 x L x 65536 ushorts (h planes)
    ushort* WL = WH + 6 * L_ * WMU;                // 6 x L x 65536 ushorts (l planes)
    unsigned* P2 = (unsigned*)(WL + 6 * L_ * WMU); // compact split proj: L x 256 x 32 uints
    int* slots = (int*)(P2 + (size_t)L_ * M_ * DH_);

    // fused prep: weights + proj + reset + embedding (blocks 801..8992)
    k_prep<<<801 + 8192, 256, 0, stream>>>(Wq, Wk, Wv, Wo, f1w, f2w, proj, WH, WL, P2, slots,
                                           x, emb_w, emb_b, A);

    const int GB = B_ * S_ / 64;               // 512 blocks per GEMM
    const int DB = B_ * H_ * S_ / 64 * 2;      // 8192 blocks for k_dmax
    const size_t ATTN_LDS = 120832;            // 118 KB dynamic LDS

    for (int l = 0; l < L_; l++) {
        const unsigned* P2l = P2 + (size_t)l * M_ * DH_;
        k_gemm_qkv<<<3 * GB, 512, 0, stream>>>(A, WH, WL, l, bq + l * D_, bk + l * D_, bv + l * D_, mask, Q, K, V);
        k_dmax<<<DB, 256, 0, stream>>>(K, P2l, slots + l);
        k_attn2<<<B_ * H_, 1024, ATTN_LDS, stream>>>(Q, K, V, P2l, slots + l, A);
        k_gemm<2><<<GB, 512, 0, stream>>>(A, WH + (3 * L_ + l) * WMU, WL + (3 * L_ + l) * WMU, bo + l * D_, n1w + l * D_, n1b + l * D_, nullptr, T);
        k_gemm<3><<<GB, 512, 0, stream>>>(T, WH + (4 * L_ + l) * WMU, WL + (4 * L_ + l) * WMU, f1b + l * HID_, nullptr, nullptr, nullptr, Q);
        k_gemm<2><<<GB, 512, 0, stream>>>(Q, WH + (5 * L_ + l) * WMU, WL + (5 * L_ + l) * WMU, f2b + l * D_, n2w + l * D_, n2b + l * D_, nullptr, A);
    }
    k_head<<<B_, 256, 0, stream>>>(A, h1w, h1b, h2w, h2b, ow, ob, (float*)d_out);
}

// Round 9
// 1467.752 us; speedup vs baseline: 1.3847x; 1.0227x over previous
//
#include <hip/hip_runtime.h>
#include <math.h>

#define B_ 256
#define N_ 127
#define S_ 128
#define NDIM_ 3
#define D_ 256
#define H_ 8
#define DH_ 32
#define M_ 256
#define HID_ 256
#define L_ 4
#define LOG2E 1.44269504088896340736f

typedef __attribute__((ext_vector_type(8))) short short8;
typedef __attribute__((ext_vector_type(4))) float floatx4;

// ---------- bf16 split helpers ----------
__device__ __forceinline__ ushort bf16_rn(float x) {
    unsigned u = __float_as_uint(x);
    u = (u + 0x7fffu + ((u >> 16) & 1u)) >> 16;
    return (ushort)u;
}
__device__ __forceinline__ unsigned split_pack(float x) {
    const ushort h = bf16_rn(x);
    const float r = x - __uint_as_float(((unsigned)h) << 16);
    const ushort l = bf16_rn(r);
    return (unsigned)h | ((unsigned)l << 16);
}
// Fast 5-inst split (attn-internal kp/qp)
__device__ __forceinline__ unsigned split_pack_fast(float x) {
    const unsigned xu = __float_as_uint(x);
    const unsigned hb = xu & 0xffff0000u;
    const float r = x - __uint_as_float(hb);
    return (hb >> 16) | (__float_as_uint(r) & 0xffff0000u);
}
__device__ __forceinline__ unsigned dup_lo(unsigned u) {
    const unsigned h = u & 0xffffu;
    return h | (h << 16);
}
__device__ __forceinline__ unsigned dup_hi(unsigned u) {
    const unsigned l = u >> 16;
    return l | (l << 16);
}
__device__ __forceinline__ float rec(unsigned u) {
    return __uint_as_float(u << 16) + __uint_as_float(u & 0xffff0000u);
}
__device__ __forceinline__ unsigned hpair(unsigned u0, unsigned u1) {
    return (u0 & 0xffffu) | (u1 << 16);
}
__device__ __forceinline__ unsigned lpair(unsigned u0, unsigned u1) {
    return (u0 >> 16) | (u1 & 0xffff0000u);
}

// ---------- block reductions ----------
__device__ __forceinline__ float blk_sum(float v, float* sred) {
#pragma unroll
    for (int o = 32; o > 0; o >>= 1) v += __shfl_xor(v, o, 64);
    if ((threadIdx.x & 63) == 0) sred[threadIdx.x >> 6] = v;
    __syncthreads();
    v = sred[0] + sred[1] + sred[2] + sred[3];
    __syncthreads();
    return v;
}

// ---------- fused prep: weight planes + proj conv + slot reset + embedding ----------
__global__ void __launch_bounds__(256) k_prep(
    const float* __restrict__ Wq, const float* __restrict__ Wk, const float* __restrict__ Wv,
    const float* __restrict__ Wo, const float* __restrict__ f1w, const float* __restrict__ f2w,
    const float* __restrict__ proj, ushort* __restrict__ WH, ushort* __restrict__ WL,
    unsigned* __restrict__ P2, int* __restrict__ slots,
    const float* __restrict__ x, const float* __restrict__ ew, const float* __restrict__ eb,
    unsigned* __restrict__ Aout)
{
    const int bid = blockIdx.x;
    if (bid < 768) {
        const int tensor = bid / 128;
        const int tid = (bid & 127) * 256 + threadIdx.x;
        const float* src = tensor == 0 ? Wq : tensor == 1 ? Wk : tensor == 2 ? Wv
                         : tensor == 3 ? Wo : tensor == 4 ? f1w : f2w;
        ushort* dh = WH + (size_t)tensor * L_ * 65536;
        ushort* dl = WL + (size_t)tensor * L_ * 65536;
        const int l = tid >> 13;
        const int col = (tid >> 5) & 255, kc = tid & 31;
        const float* sp = src + ((size_t)l << 16) + col * 256 + kc * 8;
        float v[8];
        *(float4*)&v[0] = *(const float4*)sp;
        *(float4*)&v[4] = *(const float4*)(sp + 4);
        unsigned hu[4], lu[4];
#pragma unroll
        for (int i = 0; i < 4; i++) {
            const unsigned u0 = split_pack(v[2 * i]);
            const unsigned u1 = split_pack(v[2 * i + 1]);
            hu[i] = hpair(u0, u1);
            lu[i] = lpair(u0, u1);
        }
        const size_t off = ((size_t)l << 16) + ((size_t)(kc * 256 + col)) * 8;
        *(uint4*)&dh[off] = make_uint4(hu[0], hu[1], hu[2], hu[3]);
        *(uint4*)&dl[off] = make_uint4(lu[0], lu[1], lu[2], lu[3]);
    } else if (bid < 800) {
        const int idx = ((bid - 768) * 256 + threadIdx.x) * 4;
        const float4 w4 = *(const float4*)&proj[idx];
        const float v[4] = {w4.x, w4.y, w4.z, w4.w};
        unsigned u[4];
#pragma unroll
        for (int i = 0; i < 4; i++) u[i] = split_pack(v[i]);
        *(uint4*)&P2[idx] = make_uint4(u[0], u[1], u[2], u[3]);
    } else if (bid == 800) {
        if (threadIdx.x < 4) {
            const int i = __float_as_int(-INFINITY);
            slots[threadIdx.x] = (i >= 0) ? i : (i ^ 0x7fffffff);
        }
    } else {
        const int idx4 = (bid - 801) * 256 + threadIdx.x;
        const int d0 = (idx4 & 63) * 4;
        const int n = (idx4 >> 6) & (S_ - 1);
        const int b = idx4 >> 13;
        unsigned r[4] = {0u, 0u, 0u, 0u};
        if (n > 0) {
            const float* xr = x + ((size_t)b * N_ + (n - 1)) * NDIM_;
            const float x0 = xr[0], x1 = xr[1], x2 = xr[2];
#pragma unroll
            for (int j = 0; j < 4; j++) {
                const int d = d0 + j;
                const float val = eb[d] + x0 * ew[d * 3 + 0] + x1 * ew[d * 3 + 1] + x2 * ew[d * 3 + 2];
                r[j] = split_pack(val);
            }
        }
        *(uint4*)&Aout[(size_t)idx4 * 4] = make_uint4(r[0], r[1], r[2], r[3]);
    }
}

// ---------- 3-product split MFMA GEMM, W direct-from-global ----------
template<int EPI>
__global__ void __launch_bounds__(512, 4) k_gemm(
    const unsigned* __restrict__ Ap, const ushort* __restrict__ WH,
    const ushort* __restrict__ WL,
    const float* __restrict__ bias, const float* __restrict__ g1,
    const float* __restrict__ g2, const int* __restrict__ mask,
    unsigned* __restrict__ out)
{
    __shared__ ushort sAh[2][2080];
    __shared__ ushort sAl[2][2080];
    __shared__ float sredA[64][4], sredB[64][4];
    const int t = threadIdx.x;
    const int w = t >> 6, lane = t & 63;
    const int quad = lane >> 4, l16 = lane & 15;
    const int rowbase = 32 * (w >> 2), colbase = 64 * (w & 3);
    const int colg = w & 3;
    const int row0 = blockIdx.x * 64;

    floatx4 acc[2][4];
#pragma unroll
    for (int rt = 0; rt < 2; rt++)
#pragma unroll
        for (int ct = 0; ct < 4; ct++) acc[rt][ct] = (floatx4){0.f, 0.f, 0.f, 0.f};

    const int arow = t >> 3, akq = t & 7;
    const unsigned* AG = Ap + (size_t)(row0 + arow) * D_ + akq * 4;
    const int aidx = (akq >> 1) * 520 + arow * 8 + (akq & 1) * 4;

    {
        const uint4 a4 = *(const uint4*)AG;
        *(uint2*)&sAh[0][aidx] = make_uint2(hpair(a4.x, a4.y), hpair(a4.z, a4.w));
        *(uint2*)&sAl[0][aidx] = make_uint2(lpair(a4.x, a4.y), lpair(a4.z, a4.w));
    }
    __syncthreads();

    for (int s = 0; s < 8; s++) {
        const int p = s & 1;
        uint4 a_n;
        if (s + 1 < 8) a_n = *(const uint4*)(AG + (s + 1) * 32);
        const size_t wbase = ((size_t)((s * 4 + quad) * 256 + colbase + l16)) * 8;
        const ushort* WHf = WH + wbase;
        const ushort* WLf = WL + wbase;
        short8 ah[2], al[2], wh[4], wl[4];
#pragma unroll
        for (int ct = 0; ct < 4; ct++) {
            wh[ct] = *(const short8*)&WHf[ct * 128];
            wl[ct] = *(const short8*)&WLf[ct * 128];
        }
#pragma unroll
        for (int rt = 0; rt < 2; rt++) {
            const int ai = quad * 520 + (rowbase + 16 * rt + l16) * 8;
            ah[rt] = *(const short8*)&sAh[p][ai];
            al[rt] = *(const short8*)&sAl[p][ai];
        }
#pragma unroll
        for (int rt = 0; rt < 2; rt++)
#pragma unroll
            for (int ct = 0; ct < 4; ct++) {
                acc[rt][ct] = __builtin_amdgcn_mfma_f32_16x16x32_bf16(ah[rt], wh[ct], acc[rt][ct], 0, 0, 0);
                acc[rt][ct] = __builtin_amdgcn_mfma_f32_16x16x32_bf16(ah[rt], wl[ct], acc[rt][ct], 0, 0, 0);
                acc[rt][ct] = __builtin_amdgcn_mfma_f32_16x16x32_bf16(al[rt], wh[ct], acc[rt][ct], 0, 0, 0);
            }
        if (s + 1 < 8) {
            *(uint2*)&sAh[p ^ 1][aidx] = make_uint2(hpair(a_n.x, a_n.y), hpair(a_n.z, a_n.w));
            *(uint2*)&sAl[p ^ 1][aidx] = make_uint2(lpair(a_n.x, a_n.y), lpair(a_n.z, a_n.w));
        }
        __syncthreads();
    }

    int colv[4]; float bv[4];
#pragma unroll
    for (int ct = 0; ct < 4; ct++) { colv[ct] = colbase + 16 * ct + l16; bv[ct] = bias[colv[ct]]; }

    if (EPI <= 1) {
        const int b = row0 >> 7;
#pragma unroll
        for (int rt = 0; rt < 2; rt++)
#pragma unroll
        for (int i = 0; i < 4; i++) {
            const int rl = rowbase + 16 * rt + quad * 4 + i;
            const int n = (row0 + rl) & (S_ - 1);
            float keep = 1.f;
            if (EPI == 1) keep = (n == 0) ? 1.f : (mask[b * N_ + n - 1] ? 0.f : 1.f);
#pragma unroll
            for (int ct = 0; ct < 4; ct++) {
                float c = acc[rt][ct][i] + bv[ct];
                if (EPI == 1) c *= keep;
                const int col = colv[ct];
                out[(((size_t)b * H_ + (col >> 5)) * S_ + n) * DH_ + (col & 31)] = split_pack(c);
            }
        }
    } else if (EPI == 2) {
        float gv[4], bbv[4];
#pragma unroll
        for (int ct = 0; ct < 4; ct++) { gv[ct] = g1[colv[ct]]; bbv[ct] = g2[colv[ct]]; }
#pragma unroll
        for (int rt = 0; rt < 2; rt++)
#pragma unroll
        for (int i = 0; i < 4; i++) {
            const int rl = rowbase + 16 * rt + quad * 4 + i;
            float s = 0.f, s2 = 0.f;
#pragma unroll
            for (int ct = 0; ct < 4; ct++) {
                const float c = acc[rt][ct][i] + bv[ct];
                s += c; s2 += c * c;
            }
#pragma unroll
            for (int o = 8; o > 0; o >>= 1) { s += __shfl_xor(s, o, 64); s2 += __shfl_xor(s2, o, 64); }
            if (l16 == 0) { sredA[rl][colg] = s; sredB[rl][colg] = s2; }
        }
        __syncthreads();
#pragma unroll
        for (int rt = 0; rt < 2; rt++)
#pragma unroll
        for (int i = 0; i < 4; i++) {
            const int rl = rowbase + 16 * rt + quad * 4 + i;
            const float s = sredA[rl][0] + sredA[rl][1] + sredA[rl][2] + sredA[rl][3];
            const float s2 = sredB[rl][0] + sredB[rl][1] + sredB[rl][2] + sredB[rl][3];
            const float mu = s * (1.f / D_);
            const float rs = rsqrtf(s2 * (1.f / D_) - mu * mu + 1e-5f);
#pragma unroll
            for (int ct = 0; ct < 4; ct++) {
                const float c = acc[rt][ct][i] + bv[ct];
                out[(size_t)(row0 + rl) * D_ + colv[ct]] = split_pack((c - mu) * rs * gv[ct] + bbv[ct]);
            }
        }
    } else {
#pragma unroll
        for (int rt = 0; rt < 2; rt++)
#pragma unroll
        for (int i = 0; i < 4; i++) {
            const int rl = rowbase + 16 * rt + quad * 4 + i;
#pragma unroll
            for (int ct = 0; ct < 4; ct++) {
                const float c = acc[rt][ct][i] + bv[ct];
                out[(size_t)(row0 + rl) * D_ + colv[ct]] = split_pack((c >= 0.f) ? c : 0.2f * c);
            }
        }
    }
}

// ---------- fused Q/K/V GEMM (grid 1536) ----------
__global__ void __launch_bounds__(512, 4) k_gemm_qkv(
    const unsigned* __restrict__ Ap, const ushort* __restrict__ WHb,
    const ushort* __restrict__ WLb, const int l,
    const float* __restrict__ bq, const float* __restrict__ bk, const float* __restrict__ bv_,
    const int* __restrict__ mask,
    unsigned* __restrict__ Qo, unsigned* __restrict__ Ko, unsigned* __restrict__ Vo)
{
    __shared__ ushort sAh[2][2080];
    __shared__ ushort sAl[2][2080];
    const int t = threadIdx.x;
    const int w = t >> 6, lane = t & 63;
    const int quad = lane >> 4, l16 = lane & 15;
    const int rowbase = 32 * (w >> 2), colbase = 64 * (w & 3);
    const int which = blockIdx.x >> 9;
    const int row0 = (blockIdx.x & 511) * 64;
    const ushort* WH = WHb + ((size_t)(which * L_ + l)) * 65536;
    const ushort* WL = WLb + ((size_t)(which * L_ + l)) * 65536;
    const float* bias = which == 0 ? bq : which == 1 ? bk : bv_;
    unsigned* out = which == 0 ? Qo : which == 1 ? Ko : Vo;

    floatx4 acc[2][4];
#pragma unroll
    for (int rt = 0; rt < 2; rt++)
#pragma unroll
        for (int ct = 0; ct < 4; ct++) acc[rt][ct] = (floatx4){0.f, 0.f, 0.f, 0.f};

    const int arow = t >> 3, akq = t & 7;
    const unsigned* AG = Ap + (size_t)(row0 + arow) * D_ + akq * 4;
    const int aidx = (akq >> 1) * 520 + arow * 8 + (akq & 1) * 4;

    {
        const uint4 a4 = *(const uint4*)AG;
        *(uint2*)&sAh[0][aidx] = make_uint2(hpair(a4.x, a4.y), hpair(a4.z, a4.w));
        *(uint2*)&sAl[0][aidx] = make_uint2(lpair(a4.x, a4.y), lpair(a4.z, a4.w));
    }
    __syncthreads();

    for (int s = 0; s < 8; s++) {
        const int p = s & 1;
        uint4 a_n;
        if (s + 1 < 8) a_n = *(const uint4*)(AG + (s + 1) * 32);
        const size_t wbase = ((size_t)((s * 4 + quad) * 256 + colbase + l16)) * 8;
        const ushort* WHf = WH + wbase;
        const ushort* WLf = WL + wbase;
        short8 ah[2], al[2], wh[4], wl[4];
#pragma unroll
        for (int ct = 0; ct < 4; ct++) {
            wh[ct] = *(const short8*)&WHf[ct * 128];
            wl[ct] = *(const short8*)&WLf[ct * 128];
        }
#pragma unroll
        for (int rt = 0; rt < 2; rt++) {
            const int ai = quad * 520 + (rowbase + 16 * rt + l16) * 8;
            ah[rt] = *(const short8*)&sAh[p][ai];
            al[rt] = *(const short8*)&sAl[p][ai];
        }
#pragma unroll
        for (int rt = 0; rt < 2; rt++)
#pragma unroll
            for (int ct = 0; ct < 4; ct++) {
                acc[rt][ct] = __builtin_amdgcn_mfma_f32_16x16x32_bf16(ah[rt], wh[ct], acc[rt][ct], 0, 0, 0);
                acc[rt][ct] = __builtin_amdgcn_mfma_f32_16x16x32_bf16(ah[rt], wl[ct], acc[rt][ct], 0, 0, 0);
                acc[rt][ct] = __builtin_amdgcn_mfma_f32_16x16x32_bf16(al[rt], wh[ct], acc[rt][ct], 0, 0, 0);
            }
        if (s + 1 < 8) {
            *(uint2*)&sAh[p ^ 1][aidx] = make_uint2(hpair(a_n.x, a_n.y), hpair(a_n.z, a_n.w));
            *(uint2*)&sAl[p ^ 1][aidx] = make_uint2(lpair(a_n.x, a_n.y), lpair(a_n.z, a_n.w));
        }
        __syncthreads();
    }

    int colv[4]; float bv[4];
#pragma unroll
    for (int ct = 0; ct < 4; ct++) { colv[ct] = colbase + 16 * ct + l16; bv[ct] = bias[colv[ct]]; }

    const int b = row0 >> 7;
#pragma unroll
    for (int rt = 0; rt < 2; rt++)
#pragma unroll
    for (int i = 0; i < 4; i++) {
        const int rl = rowbase + 16 * rt + quad * 4 + i;
        const int n = (row0 + rl) & (S_ - 1);
        float keep = 1.f;
        if (which == 2) keep = (n == 0) ? 1.f : (mask[b * N_ + n - 1] ? 0.f : 1.f);
#pragma unroll
        for (int ct = 0; ct < 4; ct++) {
            float c = acc[rt][ct][i] + bv[ct];
            c *= keep;
            const int col = colv[ct];
            out[(((size_t)b * H_ + (col >> 5)) * S_ + n) * DH_ + (col & 31)] = split_pack(c);
        }
    }
}

// ---------- fused FFN: out = LN2(leaky(T*f1w + f1b)*f2w + f2b) ----------
// Stage 1 computes G1^T via swapped MFMA operands so the C-layout has 4
// consecutive HID-cols per register group -> coalesced 8B LDS writes into
// [row][264] h/l planes (which alias the dead input-staging buffers).
// Stage 2 reads G1 fragments row-major from LDS (16B ds_read, min-aliased)
// and f2w from global planes; NO barriers in the stage-2 K-loop.
// Arithmetic bit-identical to the former k_gemm<3> + k_gemm<2> pair.
__global__ void __launch_bounds__(512, 4) k_ffn(
    const unsigned* __restrict__ Ap,
    const ushort* __restrict__ W1H, const ushort* __restrict__ W1L,
    const ushort* __restrict__ W2H, const ushort* __restrict__ W2L,
    const float* __restrict__ b1, const float* __restrict__ b2,
    const float* __restrict__ g1, const float* __restrict__ g2,
    unsigned* __restrict__ out)
{
    __shared__ char smemc[67584];              // h1 planes; staging aliases front
    ushort* h1h = (ushort*)smemc;              // [64][264]
    ushort* h1l = (ushort*)(smemc + 33792);
    ushort* sTh = (ushort*)smemc;              // [2][2080] (alias, dead before h1 writes)
    ushort* sTl = (ushort*)(smemc + 8320);
    __shared__ float sredA[64][4], sredB[64][4];
    const int t = threadIdx.x;
    const int w = t >> 6, lane = t & 63;
    const int quad = lane >> 4, l16 = lane & 15;
    const int row0 = blockIdx.x * 64;

    // ---- stage 1: G1^T = (f1w, T) swapped-operand MFMA ----
    floatx4 acc[2][4];
#pragma unroll
    for (int rt = 0; rt < 2; rt++)
#pragma unroll
        for (int ct = 0; ct < 4; ct++) acc[rt][ct] = (floatx4){0.f, 0.f, 0.f, 0.f};

    const int arow = t >> 3, akq = t & 7;
    const unsigned* AG = Ap + (size_t)(row0 + arow) * D_ + akq * 4;
    const int aidx = (akq >> 1) * 520 + arow * 8 + (akq & 1) * 4;

    {
        const uint4 a4 = *(const uint4*)AG;
        *(uint2*)&sTh[aidx] = make_uint2(hpair(a4.x, a4.y), hpair(a4.z, a4.w));
        *(uint2*)&sTl[aidx] = make_uint2(lpair(a4.x, a4.y), lpair(a4.z, a4.w));
    }
    __syncthreads();

    for (int s = 0; s < 8; s++) {
        const int p = s & 1;
        uint4 a_n;
        if (s + 1 < 8) a_n = *(const uint4*)(AG + (s + 1) * 32);
        // A-operand: f1w fragments at col2 = 32w + 16rt + l16
        const size_t wbase = ((size_t)((s * 4 + quad) * 256 + 32 * w + l16)) * 8;
        short8 fh[2], fl[2], th[4], tl[4];
#pragma unroll
        for (int rt = 0; rt < 2; rt++) {
            fh[rt] = *(const short8*)&W1H[wbase + rt * 128];
            fl[rt] = *(const short8*)&W1L[wbase + rt * 128];
        }
#pragma unroll
        for (int ct = 0; ct < 4; ct++) {
            const int ti = p * 2080 + quad * 520 + (16 * ct + l16) * 8;
            th[ct] = *(const short8*)&sTh[ti];
            tl[ct] = *(const short8*)&sTl[ti];
        }
#pragma unroll
        for (int rt = 0; rt < 2; rt++)
#pragma unroll
            for (int ct = 0; ct < 4; ct++) {
                acc[rt][ct] = __builtin_amdgcn_mfma_f32_16x16x32_bf16(fh[rt], th[ct], acc[rt][ct], 0, 0, 0);
                acc[rt][ct] = __builtin_amdgcn_mfma_f32_16x16x32_bf16(fl[rt], th[ct], acc[rt][ct], 0, 0, 0);
                acc[rt][ct] = __builtin_amdgcn_mfma_f32_16x16x32_bf16(fh[rt], tl[ct], acc[rt][ct], 0, 0, 0);
            }
        if (s + 1 < 8) {
            *(uint2*)&sTh[(p ^ 1) * 2080 + aidx] = make_uint2(hpair(a_n.x, a_n.y), hpair(a_n.z, a_n.w));
            *(uint2*)&sTl[(p ^ 1) * 2080 + aidx] = make_uint2(lpair(a_n.x, a_n.y), lpair(a_n.z, a_n.w));
        }
        __syncthreads();
    }
    // staging now dead (final barrier above) -> write h1 planes over it
#pragma unroll
    for (int rt = 0; rt < 2; rt++)
#pragma unroll
    for (int ct = 0; ct < 4; ct++) {
        unsigned u[4];
#pragma unroll
        for (int i = 0; i < 4; i++) {
            const int col2 = 32 * w + 16 * rt + quad * 4 + i;
            float c = acc[rt][ct][i] + b1[col2];
            c = (c >= 0.f) ? c : 0.2f * c;
            u[i] = split_pack(c);
        }
        const int base = (16 * ct + l16) * 264 + 32 * w + 16 * rt + quad * 4;
        *(uint2*)&h1h[base] = make_uint2(hpair(u[0], u[1]), hpair(u[2], u[3]));
        *(uint2*)&h1l[base] = make_uint2(lpair(u[0], u[1]), lpair(u[2], u[3]));
    }
    __syncthreads();

    // ---- stage 2: out = G1 * f2w, barrier-free K-loop ----
    const int rowbase = 32 * (w >> 2), colbase = 64 * (w & 3);
    const int colg = w & 3;
    floatx4 acc2[2][4];
#pragma unroll
    for (int rt = 0; rt < 2; rt++)
#pragma unroll
        for (int ct = 0; ct < 4; ct++) acc2[rt][ct] = (floatx4){0.f, 0.f, 0.f, 0.f};

    for (int ks = 0; ks < 8; ks++) {
        const size_t w2base = ((size_t)((ks * 4 + quad) * 256 + colbase + l16)) * 8;
        short8 ah[2], al[2], wh[4], wl[4];
#pragma unroll
        for (int ct = 0; ct < 4; ct++) {
            wh[ct] = *(const short8*)&W2H[w2base + ct * 128];
            wl[ct] = *(const short8*)&W2L[w2base + ct * 128];
        }
#pragma unroll
        for (int rt = 0; rt < 2; rt++) {
            const int gi = (rowbase + 16 * rt + l16) * 264 + ks * 32 + quad * 8;
            ah[rt] = *(const short8*)&h1h[gi];
            al[rt] = *(const short8*)&h1l[gi];
        }
#pragma unroll
        for (int rt = 0; rt < 2; rt++)
#pragma unroll
            for (int ct = 0; ct < 4; ct++) {
                acc2[rt][ct] = __builtin_amdgcn_mfma_f32_16x16x32_bf16(ah[rt], wh[ct], acc2[rt][ct], 0, 0, 0);
                acc2[rt][ct] = __builtin_amdgcn_mfma_f32_16x16x32_bf16(ah[rt], wl[ct], acc2[rt][ct], 0, 0, 0);
                acc2[rt][ct] = __builtin_amdgcn_mfma_f32_16x16x32_bf16(al[rt], wh[ct], acc2[rt][ct], 0, 0, 0);
            }
    }
    __syncthreads();

    // ---- LN epilogue (identical to k_gemm EPI==2) ----
    int colv[4]; float bv[4], gv[4], bbv[4];
#pragma unroll
    for (int ct = 0; ct < 4; ct++) {
        colv[ct] = colbase + 16 * ct + l16;
        bv[ct] = b2[colv[ct]];
        gv[ct] = g1[colv[ct]];
        bbv[ct] = g2[colv[ct]];
    }
#pragma unroll
    for (int rt = 0; rt < 2; rt++)
#pragma unroll
    for (int i = 0; i < 4; i++) {
        const int rl = rowbase + 16 * rt + quad * 4 + i;
        float s = 0.f, s2 = 0.f;
#pragma unroll
        for (int ct = 0; ct < 4; ct++) {
            const float c = acc2[rt][ct][i] + bv[ct];
            s += c; s2 += c * c;
        }
#pragma unroll
        for (int o = 8; o > 0; o >>= 1) { s += __shfl_xor(s, o, 64); s2 += __shfl_xor(s2, o, 64); }
        if (l16 == 0) { sredA[rl][colg] = s; sredB[rl][colg] = s2; }
    }
    __syncthreads();
#pragma unroll
    for (int rt = 0; rt < 2; rt++)
#pragma unroll
    for (int i = 0; i < 4; i++) {
        const int rl = rowbase + 16 * rt + quad * 4 + i;
        const float s = sredA[rl][0] + sredA[rl][1] + sredA[rl][2] + sredA[rl][3];
        const float s2 = sredB[rl][0] + sredB[rl][1] + sredB[rl][2] + sredB[rl][3];
        const float mu = s * (1.f / D_);
        const float rs = rsqrtf(s2 * (1.f / D_) - mu * mu + 1e-5f);
#pragma unroll
        for (int ct = 0; ct < 4; ct++) {
            const float c = acc2[rt][ct][i] + bv[ct];
            out[(size_t)(row0 + rl) * D_ + colv[ct]] = split_pack((c - mu) * rs * gv[ct] + bbv[ct]);
        }
    }
}

// ---------- lite MFMA global k-max (h-plane only) ----------
__global__ void __launch_bounds__(256) k_dmax(
    const unsigned* __restrict__ kg, const unsigned* __restrict__ P2, int* __restrict__ slot)
{
    __shared__ __align__(16) ushort A2s[64 * 40];
    __shared__ __align__(16) ushort Ps[128 * 40];
    __shared__ float sred[4];
    const int t = threadIdx.x;
    const size_t row0 = (size_t)(blockIdx.x >> 1) * 64;
    const int m0 = (blockIdx.x & 1) * 128;
    {
        const int row = t >> 2, seg = t & 3;
        const unsigned* src = kg + (row0 + row) * DH_ + seg * 8;
        const uint4 f0 = *(const uint4*)src;
        const uint4 f1 = *(const uint4*)(src + 4);
        *(uint4*)&A2s[row * 40 + seg * 8] =
            make_uint4(hpair(f0.x, f0.y), hpair(f0.z, f0.w), hpair(f1.x, f1.y), hpair(f1.z, f1.w));
    }
    {
        const int col = t >> 1, half = t & 1;
        const unsigned* src = P2 + (m0 + col) * DH_ + half * 16;
        const uint4 g0 = *(const uint4*)src;
        const uint4 g1 = *(const uint4*)(src + 4);
        const uint4 g2 = *(const uint4*)(src + 8);
        const uint4 g3 = *(const uint4*)(src + 12);
        *(uint4*)&Ps[col * 40 + half * 16] =
            make_uint4(hpair(g0.x, g0.y), hpair(g0.z, g0.w), hpair(g1.x, g1.y), hpair(g1.z, g1.w));
        *(uint4*)&Ps[col * 40 + half * 16 + 8] =
            make_uint4(hpair(g2.x, g2.y), hpair(g2.z, g2.w), hpair(g3.x, g3.y), hpair(g3.z, g3.w));
    }
    __syncthreads();
    const int w = t >> 6, lane = t & 63, quad = lane >> 4, l16 = lane & 15;
    floatx4 acc[4][2];
#pragma unroll
    for (int rt = 0; rt < 4; rt++)
#pragma unroll
        for (int ct = 0; ct < 2; ct++) acc[rt][ct] = (floatx4){0.f, 0.f, 0.f, 0.f};
    short8 af[4], bf[2];
#pragma unroll
    for (int rt = 0; rt < 4; rt++)
        af[rt] = *(const short8*)&A2s[(rt * 16 + l16) * 40 + quad * 8];
#pragma unroll
    for (int ct = 0; ct < 2; ct++)
        bf[ct] = *(const short8*)&Ps[((w * 2 + ct) * 16 + l16) * 40 + quad * 8];
#pragma unroll
    for (int rt = 0; rt < 4; rt++)
#pragma unroll
        for (int ct = 0; ct < 2; ct++)
            acc[rt][ct] = __builtin_amdgcn_mfma_f32_16x16x32_bf16(af[rt], bf[ct], acc[rt][ct], 0, 0, 0);
    float mx = -INFINITY;
#pragma unroll
    for (int rt = 0; rt < 4; rt++)
#pragma unroll
        for (int ct = 0; ct < 2; ct++)
#pragma unroll
            for (int i = 0; i < 4; i++) mx = fmaxf(mx, acc[rt][ct][i]);
#pragma unroll
    for (int o = 32; o > 0; o >>= 1) mx = fmaxf(mx, __shfl_xor(mx, o, 64));
    if (lane == 0) sred[w] = mx;
    __syncthreads();
    if (t == 0) {
        const float m4 = fmaxf(fmaxf(sred[0], sred[1]), fmaxf(sred[2], sred[3]))
                       * 0.42044820762685725f;
        const int i = __float_as_int(m4);
        atomicMax(slot, (i >= 0) ? i : (i ^ 0x7fffffff));
    }
}

// ---------- full-MFMA performer attention v4 (3-product kp/qp, h/l planes) ----------
__global__ void __launch_bounds__(1024) k_attn2(
    const unsigned* __restrict__ qg, const unsigned* __restrict__ kg, const unsigned* __restrict__ vg,
    const unsigned* __restrict__ P2, const int* __restrict__ slot,
    unsigned* __restrict__ outp)
{
    extern __shared__ char smem[];
    ushort* sAh   = (ushort*)(smem);            // [128][40] K h-plane
    ushort* sAl   = (ushort*)(smem + 10240);    // [128][40] K l-plane
    ushort* sBh   = (ushort*)(smem + 20480);    // [64][40] P-quarter h
    ushort* sBl   = (ushort*)(smem + 25600);    // [64][40] P-quarter l
    ushort* sBig  = (ushort*)(smem + 30720);    // kpT [64][264]; later oRed f32[4096]
    ushort* sV    = (ushort*)(smem + 64512);    // [32][264] v dup
    ushort* sCtx  = (ushort*)(smem + 81408);    // [32][520] ctx dup
    float* sdk    = (float*)(smem + 114688);    // [128] (+kmax fold)
    float* sdq    = (float*)(smem + 115200);    // [128]
    float* smaxP  = (float*)(smem + 115712);    // [2][128]
    float* sdenP  = (float*)(smem + 116736);    // [2][128]
    float* sksum  = (float*)(smem + 117760);    // [256]
    float* sksP   = (float*)(smem + 118784);    // [16][32]

    const int bh = blockIdx.x;
    const int b = bh >> 3, hh = bh & 7;
    const int t = threadIdx.x;
    const int w = t >> 6, lane = t & 63, quad = lane >> 4, l16 = lane & 15;
    const int wg = w & 7, wh = w >> 3;
    const int nq = wg * 16 + l16;
    const unsigned* kb = kg + (size_t)bh * S_ * DH_;
    const unsigned* qb = qg + (size_t)bh * S_ * DH_;
    const unsigned* vb = vg + (size_t)bh * S_ * DH_;
    const float nrm = 0.42044820762685725f;
    const float diagc = 0.5f * nrm * nrm;
    const float ratio = 0.0625f;

    union U8 { uint4 u; short8 s; };

    float kmaxv;
    { const int iv = *slot; kmaxv = __int_as_float((iv >= 0) ? iv : (iv ^ 0x7fffffff)); }

    short8 qfh, qfl;
    {
        const unsigned* qrow = qb + (size_t)nq * DH_ + quad * 8;
        const uint4 q0 = *(const uint4*)qrow;
        const uint4 q1 = *(const uint4*)(qrow + 4);
        U8 th; th.u = make_uint4(hpair(q0.x, q0.y), hpair(q0.z, q0.w), hpair(q1.x, q1.y), hpair(q1.z, q1.w));
        U8 tl; tl.u = make_uint4(lpair(q0.x, q0.y), lpair(q0.z, q0.w), lpair(q1.x, q1.y), lpair(q1.z, q1.w));
        qfh = th.s; qfl = tl.s;
    }

    if (t < 512) {
        const int row = t >> 2, seg = t & 3;
        const unsigned* src = kb + row * DH_ + seg * 8;
        const uint4 f0 = *(const uint4*)&src[0];
        const uint4 f1 = *(const uint4*)&src[4];
        *(uint4*)&sAh[row * 40 + seg * 8] =
            make_uint4(hpair(f0.x, f0.y), hpair(f0.z, f0.w), hpair(f1.x, f1.y), hpair(f1.z, f1.w));
        *(uint4*)&sAl[row * 40 + seg * 8] =
            make_uint4(lpair(f0.x, f0.y), lpair(f0.z, f0.w), lpair(f1.x, f1.y), lpair(f1.z, f1.w));
    } else {
        const int tt2 = t - 512;
        const int n = tt2 & 127, d0 = (tt2 >> 7) * 8;
        const unsigned* src = vb + n * DH_ + d0;
        const uint4 f0 = *(const uint4*)&src[0];
        const uint4 f1 = *(const uint4*)&src[4];
        const unsigned uu[8] = {f0.x, f0.y, f0.z, f0.w, f1.x, f1.y, f1.z, f1.w};
        unsigned* dst = (unsigned*)sV;
#pragma unroll
        for (int j = 0; j < 8; j++)
            dst[(d0 + j) * 132 + n] = dup_lo(uu[j]);
    }
    if (t < 128) {
        float s = 0.f, s2 = 0.f;
#pragma unroll
        for (int d4 = 0; d4 < DH_ / 4; d4++) {
            const uint4 kk = *(const uint4*)&kb[t * DH_ + d4 * 4];
            const float k0 = rec(kk.x), k1 = rec(kk.y), k2 = rec(kk.z), k3 = rec(kk.w);
            s += k0 * k0 + k1 * k1 + k2 * k2 + k3 * k3;
            const uint4 qq = *(const uint4*)&qb[t * DH_ + d4 * 4];
            const float q0 = rec(qq.x), q1 = rec(qq.y), q2 = rec(qq.z), q3 = rec(qq.w);
            s2 += q0 * q0 + q1 * q1 + q2 * q2 + q3 * q3;
        }
        sdk[t] = s * diagc + kmaxv;
        sdq[t] = s2 * diagc;
    }
    __syncthreads();

    floatx4 adq[2][4];
#pragma unroll
    for (int j = 0; j < 2; j++)
#pragma unroll
        for (int mtl = 0; mtl < 4; mtl++) adq[j][mtl] = (floatx4){0.f, 0.f, 0.f, 0.f};

#pragma unroll
    for (int qd = 0; qd < 4; qd++) {
        {
            const int col = t >> 4, ch2 = t & 15;
            const unsigned* src = P2 + (size_t)(qd * 64 + col) * DH_ + ch2 * 2;
            const unsigned u0 = src[0], u1 = src[1];
            ((unsigned*)sBh)[col * 20 + ch2] = hpair(u0, u1);
            ((unsigned*)sBl)[col * 20 + ch2] = lpair(u0, u1);
        }
        __syncthreads();
        floatx4 acc[2];
        acc[0] = (floatx4){0.f, 0.f, 0.f, 0.f};
        acc[1] = (floatx4){0.f, 0.f, 0.f, 0.f};
        {
            const short8 afh = *(const short8*)&sAh[nq * 40 + quad * 8];
            const short8 afl = *(const short8*)&sAl[nq * 40 + quad * 8];
#pragma unroll
            for (int ctl = 0; ctl < 2; ctl++) {
                const int mrow = ((2 * wh + ctl) * 16 + l16) * 40 + quad * 8;
                const short8 bfh = *(const short8*)&sBh[mrow];
                const short8 bfl = *(const short8*)&sBl[mrow];
                acc[ctl] = __builtin_amdgcn_mfma_f32_16x16x32_bf16(afh, bfh, acc[ctl], 0, 0, 0);
                acc[ctl] = __builtin_amdgcn_mfma_f32_16x16x32_bf16(afh, bfl, acc[ctl], 0, 0, 0);
                acc[ctl] = __builtin_amdgcn_mfma_f32_16x16x32_bf16(afl, bfh, acc[ctl], 0, 0, 0);
            }
        }
        unsigned* kpT = (unsigned*)sBig;
        float kc[2];
#pragma unroll
        for (int ctl = 0; ctl < 2; ctl++) {
            float kcl = 0.f;
            unsigned pk[4];
#pragma unroll
            for (int i = 0; i < 4; i++) {
                const int n = wg * 16 + quad * 4 + i;
                const float kp = ratio * (__expf(acc[ctl][i] * nrm - sdk[n]) + 1e-4f);
                kcl += kp;
                pk[i] = split_pack_fast(kp);
            }
            *(uint4*)&kpT[((2 * wh + ctl) * 16 + l16) * 132 + wg * 16 + quad * 4] =
                make_uint4(pk[0], pk[1], pk[2], pk[3]);
            kc[ctl] = kcl;
        }
#pragma unroll
        for (int ctl = 0; ctl < 2; ctl++) {
            kc[ctl] += __shfl_xor(kc[ctl], 16, 64);
            kc[ctl] += __shfl_xor(kc[ctl], 32, 64);
        }
        if (quad == 0) {
            sksP[w * 32 + l16] = kc[0];
            sksP[w * 32 + 16 + l16] = kc[1];
        }
        __syncthreads();
        const int qown = (qd & 1) ^ 1;
        if (wh == qown) {
            const int aidx2 = qd >> 1;
#pragma unroll
            for (int mtl = 0; mtl < 4; mtl++) {
                const int prow = (mtl * 16 + l16) * 40 + quad * 8;
                const short8 aPh = *(const short8*)&sBh[prow];
                const short8 aPl = *(const short8*)&sBl[prow];
                adq[aidx2][mtl] = __builtin_amdgcn_mfma_f32_16x16x32_bf16(aPh, qfh, adq[aidx2][mtl], 0, 0, 0);
                adq[aidx2][mtl] = __builtin_amdgcn_mfma_f32_16x16x32_bf16(aPh, qfl, adq[aidx2][mtl], 0, 0, 0);
                adq[aidx2][mtl] = __builtin_amdgcn_mfma_f32_16x16x32_bf16(aPl, qfh, adq[aidx2][mtl], 0, 0, 0);
            }
        } else {
            const int mt = wg & 3, dt = wg >> 2;
            floatx4 cacc = (floatx4){0.f, 0.f, 0.f, 0.f};
#pragma unroll
            for (int ks = 0; ks < 8; ks++) {
                const short8 a = *(const short8*)&sBig[(mt * 16 + l16) * 264 + ks * 32 + quad * 8];
                const short8 bvv = *(const short8*)&sV[(dt * 16 + l16) * 264 + ks * 32 + quad * 8];
                cacc = __builtin_amdgcn_mfma_f32_16x16x32_bf16(a, bvv, cacc, 0, 0, 0);
            }
            unsigned* ctxB = (unsigned*)sCtx;
            unsigned pk2[4];
#pragma unroll
            for (int i = 0; i < 4; i++) pk2[i] = (unsigned)bf16_rn(cacc[i]) * 0x10001u;
            *(uint4*)&ctxB[(dt * 16 + l16) * 260 + qd * 64 + mt * 16 + quad * 4] =
                make_uint4(pk2[0], pk2[1], pk2[2], pk2[3]);
        }
        if (t < 64) {
            float s = 0.f;
#pragma unroll
            for (int wg2 = 0; wg2 < 8; wg2++)
                s += sksP[((t >> 5) * 8 + wg2) * 32 + (t & 31)];
            sksum[qd * 64 + t] = s;
        }
        __syncthreads();
    }

    {
        float mxn = -INFINITY;
#pragma unroll
        for (int j = 0; j < 2; j++)
#pragma unroll
            for (int mtl = 0; mtl < 4; mtl++)
#pragma unroll
                for (int i = 0; i < 4; i++) mxn = fmaxf(mxn, adq[j][mtl][i]);
        mxn = fmaxf(mxn, __shfl_xor(mxn, 16, 64));
        mxn = fmaxf(mxn, __shfl_xor(mxn, 32, 64));
        if (quad == 0) smaxP[wh * 128 + nq] = mxn;
    }
    __syncthreads();
    const float dmq = sdq[nq] + fmaxf(smaxP[nq], smaxP[128 + nq]) * nrm;

    floatx4 oT[2];
    oT[0] = (floatx4){0.f, 0.f, 0.f, 0.f};
    oT[1] = (floatx4){0.f, 0.f, 0.f, 0.f};
    float dp = 0.f;
#pragma unroll
    for (int j = 0; j < 2; j++) {
        const int qdo = 2 * j + (wh ^ 1);
#pragma unroll
        for (int mtl = 0; mtl < 4; mtl++) {
            unsigned pk[4];
#pragma unroll
            for (int i = 0; i < 4; i++) {
                const float qp = ratio * (__expf(adq[j][mtl][i] * nrm - dmq) + 1e-4f);
                dp += qp * sksum[qdo * 64 + mtl * 16 + quad * 4 + i];
                pk[i] = split_pack_fast(qp);
            }
            U8 tb; tb.u = make_uint4(pk[0], pk[1], pk[2], pk[3]);
#pragma unroll
            for (int dt = 0; dt < 2; dt++) {
                const short8 actx = *(const short8*)&sCtx[(dt * 16 + l16) * 520 + qdo * 128 + mtl * 32 + quad * 8];
                oT[dt] = __builtin_amdgcn_mfma_f32_16x16x32_bf16(actx, tb.s, oT[dt], 0, 0, 0);
            }
        }
    }
    dp += __shfl_xor(dp, 16, 64);
    dp += __shfl_xor(dp, 32, 64);
    if (quad == 0) sdenP[wh * 128 + nq] = dp;

    float* oRed = (float*)sBig;
    if (wh == 1) {
#pragma unroll
        for (int dt = 0; dt < 2; dt++)
            *(floatx4*)&oRed[((wg * 2 + dt) * 64 + lane) * 4] = oT[dt];
    }
    __syncthreads();
    if (wh == 0) {
        const float inv = 1.0f / (sdenP[nq] + sdenP[128 + nq]);
#pragma unroll
        for (int dt = 0; dt < 2; dt++) {
            const floatx4 o2 = *(const floatx4*)&oRed[((wg * 2 + dt) * 64 + lane) * 4];
            const unsigned r0 = split_pack((oT[dt][0] + o2[0]) * inv);
            const unsigned r1 = split_pack((oT[dt][1] + o2[1]) * inv);
            const unsigned r2 = split_pack((oT[dt][2] + o2[2]) * inv);
            const unsigned r3 = split_pack((oT[dt][3] + o2[3]) * inv);
            *(uint4*)&outp[((size_t)b * S_ + nq) * D_ + hh * DH_ + dt * 16 + quad * 4] =
                make_uint4(r0, r1, r2, r3);
        }
    }
}

// ---------- classification head (packed input) ----------
__global__ void __launch_bounds__(256) k_head(
    const unsigned* __restrict__ hfin, const float* __restrict__ h1w, const float* __restrict__ h1b,
    const float* __restrict__ h2w, const float* __restrict__ h2b,
    const float* __restrict__ ow, const float* __restrict__ ob, float* __restrict__ outp)
{
    __shared__ float c0[D_];
    __shared__ float c1[2 * HID_];
    __shared__ float sred[4];
    const int t = threadIdx.x;
    const int b = blockIdx.x;
    c0[t] = rec(hfin[(size_t)b * S_ * D_ + t]);
    __syncthreads();
#pragma unroll
    for (int half = 0; half < 2; half++) {
        const int j = half * 256 + t;
        float a = h1b[j];
        const float* w = h1w + (size_t)j * D_;
        for (int d = 0; d < D_; d += 4) {
            const float4 w4 = *(const float4*)&w[d];
            const float4 x4 = *(const float4*)&c0[d];
            a += x4.x * w4.x + x4.y * w4.y + x4.z * w4.z + x4.w * w4.w;
        }
        c1[j] = (a >= 0.f) ? a : 0.2f * a;
    }
    __syncthreads();
    float a2 = h2b[t];
    const float* w2 = h2w + (size_t)t * (2 * HID_);
    for (int j = 0; j < 2 * HID_; j += 4) {
        const float4 w4 = *(const float4*)&w2[j];
        const float4 x4 = *(const float4*)&c1[j];
        a2 += x4.x * w4.x + x4.y * w4.y + x4.z * w4.z + x4.w * w4.w;
    }
    const float c2 = (a2 >= 0.f) ? a2 : 0.2f * a2;
    const float s = blk_sum(c2 * ow[t], sred);
    if (t == 0) outp[b] = s + ob[0];
}

extern "C" void kernel_launch(void* const* d_in, const int* in_sizes, int n_in,
                              void* d_out, int out_size, void* d_ws, size_t ws_size,
                              hipStream_t stream)
{
    const float* x     = (const float*)d_in[0];
    const int*   mask  = (const int*)d_in[1];
    const float* emb_w = (const float*)d_in[2];
    const float* emb_b = (const float*)d_in[3];
    const float* Wq    = (const float*)d_in[4];
    const float* bq    = (const float*)d_in[5];
    const float* Wk    = (const float*)d_in[6];
    const float* bk    = (const float*)d_in[7];
    const float* Wv    = (const float*)d_in[8];
    const float* bv    = (const float*)d_in[9];
    const float* Wo    = (const float*)d_in[10];
    const float* bo    = (const float*)d_in[11];
    const float* proj  = (const float*)d_in[12];
    const float* n1w   = (const float*)d_in[13];
    const float* n1b   = (const float*)d_in[14];
    const float* n2w   = (const float*)d_in[15];
    const float* n2b   = (const float*)d_in[16];
    const float* f1w   = (const float*)d_in[17];
    const float* f1b   = (const float*)d_in[18];
    const float* f2w   = (const float*)d_in[19];
    const float* f2b   = (const float*)d_in[20];
    const float* h1w   = (const float*)d_in[21];
    const float* h1b   = (const float*)d_in[22];
    const float* h2w   = (const float*)d_in[23];
    const float* h2b   = (const float*)d_in[24];
    const float* ow    = (const float*)d_in[25];
    const float* ob    = (const float*)d_in[26];

    const size_t BSD = (size_t)B_ * S_ * D_;
    unsigned* A = (unsigned*)d_ws;                 // packed activations
    unsigned* Q = A + BSD;
    unsigned* K = Q + BSD;
    unsigned* V = K + BSD;
    unsigned* T = K;                               // post-LN1 alias (K dead after attn)
    const size_t WMU = 65536;                      // ushorts per matrix plane (256x256)
    ushort* WH = (ushort*)(V + BSD);               // 6 x L x 65536 ushorts (h planes)
    ushort* WL = WH + 6 * L_ * WMU;                // 6 x L x 65536 ushorts (l planes)
    unsigned* P2 = (unsigned*)(WL + 6 * L_ * WMU); // compact split proj: L x 256 x 32 uints
    int* slots = (int*)(P2 + (size_t)L_ * M_ * DH_);

    // fused prep: weights + proj + reset + embedding (blocks 801..8992)
    k_prep<<<801 + 8192, 256, 0, stream>>>(Wq, Wk, Wv, Wo, f1w, f2w, proj, WH, WL, P2, slots,
                                           x, emb_w, emb_b, A);

    const int GB = B_ * S_ / 64;               // 512 blocks per GEMM
    const int DB = B_ * H_ * S_ / 64 * 2;      // 8192 blocks for k_dmax
    const size_t ATTN_LDS = 120832;            // 118 KB dynamic LDS

    for (int l = 0; l < L_; l++) {
        const unsigned* P2l = P2 + (size_t)l * M_ * DH_;
        k_gemm_qkv<<<3 * GB, 512, 0, stream>>>(A, WH, WL, l, bq + l * D_, bk + l * D_, bv + l * D_, mask, Q, K, V);
        k_dmax<<<DB, 256, 0, stream>>>(K, P2l, slots + l);
        k_attn2<<<B_ * H_, 1024, ATTN_LDS, stream>>>(Q, K, V, P2l, slots + l, A);
        k_gemm<2><<<GB, 512, 0, stream>>>(A, WH + (3 * L_ + l) * WMU, WL + (3 * L_ + l) * WMU, bo + l * D_, n1w + l * D_, n1b + l * D_, nullptr, T);
        k_ffn<<<GB, 512, 0, stream>>>(T, WH + (4 * L_ + l) * WMU, WL + (4 * L_ + l) * WMU,
                                      WH + (5 * L_ + l) * WMU, WL + (5 * L_ + l) * WMU,
                                      f1b + l * HID_, f2b + l * D_, n2w + l * D_, n2b + l * D_, A);
    }
    k_head<<<B_, 256, 0, stream>>>(A, h1w, h1b, h2w, h2b, ow, ob, (float*)d_out);
}